// Round 13
// baseline (1096.524 us; speedup 1.0000x reference)
//
#include <hip/hip_runtime.h>
#include <math.h>

#define Bv 8
#define Pv 12
#define Nv 5000
#define Hv 8
#define Ev 50000
#define NBv 8
#define TD1v 64
#define NIMG (Bv * Pv)
#define NPB 10                  // nodes per block (stage1/2)
#define TPB 240                 // active threads = NPB * 24
#define EC2 512                 // LDS edge capacity per 10-node chunk

// interleaved layout for h/vt/v2/acc: [b][n][p][ch]
#define IDX(b, n, p) ((((size_t)(b) * Nv + (n)) * Pv + (p)) * Hv)

typedef float f4v __attribute__((ext_vector_type(4)));

__device__ inline float4 nt_load4(const float* p) {
  f4v v = __builtin_nontemporal_load((const f4v*)p);
  return make_float4(v.x, v.y, v.z, v.w);
}
__device__ inline void nt_store4(float* p, float a, float b, float c, float d) {
  f4v v = {a, b, c, d};
  __builtin_nontemporal_store(v, (f4v*)p);
}

// correctly-rounded f32 of 10^(d/4), d=0..15 (matches numpy float32 powf)
__device__ __constant__ float POW10Q[16] = {
  1.0f, 1.7782794100389228f, 3.1622776601683795f, 5.623413251903491f,
  10.0f, 17.78279410038923f, 31.622776601683793f, 56.23413251903491f,
  100.0f, 177.82794100389228f, 316.22776601683796f, 562.341325190349f,
  1000.0f, 1778.2794100389228f, 3162.2776601683795f, 5623.413251903491f
};

// ---------------- setup: time-embedding chain, per-block t vectors, softmax(attn)
__global__ void k_setup(const int* timei, const float* attn,
                        const float* te_w1, const float* te_b1,
                        const float* te_w2, const float* te_b2,
                        const float* bt_w1, const float* bt_b1,
                        const float* bt_w2, const float* bt_b2,
                        float* t_all, float* a9) {
  __shared__ float te0[Bv][32];
  __shared__ float te1[Bv][64];
  __shared__ float te2[Bv][64];
  int t = threadIdx.x; // 64 threads
  for (int idx = t; idx < Bv * 16; idx += 64) {
    int b = idx >> 4, d = idx & 15;
    float e = (float)timei[b] * POW10Q[d];
    te0[b][d]      = (float)sin((double)e);
    te0[b][d + 16] = (float)cos((double)e);
  }
  __syncthreads();
  for (int idx = t; idx < Bv * 64; idx += 64) {
    int b = idx >> 6, j = idx & 63;
    float s = te_b1[j];
    for (int k = 0; k < 32; ++k) s += te0[b][k] * te_w1[k * 64 + j];
    te1[b][j] = s / (1.0f + expf(-s));
  }
  __syncthreads();
  for (int idx = t; idx < Bv * 64; idx += 64) {
    int b = idx >> 6, j = idx & 63;
    float s = te_b2[j];
    for (int k = 0; k < 64; ++k) s += te1[b][k] * te_w2[k * 64 + j];
    te2[b][j] = s / (1.0f + expf(-s));
  }
  __syncthreads();
  {
    int i = t >> 3, b = t & 7;
    float u[Hv];
    for (int j = 0; j < Hv; ++j) {
      float s = bt_b1[i * Hv + j];
      for (int k = 0; k < TD1v; ++k) s += te2[b][k] * bt_w1[(i * TD1v + k) * Hv + j];
      u[j] = fmaxf(s, 0.0f);
    }
    for (int ch = 0; ch < Hv; ++ch) {
      float s = bt_b2[i * Hv + ch];
      for (int j = 0; j < Hv; ++j) s += u[j] * bt_w2[(i * Hv + j) * Hv + ch];
      t_all[(i * Bv + b) * Hv + ch] = s;
    }
  }
  if (t == 0) {
    float m = attn[0];
    for (int i = 1; i < 9; ++i) m = fmaxf(m, attn[i]);
    float s = 0.f, ex[9];
    for (int i = 0; i < 9; ++i) { ex[i] = expf(attn[i] - m); s += ex[i]; }
    for (int i = 0; i < 9; ++i) a9[i] = ex[i] / s;
  }
}

// ---------------- positional projection, once: posp[n][ch]
__global__ void k_posp(const float* pos, const float* pw1, const float* pb1,
                       const float* pw2, const float* pb2, float* posp) {
  int n = blockIdx.x * blockDim.x + threadIdx.x;
  if (n >= Nv) return;
  const float4* pr = (const float4*)(pos + (size_t)n * Hv);
  float4 r0 = pr[0], r1 = pr[1];
  float x[8] = {r0.x, r0.y, r0.z, r0.w, r1.x, r1.y, r1.z, r1.w};
  float u[8];
  #pragma unroll
  for (int j = 0; j < 8; ++j) {
    float s = pb1[j];
    #pragma unroll
    for (int k = 0; k < 8; ++k) s += x[k] * pw1[k * 8 + j];
    u[j] = fmaxf(s, 0.f);
  }
  float o[8];
  #pragma unroll
  for (int ch = 0; ch < 8; ++ch) {
    float s = pb2[ch];
    #pragma unroll
    for (int j = 0; j < 8; ++j) s += u[j] * pw2[j * 8 + ch];
    o[ch] = s;
  }
  float4* po = (float4*)(posp + (size_t)n * Hv);
  po[0] = make_float4(o[0], o[1], o[2], o[3]);
  po[1] = make_float4(o[4], o[5], o[6], o[7]);
}

// zero deg/cursor + all stats slots
__global__ void k_zero(float* deg, int* cursor, float* stats) {
  int i = blockIdx.x * blockDim.x + threadIdx.x;
  if (i < Nv) { deg[i] = 0.f; cursor[i] = 0; }
  if (i < NBv * 2 * NIMG * 2) stats[i] = 0.f;
}

__global__ void k_deg(const int* eidx, float* deg) {
  int e = blockIdx.x * blockDim.x + threadIdx.x;
  if (e < Ev) atomicAdd(&deg[eidx[Ev + e]], 1.0f);
}

__global__ void k_dinv(const float* deg, float* dinv) {
  int n = blockIdx.x * blockDim.x + threadIdx.x;
  if (n < Nv) {
    float d = deg[n];
    dinv[n] = d > 0.f ? (float)(1.0 / sqrt((double)d)) : 0.f;
  }
}

// single-block Hillis-Steele scan of per-dst counts -> row_ptr[0..Nv]
__global__ void k_scan(const float* deg, int* row_ptr) {
  __shared__ int buf[1024];
  __shared__ int base_s;
  int t = threadIdx.x;
  if (t == 0) { base_s = 0; row_ptr[0] = 0; }
  __syncthreads();
  for (int c = 0; c < 5; ++c) {
    int i = c * 1024 + t;
    int v = (i < Nv) ? (int)(deg[i] + 0.5f) : 0;
    buf[t] = v;
    __syncthreads();
    for (int off = 1; off < 1024; off <<= 1) {
      int add = (t >= off) ? buf[t - off] : 0;
      __syncthreads();
      buf[t] += add;
      __syncthreads();
    }
    int base = base_s;
    if (i < Nv) row_ptr[i + 1] = base + buf[t];
    __syncthreads();
    if (t == 1023) base_s = base + buf[1023];
    __syncthreads();
  }
}

// CSR fill: packed (src_bits, w) per edge
__global__ void k_csr(const int* eidx, const float* dinv, const int* row_ptr,
                      int* cursor, float2* epack) {
  int e = blockIdx.x * blockDim.x + threadIdx.x;
  if (e >= Ev) return;
  int s = eidx[e], d = eidx[Ev + e];
  int slot = atomicAdd(&cursor[d], 1);
  int pos = row_ptr[d] + slot;
  epack[pos] = make_float2(__int_as_float(s), dinv[s] * dinv[d]);
}

// ---------------- per block-iter, image-independent: Gw[i][n]=Σ w_e gnw_i[src], Gb likewise
__global__ __launch_bounds__(256) void k_gwb(
    const int* __restrict__ row_ptr, const float2* __restrict__ epack,
    const float* __restrict__ gn_w, const float* __restrict__ gn_b,
    float* __restrict__ Gw, float* __restrict__ Gb) {
  int id = blockIdx.x * 256 + threadIdx.x;
  if (id >= NBv * Nv) return;
  int i = id / Nv, n = id % Nv;
  const float* gw = gn_w + (size_t)i * Nv * Hv;
  const float* gb = gn_b + (size_t)i * Nv * Hv;
  float aw[8] = {0,0,0,0,0,0,0,0}, ab[8] = {0,0,0,0,0,0,0,0};
  int e0 = row_ptr[n], e1 = row_ptr[n + 1];
  for (int e = e0; e < e1; ++e) {
    float2 ep = epack[e];
    int s = __float_as_int(ep.x);
    float w = ep.y;
    const float4* wr = (const float4*)(gw + (size_t)s * Hv);
    const float4* br = (const float4*)(gb + (size_t)s * Hv);
    float4 w0 = wr[0], w1 = wr[1], b0 = br[0], b1 = br[1];
    aw[0] += w * w0.x; aw[1] += w * w0.y; aw[2] += w * w0.z; aw[3] += w * w0.w;
    aw[4] += w * w1.x; aw[5] += w * w1.y; aw[6] += w * w1.z; aw[7] += w * w1.w;
    ab[0] += w * b0.x; ab[1] += w * b0.y; ab[2] += w * b0.z; ab[3] += w * b0.w;
    ab[4] += w * b1.x; ab[5] += w * b1.y; ab[6] += w * b1.z; ab[7] += w * b1.w;
  }
  float4* wo = (float4*)(Gw + (size_t)id * Hv);
  wo[0] = make_float4(aw[0], aw[1], aw[2], aw[3]);
  wo[1] = make_float4(aw[4], aw[5], aw[6], aw[7]);
  float4* bo = (float4*)(Gb + (size_t)id * Hv);
  bo[0] = make_float4(ab[0], ab[1], ab[2], ab[3]);
  bo[1] = make_float4(ab[4], ab[5], ab[6], ab[7]);
}

// ---------------- h init: input proj + pos proj; acc = a0*h (interleaved layout)
__global__ void k_init(const float* x, const float* posp,
                       const float* iw1, const float* ib1,
                       const float* iw2, const float* ib2,
                       const float* a9, float* h, float* acc) {
  int t = blockIdx.x * blockDim.x + threadIdx.x;
  if (t >= Bv * Pv * Nv) return;
  int b = t / (Pv * Nv);
  int r = t - b * (Pv * Nv);
  int p = r / Nv, n = r - p * Nv;
  float xv = __builtin_nontemporal_load(x + t);
  float u[8];
  #pragma unroll
  for (int j = 0; j < 8; ++j) u[j] = fmaxf(xv * iw1[j] + ib1[j], 0.f);
  const float4* pp = (const float4*)(posp + (size_t)n * Hv);
  float4 p0 = pp[0], p1 = pp[1];
  float pv[8] = {p0.x, p0.y, p0.z, p0.w, p1.x, p1.y, p1.z, p1.w};
  float a0 = a9[0];
  float o[8];
  #pragma unroll
  for (int ch = 0; ch < 8; ++ch) {
    float s = ib2[ch];
    #pragma unroll
    for (int j = 0; j < 8; ++j) s += u[j] * iw2[j * 8 + ch];
    o[ch] = s + pv[ch];
  }
  size_t a = IDX(b, n, p);
  float4* hr = (float4*)(h + a);
  hr[0] = make_float4(o[0], o[1], o[2], o[3]);
  hr[1] = make_float4(o[4], o[5], o[6], o[7]);
  nt_store4(acc + a,     a0 * o[0], a0 * o[1], a0 * o[2], a0 * o[3]);
  nt_store4(acc + a + 4, a0 * o[4], a0 * o[5], a0 * o[6], a0 * o[7]);
}

// ---------------- stage 1: vt = gnw ⊙ (h + proj(cond)); stats over v1
// grid: 8 (b=XCD) x 500 chunks; thread = (n_local, p, quad), 240 active
__global__ __launch_bounds__(256) void k_stage1(
    const float* __restrict__ h, const float* __restrict__ cond,
    const float* w1, const float* b1, const float* w2, const float* b2,
    const float* __restrict__ gnw,
    float* __restrict__ vt, float* stats1) {
  __shared__ float lw1[64], lw2[64], lb1[8], lb2[8];
  __shared__ float sm1[12], sm2[12];
  int t = threadIdx.x;
  int b = blockIdx.x & 7;
  int chunk = blockIdx.x >> 3;
  if (t < 64) lw1[t] = w1[t];
  else if (t < 128) lw2[t - 64] = w2[t - 64];
  else if (t < 136) lb1[t - 128] = b1[t - 128];
  else if (t < 144) lb2[t - 136] = b2[t - 136];
  else if (t < 156) sm1[t - 144] = 0.f;
  else if (t < 168) sm2[t - 156] = 0.f;
  __syncthreads();
  if (t < TPB) {
    int nl = t / 24, pq = t % 24;
    int p = pq >> 1, quad = pq & 1;
    int n = chunk * NPB + nl;
    // cond row half (input layout [B][P][N][H]) + pair-exchange for full 8 ch
    size_t caddr = (((size_t)(b * Pv + p)) * Nv + n) * Hv + quad * 4;
    float4 cme = nt_load4(cond + caddr);
    float e0 = __shfl_xor(cme.x, 1, 64);
    float e1 = __shfl_xor(cme.y, 1, 64);
    float e2 = __shfl_xor(cme.z, 1, 64);
    float e3 = __shfl_xor(cme.w, 1, 64);
    float c8[8];
    if (quad == 0) {
      c8[0] = cme.x; c8[1] = cme.y; c8[2] = cme.z; c8[3] = cme.w;
      c8[4] = e0; c8[5] = e1; c8[6] = e2; c8[7] = e3;
    } else {
      c8[0] = e0; c8[1] = e1; c8[2] = e2; c8[3] = e3;
      c8[4] = cme.x; c8[5] = cme.y; c8[6] = cme.z; c8[7] = cme.w;
    }
    float u[8];
    #pragma unroll
    for (int j = 0; j < 8; ++j) {
      float s = lb1[j];
      #pragma unroll
      for (int k = 0; k < 8; ++k) s += c8[k] * lw1[k * 8 + j];
      u[j] = fmaxf(s, 0.f);
    }
    size_t a = IDX(b, n, p) + quad * 4;
    float4 h4 = *(const float4*)(h + a);
    float hv[4] = {h4.x, h4.y, h4.z, h4.w};
    float val[4];
    float s1 = 0.f, s2 = 0.f;
    #pragma unroll
    for (int m = 0; m < 4; ++m) {
      int ch = quad * 4 + m;
      float s = lb2[ch];
      #pragma unroll
      for (int j = 0; j < 8; ++j) s += u[j] * lw2[j * 8 + ch];
      float v = s + hv[m];
      val[m] = v;
      s1 += v; s2 += v * v;
    }
    atomicAdd(&sm1[p], s1);
    atomicAdd(&sm2[p], s2);
    float4 g4 = *(const float4*)(gnw + (size_t)n * Hv + quad * 4);
    *(float4*)(vt + a) = make_float4(val[0] * g4.x, val[1] * g4.y,
                                     val[2] * g4.z, val[3] * g4.w);
  }
  __syncthreads();
  if (t < 12) {
    atomicAdd(&stats1[(b * Pv + t) * 2],     sm1[t]);
    atomicAdd(&stats1[(b * Pv + t) * 2 + 1], sm2[t]);
  }
}

// ---------------- stage 2: v2 = rstd*SpMM(vt) - mean*rstd*Gw + Gb + t; stats2
// grid: 8 x 500; per edge, the 24-thread node-group reads 384B contiguous (12 images)
__global__ __launch_bounds__(256) void k_stage2(
    const float* __restrict__ vt, float* __restrict__ v2,
    const int* __restrict__ row_ptr, const float2* __restrict__ epack,
    const float* __restrict__ Gw, const float* __restrict__ Gb,
    const float* __restrict__ stats1, float* stats2,
    const float* __restrict__ tvec) {
  __shared__ float2 se[EC2];
  __shared__ float smean[12], srstd[12], sm1[12], sm2[12];
  int t = threadIdx.x;
  int b = blockIdx.x & 7;
  int chunk = blockIdx.x >> 3;
  int n0 = chunk * NPB;
  if (t < 12) {
    int g = b * Pv + t;
    float m  = stats1[g * 2]     * (1.f / 40000.f);
    float m2 = stats1[g * 2 + 1] * (1.f / 40000.f);
    float var = m2 - m * m;
    smean[t] = m;
    srstd[t] = (float)(1.0 / sqrt((double)var + 1e-5));
    sm1[t] = 0.f; sm2[t] = 0.f;
  }
  int eb0 = row_ptr[n0];
  int cnt = row_ptr[n0 + NPB] - eb0;
  bool staged = (cnt <= EC2);
  if (staged) {
    for (int k = t; k < cnt; k += 256) se[k] = epack[eb0 + k];
  }
  __syncthreads();
  if (t < TPB) {
    int nl = t / 24, pq = t % 24;
    int p = pq >> 1, quad = pq & 1;
    int n = n0 + nl;
    float a0 = 0.f, a1 = 0.f, a2 = 0.f, a3 = 0.f;
    int e0 = row_ptr[n], e1 = row_ptr[n + 1];
    size_t bbase = (size_t)b * Nv * Pv * Hv + (size_t)p * Hv + quad * 4;
    if (staged) {
      for (int e = e0 - eb0; e < e1 - eb0; ++e) {
        float2 ep = se[e];
        int s = __float_as_int(ep.x);
        float w = ep.y;
        float4 v = *(const float4*)(vt + bbase + (size_t)s * (Pv * Hv));
        a0 += w * v.x; a1 += w * v.y; a2 += w * v.z; a3 += w * v.w;
      }
    } else {
      for (int e = e0; e < e1; ++e) {
        float2 ep = epack[e];
        int s = __float_as_int(ep.x);
        float w = ep.y;
        float4 v = *(const float4*)(vt + bbase + (size_t)s * (Pv * Hv));
        a0 += w * v.x; a1 += w * v.y; a2 += w * v.z; a3 += w * v.w;
      }
    }
    float mean = smean[p], rstd = srstd[p];
    float mrs = mean * rstd;
    float4 gw4 = *(const float4*)(Gw + (size_t)n * Hv + quad * 4);
    float4 gb4 = *(const float4*)(Gb + (size_t)n * Hv + quad * 4);
    float4 t4  = *(const float4*)(tvec + b * Hv + quad * 4);
    float o0 = rstd * a0 - mrs * gw4.x + gb4.x + t4.x;
    float o1 = rstd * a1 - mrs * gw4.y + gb4.y + t4.y;
    float o2 = rstd * a2 - mrs * gw4.z + gb4.z + t4.z;
    float o3 = rstd * a3 - mrs * gw4.w + gb4.w + t4.w;
    atomicAdd(&sm1[p], o0 + o1 + o2 + o3);
    atomicAdd(&sm2[p], o0 * o0 + o1 * o1 + o2 * o2 + o3 * o3);
    *(float4*)(v2 + IDX(b, n, p) + quad * 4) = make_float4(o0, o1, o2, o3);
  }
  __syncthreads();
  if (t < 12) {
    atomicAdd(&stats2[(b * Pv + t) * 2],     sm1[t]);
    atomicAdd(&stats2[(b * Pv + t) * 2 + 1], sm2[t]);
  }
}

// ---------------- stage 3: LN(v2) + 12x12 conv over P (in-place) + skip acc
// grid: 8 x 40; thread = (n, quad); per-node data is 384B contiguous
__global__ __launch_bounds__(256) void k_stage3(
    float* __restrict__ v2, float* __restrict__ acc,
    const float* __restrict__ stats2,
    const float* __restrict__ tnw, const float* __restrict__ tnb,
    const float* __restrict__ cw, const float* __restrict__ cb,
    const float* __restrict__ a9, int iblk) {
  __shared__ float scw[144], scb[12], smean[12], srstd[12];
  int t = threadIdx.x;
  int b = blockIdx.x & 7;
  int chunk = blockIdx.x >> 3;
  if (t < 144) scw[t] = cw[t];
  else if (t < 156) scb[t - 144] = cb[t - 144];
  else if (t < 168) {
    int p = t - 156;
    int g = b * Pv + p;
    float mean = stats2[g * 2]     * (1.f / 40000.f);
    float m2   = stats2[g * 2 + 1] * (1.f / 40000.f);
    float var  = m2 - mean * mean;
    smean[p] = mean;
    srstd[p] = (float)(1.0 / sqrt((double)var + 1e-5));
  }
  __syncthreads();
  int idx = chunk * 256 + t;
  if (idx >= Nv * 2) return;
  int n = idx >> 1, quad = idx & 1;
  const float4 w4 = nt_load4(tnw + (size_t)n * Hv + quad * 4);
  const float4 b4 = nt_load4(tnb + (size_t)n * Hv + quad * 4);
  size_t base = IDX(b, n, 0) + quad * 4;
  float4 in[12];
  #pragma unroll
  for (int p = 0; p < 12; ++p) {
    float4 v = *(const float4*)(v2 + base + p * Hv);
    float mean = smean[p], rstd = srstd[p];
    in[p].x = (v.x - mean) * rstd * w4.x + b4.x;
    in[p].y = (v.y - mean) * rstd * w4.y + b4.y;
    in[p].z = (v.z - mean) * rstd * w4.z + b4.z;
    in[p].w = (v.w - mean) * rstd * w4.w + b4.w;
  }
  float ai = a9[iblk + 1];
  #pragma unroll
  for (int q = 0; q < 12; ++q) {
    float4 o = make_float4(scb[q], scb[q], scb[q], scb[q]);
    #pragma unroll
    for (int p = 0; p < 12; ++p) {
      float c = scw[q * 12 + p];
      o.x += c * in[p].x; o.y += c * in[p].y;
      o.z += c * in[p].z; o.w += c * in[p].w;
    }
    size_t off = base + q * Hv;
    *(float4*)(v2 + off) = o;        // live: next stage1 reads it
    float4 av = nt_load4(acc + off); // acc: streaming RMW
    nt_store4(acc + off, av.x + ai * o.x, av.y + ai * o.y,
                         av.z + ai * o.z, av.w + ai * o.w);
  }
}

// ---------------- output projection (reads interleaved acc, writes [B][P][N])
__global__ void k_out(const float* acc, const float* ow1, const float* ob1,
                      const float* ow2, const float* ob2, float* out) {
  int t = blockIdx.x * blockDim.x + threadIdx.x;
  if (t >= Bv * Pv * Nv) return;
  int b = t / (Pv * Nv);
  int r = t - b * (Pv * Nv);
  int p = r / Nv, n = r - p * Nv;
  size_t a = IDX(b, n, p);
  float4 a0 = nt_load4(acc + a);
  float4 a1 = nt_load4(acc + a + 4);
  float x[8] = {a0.x, a0.y, a0.z, a0.w, a1.x, a1.y, a1.z, a1.w};
  float o = ob2[0];
  #pragma unroll
  for (int j = 0; j < 8; ++j) {
    float s = ob1[j];
    #pragma unroll
    for (int k = 0; k < 8; ++k) s += x[k] * ow1[k * 8 + j];
    o += fmaxf(s, 0.f) * ow2[j];
  }
  out[t] = o;
}

extern "C" void kernel_launch(void* const* d_in, const int* in_sizes, int n_in,
                              void* d_out, int out_size, void* d_ws, size_t ws_size,
                              hipStream_t stream) {
  const float* x      = (const float*)d_in[0];
  const float* cond   = (const float*)d_in[1];
  const float* pos    = (const float*)d_in[2];
  const int*   timei  = (const int*)  d_in[3];
  const int*   eidx   = (const int*)  d_in[4];
  const float* te_w1  = (const float*)d_in[5];
  const float* te_b1  = (const float*)d_in[6];
  const float* te_w2  = (const float*)d_in[7];
  const float* te_b2  = (const float*)d_in[8];
  const float* in_w1  = (const float*)d_in[9];
  const float* in_b1  = (const float*)d_in[10];
  const float* in_w2  = (const float*)d_in[11];
  const float* in_b2  = (const float*)d_in[12];
  const float* pos_w1 = (const float*)d_in[13];
  const float* pos_b1 = (const float*)d_in[14];
  const float* pos_w2 = (const float*)d_in[15];
  const float* pos_b2 = (const float*)d_in[16];
  const float* attn   = (const float*)d_in[17];
  const float* bt_w1  = (const float*)d_in[18];
  const float* bt_b1  = (const float*)d_in[19];
  const float* bt_w2  = (const float*)d_in[20];
  const float* bt_b2  = (const float*)d_in[21];
  const float* bc_w1  = (const float*)d_in[22];
  const float* bc_b1  = (const float*)d_in[23];
  const float* bc_w2  = (const float*)d_in[24];
  const float* bc_b2  = (const float*)d_in[25];
  const float* gn_w   = (const float*)d_in[26];
  const float* gn_b   = (const float*)d_in[27];
  const float* tn_w   = (const float*)d_in[28];
  const float* tn_b   = (const float*)d_in[29];
  const float* cv_w   = (const float*)d_in[30];
  const float* cv_b   = (const float*)d_in[31];
  const float* out_w1 = (const float*)d_in[32];
  const float* out_b1 = (const float*)d_in[33];
  const float* out_w2 = (const float*)d_in[34];
  const float* out_b2 = (const float*)d_in[35];
  float* out = (float*)d_out;

  const size_t HSZ = (size_t)Bv * Pv * Nv * Hv;  // 3,840,000
  float* ws    = (float*)d_ws;
  float* X     = ws;                 // h / v2 buffer (interleaved layout)
  float* Y     = X + HSZ;            // vt buffer (interleaved layout)
  float* acc   = Y + HSZ;            // interleaved layout
  float* posp  = acc + HSZ;          // Nv*Hv
  float* deg   = posp + Nv * Hv;     // Nv
  float* dinv  = deg + Nv;           // Nv
  float* epack = dinv + Nv;          // 2*Ev floats
  float* t_all = epack + 2 * Ev;     // NBv*Bv*Hv = 512
  float* a9    = t_all + NBv * Bv * Hv;  // 16
  float* stats = a9 + 16;            // NBv*2*NIMG*2 = 3072
  float* Gw    = stats + NBv * 2 * NIMG * 2;  // NBv*Nv*Hv
  float* Gb    = Gw + NBv * Nv * Hv;
  int* row_ptr = (int*)(Gb + NBv * Nv * Hv);  // Nv+8
  int* cursor  = row_ptr + Nv + 8;   // Nv+8

  k_setup<<<1, 64, 0, stream>>>(timei, attn, te_w1, te_b1, te_w2, te_b2,
                                bt_w1, bt_b1, bt_w2, bt_b2, t_all, a9);
  k_posp<<<(Nv + 255) / 256, 256, 0, stream>>>(pos, pos_w1, pos_b1, pos_w2, pos_b2, posp);
  k_zero<<<(Nv + 255) / 256, 256, 0, stream>>>(deg, cursor, stats);
  k_deg<<<(Ev + 255) / 256, 256, 0, stream>>>(eidx, deg);
  k_dinv<<<(Nv + 255) / 256, 256, 0, stream>>>(deg, dinv);
  k_scan<<<1, 1024, 0, stream>>>(deg, row_ptr);
  k_csr<<<(Ev + 255) / 256, 256, 0, stream>>>(eidx, dinv, row_ptr, cursor, (float2*)epack);
  k_gwb<<<(NBv * Nv + 255) / 256, 256, 0, stream>>>(
      row_ptr, (const float2*)epack, gn_w, gn_b, Gw, Gb);
  k_init<<<(Bv * Pv * Nv + 255) / 256, 256, 0, stream>>>(
      x, posp, in_w1, in_b1, in_w2, in_b2, a9, X, acc);

  for (int i = 0; i < NBv; ++i) {
    float* st1 = stats + (size_t)(i * 2 + 0) * NIMG * 2;
    float* st2 = stats + (size_t)(i * 2 + 1) * NIMG * 2;
    k_stage1<<<8 * 500, 256, 0, stream>>>(
        X, cond,
        bc_w1 + i * 64, bc_b1 + i * 8, bc_w2 + i * 64, bc_b2 + i * 8,
        gn_w + (size_t)i * Nv * Hv,
        Y, st1);
    k_stage2<<<8 * 500, 256, 0, stream>>>(
        Y, X, row_ptr, (const float2*)epack,
        Gw + (size_t)i * Nv * Hv, Gb + (size_t)i * Nv * Hv,
        st1, st2, t_all + i * Bv * Hv);
    k_stage3<<<8 * 40, 256, 0, stream>>>(
        X, acc, st2,
        tn_w + (size_t)i * Nv * Hv, tn_b + (size_t)i * Nv * Hv,
        cv_w + i * 144, cv_b + i * 12, a9, i);
  }
  k_out<<<(Bv * Pv * Nv + 255) / 256, 256, 0, stream>>>(
      acc, out_w1, out_b1, out_w2, out_b2, out);
}

// Round 14
// 619.795 us; speedup vs baseline: 1.7692x; 1.7692x over previous
//
#include <hip/hip_runtime.h>
#include <math.h>

#define Bv 8
#define Pv 12
#define Nv 5000
#define Hv 8
#define Ev 50000
#define NBv 8
#define TD1v 64
#define NIMG (Bv * Pv)          // 96 images
#define BLKS_PER_IMG 20         // ceil(5000/256)
#define ECAP 3072               // LDS edge-stage capacity (24 KB)
#define IPT2 2                  // images per thread in stage2

typedef float f4v __attribute__((ext_vector_type(4)));

__device__ inline float4 nt_load4(const float* p) {
  f4v v = __builtin_nontemporal_load((const f4v*)p);
  return make_float4(v.x, v.y, v.z, v.w);
}
__device__ inline void nt_store4(float* p, float a, float b, float c, float d) {
  f4v v = {a, b, c, d};
  __builtin_nontemporal_store(v, (f4v*)p);
}

// correctly-rounded f32 of 10^(d/4), d=0..15 (matches numpy float32 powf)
__device__ __constant__ float POW10Q[16] = {
  1.0f, 1.7782794100389228f, 3.1622776601683795f, 5.623413251903491f,
  10.0f, 17.78279410038923f, 31.622776601683793f, 56.23413251903491f,
  100.0f, 177.82794100389228f, 316.22776601683796f, 562.341325190349f,
  1000.0f, 1778.2794100389228f, 3162.2776601683795f, 5623.413251903491f
};

// ---------------- setup: time-embedding chain, per-block t vectors, softmax(attn)
__global__ void k_setup(const int* timei, const float* attn,
                        const float* te_w1, const float* te_b1,
                        const float* te_w2, const float* te_b2,
                        const float* bt_w1, const float* bt_b1,
                        const float* bt_w2, const float* bt_b2,
                        float* t_all, float* a9) {
  __shared__ float te0[Bv][32];
  __shared__ float te1[Bv][64];
  __shared__ float te2[Bv][64];
  int t = threadIdx.x; // 64 threads
  for (int idx = t; idx < Bv * 16; idx += 64) {
    int b = idx >> 4, d = idx & 15;
    float e = (float)timei[b] * POW10Q[d];
    te0[b][d]      = (float)sin((double)e);
    te0[b][d + 16] = (float)cos((double)e);
  }
  __syncthreads();
  for (int idx = t; idx < Bv * 64; idx += 64) {
    int b = idx >> 6, j = idx & 63;
    float s = te_b1[j];
    for (int k = 0; k < 32; ++k) s += te0[b][k] * te_w1[k * 64 + j];
    te1[b][j] = s / (1.0f + expf(-s));
  }
  __syncthreads();
  for (int idx = t; idx < Bv * 64; idx += 64) {
    int b = idx >> 6, j = idx & 63;
    float s = te_b2[j];
    for (int k = 0; k < 64; ++k) s += te1[b][k] * te_w2[k * 64 + j];
    te2[b][j] = s / (1.0f + expf(-s));
  }
  __syncthreads();
  {
    int i = t >> 3, b = t & 7;
    float u[Hv];
    for (int j = 0; j < Hv; ++j) {
      float s = bt_b1[i * Hv + j];
      for (int k = 0; k < TD1v; ++k) s += te2[b][k] * bt_w1[(i * TD1v + k) * Hv + j];
      u[j] = fmaxf(s, 0.0f);
    }
    for (int ch = 0; ch < Hv; ++ch) {
      float s = bt_b2[i * Hv + ch];
      for (int j = 0; j < Hv; ++j) s += u[j] * bt_w2[(i * Hv + j) * Hv + ch];
      t_all[(i * Bv + b) * Hv + ch] = s;
    }
  }
  if (t == 0) {
    float m = attn[0];
    for (int i = 1; i < 9; ++i) m = fmaxf(m, attn[i]);
    float s = 0.f, ex[9];
    for (int i = 0; i < 9; ++i) { ex[i] = expf(attn[i] - m); s += ex[i]; }
    for (int i = 0; i < 9; ++i) a9[i] = ex[i] / s;
  }
}

// ---------------- positional projection, once: posp[n][ch]
__global__ void k_posp(const float* pos, const float* pw1, const float* pb1,
                       const float* pw2, const float* pb2, float* posp) {
  int n = blockIdx.x * blockDim.x + threadIdx.x;
  if (n >= Nv) return;
  const float4* pr = (const float4*)(pos + (size_t)n * Hv);
  float4 r0 = pr[0], r1 = pr[1];
  float x[8] = {r0.x, r0.y, r0.z, r0.w, r1.x, r1.y, r1.z, r1.w};
  float u[8];
  #pragma unroll
  for (int j = 0; j < 8; ++j) {
    float s = pb1[j];
    #pragma unroll
    for (int k = 0; k < 8; ++k) s += x[k] * pw1[k * 8 + j];
    u[j] = fmaxf(s, 0.f);
  }
  float o[8];
  #pragma unroll
  for (int ch = 0; ch < 8; ++ch) {
    float s = pb2[ch];
    #pragma unroll
    for (int j = 0; j < 8; ++j) s += u[j] * pw2[j * 8 + ch];
    o[ch] = s;
  }
  float4* po = (float4*)(posp + (size_t)n * Hv);
  po[0] = make_float4(o[0], o[1], o[2], o[3]);
  po[1] = make_float4(o[4], o[5], o[6], o[7]);
}

// zero deg/cursor + all stats slots
__global__ void k_zero(float* deg, int* cursor, float* stats) {
  int i = blockIdx.x * blockDim.x + threadIdx.x;
  if (i < Nv) { deg[i] = 0.f; cursor[i] = 0; }
  if (i < NBv * 2 * NIMG * 2) stats[i] = 0.f;
}

__global__ void k_deg(const int* eidx, float* deg) {
  int e = blockIdx.x * blockDim.x + threadIdx.x;
  if (e < Ev) atomicAdd(&deg[eidx[Ev + e]], 1.0f);
}

__global__ void k_dinv(const float* deg, float* dinv) {
  int n = blockIdx.x * blockDim.x + threadIdx.x;
  if (n < Nv) {
    float d = deg[n];
    dinv[n] = d > 0.f ? (float)(1.0 / sqrt((double)d)) : 0.f;
  }
}

// single-block Hillis-Steele scan of per-dst counts -> row_ptr[0..Nv]
__global__ void k_scan(const float* deg, int* row_ptr) {
  __shared__ int buf[1024];
  __shared__ int base_s;
  int t = threadIdx.x;
  if (t == 0) { base_s = 0; row_ptr[0] = 0; }
  __syncthreads();
  for (int c = 0; c < 5; ++c) {
    int i = c * 1024 + t;
    int v = (i < Nv) ? (int)(deg[i] + 0.5f) : 0;
    buf[t] = v;
    __syncthreads();
    for (int off = 1; off < 1024; off <<= 1) {
      int add = (t >= off) ? buf[t - off] : 0;
      __syncthreads();
      buf[t] += add;
      __syncthreads();
    }
    int base = base_s;
    if (i < Nv) row_ptr[i + 1] = base + buf[t];
    __syncthreads();
    if (t == 1023) base_s = base + buf[1023];
    __syncthreads();
  }
}

// CSR fill: packed (src_bits, w) per edge
__global__ void k_csr(const int* eidx, const float* dinv, const int* row_ptr,
                      int* cursor, float2* epack) {
  int e = blockIdx.x * blockDim.x + threadIdx.x;
  if (e >= Ev) return;
  int s = eidx[e], d = eidx[Ev + e];
  int slot = atomicAdd(&cursor[d], 1);
  int pos = row_ptr[d] + slot;
  epack[pos] = make_float2(__int_as_float(s), dinv[s] * dinv[d]);
}

// ---------------- per block-iter, image-independent: Gw[i][n]=Σ w_e gnw_i[src], Gb likewise
__global__ __launch_bounds__(256) void k_gwb(
    const int* __restrict__ row_ptr, const float2* __restrict__ epack,
    const float* __restrict__ gn_w, const float* __restrict__ gn_b,
    float* __restrict__ Gw, float* __restrict__ Gb) {
  int id = blockIdx.x * 256 + threadIdx.x;
  if (id >= NBv * Nv) return;
  int i = id / Nv, n = id % Nv;
  const float* gw = gn_w + (size_t)i * Nv * Hv;
  const float* gb = gn_b + (size_t)i * Nv * Hv;
  float aw[8] = {0,0,0,0,0,0,0,0}, ab[8] = {0,0,0,0,0,0,0,0};
  int e0 = row_ptr[n], e1 = row_ptr[n + 1];
  for (int e = e0; e < e1; ++e) {
    float2 ep = epack[e];
    int s = __float_as_int(ep.x);
    float w = ep.y;
    const float4* wr = (const float4*)(gw + (size_t)s * Hv);
    const float4* br = (const float4*)(gb + (size_t)s * Hv);
    float4 w0 = wr[0], w1 = wr[1], b0 = br[0], b1 = br[1];
    aw[0] += w * w0.x; aw[1] += w * w0.y; aw[2] += w * w0.z; aw[3] += w * w0.w;
    aw[4] += w * w1.x; aw[5] += w * w1.y; aw[6] += w * w1.z; aw[7] += w * w1.w;
    ab[0] += w * b0.x; ab[1] += w * b0.y; ab[2] += w * b0.z; ab[3] += w * b0.w;
    ab[4] += w * b1.x; ab[5] += w * b1.y; ab[6] += w * b1.z; ab[7] += w * b1.w;
  }
  float4* wo = (float4*)(Gw + (size_t)id * Hv);
  wo[0] = make_float4(aw[0], aw[1], aw[2], aw[3]);
  wo[1] = make_float4(aw[4], aw[5], aw[6], aw[7]);
  float4* bo = (float4*)(Gb + (size_t)id * Hv);
  bo[0] = make_float4(ab[0], ab[1], ab[2], ab[3]);
  bo[1] = make_float4(ab[4], ab[5], ab[6], ab[7]);
}

// ---------------- h init: input proj + pos proj; acc = a0 * h
__global__ void k_init(const float* x, const float* posp,
                       const float* iw1, const float* ib1,
                       const float* iw2, const float* ib2,
                       const float* a9, float* hA, float* acc) {
  int t = blockIdx.x * blockDim.x + threadIdx.x;
  if (t >= Bv * Pv * Nv) return;
  float xv = __builtin_nontemporal_load(x + t);
  float u[8];
  #pragma unroll
  for (int j = 0; j < 8; ++j) u[j] = fmaxf(xv * iw1[j] + ib1[j], 0.f);
  int n = t % Nv;
  const float4* pp = (const float4*)(posp + (size_t)n * Hv);
  float4 p0 = pp[0], p1 = pp[1];
  float pv[8] = {p0.x, p0.y, p0.z, p0.w, p1.x, p1.y, p1.z, p1.w};
  float a0 = a9[0];
  float o[8];
  #pragma unroll
  for (int ch = 0; ch < 8; ++ch) {
    float s = ib2[ch];
    #pragma unroll
    for (int j = 0; j < 8; ++j) s += u[j] * iw2[j * 8 + ch];
    o[ch] = s + pv[ch];
  }
  float4* hr = (float4*)(hA + (size_t)t * Hv);
  hr[0] = make_float4(o[0], o[1], o[2], o[3]);
  hr[1] = make_float4(o[4], o[5], o[6], o[7]);
  nt_store4(acc + (size_t)t * Hv,     a0 * o[0], a0 * o[1], a0 * o[2], a0 * o[3]);
  nt_store4(acc + (size_t)t * Hv + 4, a0 * o[4], a0 * o[5], a0 * o[6], a0 * o[7]);
}

// block-level reduce of (s1,s2) over 256 threads, then one atomicAdd pair.
// Safe to call repeatedly (trailing barrier). ALL threads must call.
__device__ inline void partial_to_stats(float s1, float s2, float* stats_g) {
  #pragma unroll
  for (int off = 32; off > 0; off >>= 1) {
    s1 += __shfl_down(s1, off, 64);
    s2 += __shfl_down(s2, off, 64);
  }
  __shared__ float r1[4], r2[4];
  int wid = threadIdx.x >> 6, lane = threadIdx.x & 63;
  if (lane == 0) { r1[wid] = s1; r2[wid] = s2; }
  __syncthreads();
  if (threadIdx.x == 0) {
    float a = r1[0] + r1[1] + r1[2] + r1[3];
    float b = r2[0] + r2[1] + r2[2] + r2[3];
    atomicAdd(&stats_g[0], a);
    atomicAdd(&stats_g[1], b);
  }
  __syncthreads();
}

// XCD-locality swizzle: blockIdx%8 = XCD; image g = xcd*12 + local/20 (XCD x owns batch x)
__device__ inline void img_swizzle(int bx, int& g, int& chunk) {
  int xcd = bx & 7;
  int local = bx >> 3;
  g = xcd * 12 + local / BLKS_PER_IMG;
  chunk = local % BLKS_PER_IMG;
}

// ---------------- stage 1: v1 = h + proj(cond); write vt = gnw ⊙ v1; stats over v1
__global__ __launch_bounds__(256) void k_stage1(
    const float* __restrict__ h, const float* __restrict__ cond,
    const float* w1, const float* b1, const float* w2, const float* b2,
    const float* __restrict__ gnw,
    float* __restrict__ vt, float* stats1) {
  __shared__ float lw1[64], lw2[64], lb1[8], lb2[8];
  int t = threadIdx.x;
  if (t < 64) lw1[t] = w1[t];
  else if (t < 128) lw2[t - 64] = w2[t - 64];
  else if (t < 136) lb1[t - 128] = b1[t - 128];
  else if (t < 144) lb2[t - 136] = b2[t - 136];
  __syncthreads();
  int g, chunk;
  img_swizzle(blockIdx.x, g, chunk);
  int n = chunk * 256 + t;
  float s1 = 0.f, s2 = 0.f;
  if (n < Nv) {
    size_t row = ((size_t)g * Nv + n) * Hv;
    float4 c0 = nt_load4(cond + row);       // single-use stream: keep out of L2
    float4 c1 = nt_load4(cond + row + 4);
    float xc[8] = {c0.x, c0.y, c0.z, c0.w, c1.x, c1.y, c1.z, c1.w};
    float u[8];
    #pragma unroll
    for (int j = 0; j < 8; ++j) {
      float s = lb1[j];
      #pragma unroll
      for (int k = 0; k < 8; ++k) s += xc[k] * lw1[k * 8 + j];
      u[j] = fmaxf(s, 0.f);
    }
    const float4* hr = (const float4*)(h + row);
    float4 h0 = hr[0], h1 = hr[1];
    float hv[8] = {h0.x, h0.y, h0.z, h0.w, h1.x, h1.y, h1.z, h1.w};
    const float4* gr = (const float4*)(gnw + (size_t)n * Hv);
    float4 g0 = gr[0], g1 = gr[1];
    float gv[8] = {g0.x, g0.y, g0.z, g0.w, g1.x, g1.y, g1.z, g1.w};
    float o[8];
    #pragma unroll
    for (int ch = 0; ch < 8; ++ch) {
      float s = lb2[ch];
      #pragma unroll
      for (int j = 0; j < 8; ++j) s += u[j] * lw2[j * 8 + ch];
      float val = s + hv[ch];
      s1 += val; s2 += val * val;
      o[ch] = val * gv[ch];          // pre-scale by gn_w for the SpMM
    }
    float4* vo = (float4*)(vt + row);     // gather target: keep IN L2 (normal store)
    vo[0] = make_float4(o[0], o[1], o[2], o[3]);
    vo[1] = make_float4(o[4], o[5], o[6], o[7]);
  }
  partial_to_stats(s1, s2, stats1 + (size_t)g * 2);
}

// ---------------- stage 2: v2 = rstd*SpMM(vt) - mean*rstd*Gw + Gb + t; stats2
// IPT2=2 images/thread: grid 8 (xcd=b) * 6 (pair) * 20 (chunk) = 960 blocks.
// Edge slice staged in LDS; inner loop: 2 edges x 2 images = 4 loads in flight.
__global__ __launch_bounds__(256) void k_stage2(
    const float* __restrict__ vt, float* __restrict__ v2,
    const int* __restrict__ row_ptr, const float2* __restrict__ epack,
    const float* __restrict__ Gw, const float* __restrict__ Gb,
    const float* __restrict__ stats1, float* stats2,
    const float* __restrict__ tvec) {
  __shared__ float2 se[ECAP];
  int t = threadIdx.x;
  int b = blockIdx.x & 7;
  int local = blockIdx.x >> 3;
  int pair = local % 6;
  int chunk = local / 6;
  int g0 = b * Pv + pair * IPT2;
  int nb0 = chunk * 256;
  int nb1 = nb0 + 256; if (nb1 > Nv) nb1 = Nv;
  int eb0 = row_ptr[nb0];
  int eb1 = row_ptr[nb1];
  int cnt = eb1 - eb0;
  const float2* eps;
  int ebase;
  if (cnt <= ECAP) {
    for (int k = t; k < cnt; k += 256) se[k] = epack[eb0 + k];
    eps = se; ebase = eb0;
  } else {
    eps = epack; ebase = 0;
  }
  __syncthreads();
  float mean[IPT2], rstd[IPT2], mrs[IPT2];
  #pragma unroll
  for (int j = 0; j < IPT2; ++j) {
    float m  = stats1[(g0 + j) * 2]     * (1.f / 40000.f);
    float m2 = stats1[(g0 + j) * 2 + 1] * (1.f / 40000.f);
    float var = m2 - m * m;
    mean[j] = m;
    rstd[j] = (float)(1.0 / sqrt((double)var + 1e-5));
    mrs[j]  = m * rstd[j];
  }
  int n = nb0 + t;
  float s1a[IPT2], s2a[IPT2];
  #pragma unroll
  for (int j = 0; j < IPT2; ++j) { s1a[j] = 0.f; s2a[j] = 0.f; }
  if (n < Nv) {
    const float* vt0 = vt + (size_t)(g0 + 0) * Nv * Hv;
    const float* vt1 = vt + (size_t)(g0 + 1) * Nv * Hv;
    float a[IPT2][8];
    #pragma unroll
    for (int j = 0; j < IPT2; ++j)
      #pragma unroll
      for (int ch = 0; ch < 8; ++ch) a[j][ch] = 0.f;
    int e0 = row_ptr[n] - ebase, e1 = row_ptr[n + 1] - ebase;
    int e = e0;
    for (; e + 2 <= e1; e += 2) {
      float2 p0 = eps[e], p1 = eps[e + 1];
      size_t so0 = (size_t)__float_as_int(p0.x) * Hv;
      size_t so1 = (size_t)__float_as_int(p1.x) * Hv;
      const float4* r00 = (const float4*)(vt0 + so0);
      const float4* r01 = (const float4*)(vt1 + so0);
      const float4* r10 = (const float4*)(vt0 + so1);
      const float4* r11 = (const float4*)(vt1 + so1);
      float4 x00a = r00[0], x00b = r00[1];
      float4 x01a = r01[0], x01b = r01[1];
      float4 x10a = r10[0], x10b = r10[1];
      float4 x11a = r11[0], x11b = r11[1];
      a[0][0] += p0.y*x00a.x + p1.y*x10a.x;
      a[0][1] += p0.y*x00a.y + p1.y*x10a.y;
      a[0][2] += p0.y*x00a.z + p1.y*x10a.z;
      a[0][3] += p0.y*x00a.w + p1.y*x10a.w;
      a[0][4] += p0.y*x00b.x + p1.y*x10b.x;
      a[0][5] += p0.y*x00b.y + p1.y*x10b.y;
      a[0][6] += p0.y*x00b.z + p1.y*x10b.z;
      a[0][7] += p0.y*x00b.w + p1.y*x10b.w;
      a[1][0] += p0.y*x01a.x + p1.y*x11a.x;
      a[1][1] += p0.y*x01a.y + p1.y*x11a.y;
      a[1][2] += p0.y*x01a.z + p1.y*x11a.z;
      a[1][3] += p0.y*x01a.w + p1.y*x11a.w;
      a[1][4] += p0.y*x01b.x + p1.y*x11b.x;
      a[1][5] += p0.y*x01b.y + p1.y*x11b.y;
      a[1][6] += p0.y*x01b.z + p1.y*x11b.z;
      a[1][7] += p0.y*x01b.w + p1.y*x11b.w;
    }
    for (; e < e1; ++e) {
      float2 ep = eps[e];
      float w = ep.y;
      size_t so = (size_t)__float_as_int(ep.x) * Hv;
      const float4* r0 = (const float4*)(vt0 + so);
      const float4* r1 = (const float4*)(vt1 + so);
      float4 xa = r0[0], xb = r0[1];
      float4 ya = r1[0], yb = r1[1];
      a[0][0] += w*xa.x; a[0][1] += w*xa.y; a[0][2] += w*xa.z; a[0][3] += w*xa.w;
      a[0][4] += w*xb.x; a[0][5] += w*xb.y; a[0][6] += w*xb.z; a[0][7] += w*xb.w;
      a[1][0] += w*ya.x; a[1][1] += w*ya.y; a[1][2] += w*ya.z; a[1][3] += w*ya.w;
      a[1][4] += w*yb.x; a[1][5] += w*yb.y; a[1][6] += w*yb.z; a[1][7] += w*yb.w;
    }
    size_t noff = (size_t)n * Hv;
    const float4* wr = (const float4*)(Gw + noff);
    const float4* br = (const float4*)(Gb + noff);
    float4 w0 = wr[0], w1 = wr[1], b0 = br[0], b1 = br[1];
    float gw8[8] = {w0.x, w0.y, w0.z, w0.w, w1.x, w1.y, w1.z, w1.w};
    float gb8[8] = {b0.x, b0.y, b0.z, b0.w, b1.x, b1.y, b1.z, b1.w};
    float tl[8];
    {
      const float4* tr = (const float4*)(tvec + b * Hv);
      float4 t0 = tr[0], t1 = tr[1];
      tl[0] = t0.x; tl[1] = t0.y; tl[2] = t0.z; tl[3] = t0.w;
      tl[4] = t1.x; tl[5] = t1.y; tl[6] = t1.z; tl[7] = t1.w;
    }
    #pragma unroll
    for (int j = 0; j < IPT2; ++j) {
      float o[8];
      #pragma unroll
      for (int ch = 0; ch < 8; ++ch) {
        float val = rstd[j] * a[j][ch] - mrs[j] * gw8[ch] + gb8[ch] + tl[ch];
        o[ch] = val;
        s1a[j] += val; s2a[j] += val * val;
      }
      float* vo = v2 + (size_t)(g0 + j) * Nv * Hv + noff;
      nt_store4(vo,     o[0], o[1], o[2], o[3]);
      nt_store4(vo + 4, o[4], o[5], o[6], o[7]);
    }
  }
  #pragma unroll
  for (int j = 0; j < IPT2; ++j)
    partial_to_stats(s1a[j], s2a[j], stats2 + (size_t)(g0 + j) * 2);
}

// ---------------- stage 3: LN(v2) on-the-fly + 12x12 conv over P (in-place) + skip acc
// 1D grid 320 blocks: b = blockIdx%8 (keeps batch b on XCD b), chunk = blockIdx/8
__global__ __launch_bounds__(256) void k_stage3(
    float* __restrict__ v2, float* __restrict__ acc,
    const float* __restrict__ stats2,
    const float* __restrict__ tnw, const float* __restrict__ tnb,
    const float* __restrict__ cw, const float* __restrict__ cb,
    const float* __restrict__ a9, int iblk) {
  __shared__ float scw[144], scb[12], smean[12], srstd[12];
  int t = threadIdx.x;
  int b = blockIdx.x & 7;
  int chunk = blockIdx.x >> 3;
  if (t < 144) scw[t] = cw[t];
  else if (t < 156) scb[t - 144] = cb[t - 144];
  else if (t < 168) {
    int p = t - 156;
    int g = b * Pv + p;
    float mean = stats2[g * 2]     * (1.f / 40000.f);
    float m2   = stats2[g * 2 + 1] * (1.f / 40000.f);
    float var  = m2 - mean * mean;
    smean[p] = mean;
    srstd[p] = (float)(1.0 / sqrt((double)var + 1e-5));
  }
  __syncthreads();
  int idx = chunk * 256 + t;
  if (idx >= Nv * 2) return;
  int n = idx >> 1, c4 = idx & 1;
  size_t noff = (size_t)n * Hv + c4 * 4;
  const float4 w4 = nt_load4(tnw + noff);   // single-use per XCD
  const float4 b4 = nt_load4(tnb + noff);
  size_t strideP = (size_t)Nv * Hv;
  size_t base = (size_t)b * Pv * strideP + noff;
  float4 in[12];
  #pragma unroll
  for (int p = 0; p < 12; ++p) {
    float4 v = nt_load4(v2 + base + p * strideP);  // dead after this read
    float mean = smean[p], rstd = srstd[p];
    in[p].x = (v.x - mean) * rstd * w4.x + b4.x;
    in[p].y = (v.y - mean) * rstd * w4.y + b4.y;
    in[p].z = (v.z - mean) * rstd * w4.z + b4.z;
    in[p].w = (v.w - mean) * rstd * w4.w + b4.w;
  }
  float ai = a9[iblk + 1];
  #pragma unroll
  for (int q = 0; q < 12; ++q) {
    float4 o = make_float4(scb[q], scb[q], scb[q], scb[q]);
    #pragma unroll
    for (int p = 0; p < 12; ++p) {
      float c = scw[q * 12 + p];
      o.x += c * in[p].x; o.y += c * in[p].y;
      o.z += c * in[p].z; o.w += c * in[p].w;
    }
    size_t off = base + q * strideP;
    *(float4*)(v2 + off) = o;        // live: next stage1 reads it -> keep in L2
    float4 av = nt_load4(acc + off); // acc: streaming RMW, keep out of L2
    nt_store4(acc + off, av.x + ai * o.x, av.y + ai * o.y,
                         av.z + ai * o.z, av.w + ai * o.w);
  }
}

// ---------------- output projection
__global__ void k_out(const float* acc, const float* ow1, const float* ob1,
                      const float* ow2, const float* ob2, float* out) {
  int t = blockIdx.x * blockDim.x + threadIdx.x;
  if (t >= Bv * Pv * Nv) return;
  float4 a0 = nt_load4(acc + (size_t)t * Hv);
  float4 a1 = nt_load4(acc + (size_t)t * Hv + 4);
  float x[8] = {a0.x, a0.y, a0.z, a0.w, a1.x, a1.y, a1.z, a1.w};
  float o = ob2[0];
  #pragma unroll
  for (int j = 0; j < 8; ++j) {
    float s = ob1[j];
    #pragma unroll
    for (int k = 0; k < 8; ++k) s += x[k] * ow1[k * 8 + j];
    o += fmaxf(s, 0.f) * ow2[j];
  }
  out[t] = o;
}

extern "C" void kernel_launch(void* const* d_in, const int* in_sizes, int n_in,
                              void* d_out, int out_size, void* d_ws, size_t ws_size,
                              hipStream_t stream) {
  const float* x      = (const float*)d_in[0];
  const float* cond   = (const float*)d_in[1];
  const float* pos    = (const float*)d_in[2];
  const int*   timei  = (const int*)  d_in[3];
  const int*   eidx   = (const int*)  d_in[4];
  const float* te_w1  = (const float*)d_in[5];
  const float* te_b1  = (const float*)d_in[6];
  const float* te_w2  = (const float*)d_in[7];
  const float* te_b2  = (const float*)d_in[8];
  const float* in_w1  = (const float*)d_in[9];
  const float* in_b1  = (const float*)d_in[10];
  const float* in_w2  = (const float*)d_in[11];
  const float* in_b2  = (const float*)d_in[12];
  const float* pos_w1 = (const float*)d_in[13];
  const float* pos_b1 = (const float*)d_in[14];
  const float* pos_w2 = (const float*)d_in[15];
  const float* pos_b2 = (const float*)d_in[16];
  const float* attn   = (const float*)d_in[17];
  const float* bt_w1  = (const float*)d_in[18];
  const float* bt_b1  = (const float*)d_in[19];
  const float* bt_w2  = (const float*)d_in[20];
  const float* bt_b2  = (const float*)d_in[21];
  const float* bc_w1  = (const float*)d_in[22];
  const float* bc_b1  = (const float*)d_in[23];
  const float* bc_w2  = (const float*)d_in[24];
  const float* bc_b2  = (const float*)d_in[25];
  const float* gn_w   = (const float*)d_in[26];
  const float* gn_b   = (const float*)d_in[27];
  const float* tn_w   = (const float*)d_in[28];
  const float* tn_b   = (const float*)d_in[29];
  const float* cv_w   = (const float*)d_in[30];
  const float* cv_b   = (const float*)d_in[31];
  const float* out_w1 = (const float*)d_in[32];
  const float* out_b1 = (const float*)d_in[33];
  const float* out_w2 = (const float*)d_in[34];
  const float* out_b2 = (const float*)d_in[35];
  float* out = (float*)d_out;

  const size_t HSZ = (size_t)Bv * Pv * Nv * Hv;  // 3,840,000
  float* ws    = (float*)d_ws;
  float* X     = ws;                 // h / v2 buffer
  float* Y     = X + HSZ;            // vt (= gnw ⊙ v1) buffer
  float* acc   = Y + HSZ;
  float* posp  = acc + HSZ;          // Nv*Hv
  float* deg   = posp + Nv * Hv;     // Nv
  float* dinv  = deg + Nv;           // Nv
  float* epack = dinv + Nv;          // 2*Ev floats
  float* t_all = epack + 2 * Ev;     // NBv*Bv*Hv = 512
  float* a9    = t_all + NBv * Bv * Hv;  // 16
  float* stats = a9 + 16;            // NBv*2*NIMG*2 = 3072
  float* Gw    = stats + NBv * 2 * NIMG * 2;  // NBv*Nv*Hv = 320000
  float* Gb    = Gw + NBv * Nv * Hv;          // 320000
  int* row_ptr = (int*)(Gb + NBv * Nv * Hv);  // Nv+8
  int* cursor  = row_ptr + Nv + 8;   // Nv+8

  k_setup<<<1, 64, 0, stream>>>(timei, attn, te_w1, te_b1, te_w2, te_b2,
                                bt_w1, bt_b1, bt_w2, bt_b2, t_all, a9);
  k_posp<<<(Nv + 255) / 256, 256, 0, stream>>>(pos, pos_w1, pos_b1, pos_w2, pos_b2, posp);
  k_zero<<<(Nv + 255) / 256, 256, 0, stream>>>(deg, cursor, stats);
  k_deg<<<(Ev + 255) / 256, 256, 0, stream>>>(eidx, deg);
  k_dinv<<<(Nv + 255) / 256, 256, 0, stream>>>(deg, dinv);
  k_scan<<<1, 1024, 0, stream>>>(deg, row_ptr);
  k_csr<<<(Ev + 255) / 256, 256, 0, stream>>>(eidx, dinv, row_ptr, cursor, (float2*)epack);
  k_gwb<<<(NBv * Nv + 255) / 256, 256, 0, stream>>>(
      row_ptr, (const float2*)epack, gn_w, gn_b, Gw, Gb);
  k_init<<<(Bv * Pv * Nv + 255) / 256, 256, 0, stream>>>(
      x, posp, in_w1, in_b1, in_w2, in_b2, a9, X, acc);

  for (int i = 0; i < NBv; ++i) {
    float* st1 = stats + (size_t)(i * 2 + 0) * NIMG * 2;
    float* st2 = stats + (size_t)(i * 2 + 1) * NIMG * 2;
    k_stage1<<<NIMG * BLKS_PER_IMG, 256, 0, stream>>>(
        X, cond,
        bc_w1 + i * 64, bc_b1 + i * 8, bc_w2 + i * 64, bc_b2 + i * 8,
        gn_w + (size_t)i * Nv * Hv,
        Y, st1);
    k_stage2<<<8 * 6 * BLKS_PER_IMG, 256, 0, stream>>>(
        Y, X, row_ptr, (const float2*)epack,
        Gw + (size_t)i * Nv * Hv, Gb + (size_t)i * Nv * Hv,
        st1, st2, t_all + i * Bv * Hv);
    k_stage3<<<8 * 40, 256, 0, stream>>>(
        X, acc, st2,
        tn_w + (size_t)i * Nv * Hv, tn_b + (size_t)i * Nv * Hv,
        cv_w + i * 144, cv_b + i * 12, a9, i);
  }
  k_out<<<(Bv * Pv * Nv + 255) / 256, 256, 0, stream>>>(
      acc, out_w1, out_b1, out_w2, out_b2, out);
}

// Round 15
// 598.155 us; speedup vs baseline: 1.8332x; 1.0362x over previous
//
#include <hip/hip_runtime.h>
#include <math.h>

#define Bv 8
#define Pv 12
#define Nv 5000
#define Hv 8
#define Ev 50000
#define NBv 8
#define TD1v 64
#define NIMG (Bv * Pv)          // 96 images
#define BLKS_PER_IMG 20         // ceil(5000/256)
#define ECAP 3072               // LDS edge-stage capacity (24 KB)
#define IPT2 2                  // images per thread in stage2

typedef float f4v __attribute__((ext_vector_type(4)));

__device__ inline float4 nt_load4(const float* p) {
  f4v v = __builtin_nontemporal_load((const f4v*)p);
  return make_float4(v.x, v.y, v.z, v.w);
}
__device__ inline void nt_store4(float* p, float a, float b, float c, float d) {
  f4v v = {a, b, c, d};
  __builtin_nontemporal_store(v, (f4v*)p);
}

// correctly-rounded f32 of 10^(d/4), d=0..15 (matches numpy float32 powf)
__device__ __constant__ float POW10Q[16] = {
  1.0f, 1.7782794100389228f, 3.1622776601683795f, 5.623413251903491f,
  10.0f, 17.78279410038923f, 31.622776601683793f, 56.23413251903491f,
  100.0f, 177.82794100389228f, 316.22776601683796f, 562.341325190349f,
  1000.0f, 1778.2794100389228f, 3162.2776601683795f, 5623.413251903491f
};

// ---------------- setup (512 threads): time-embedding chain, t vectors, softmax(attn)
__global__ __launch_bounds__(512) void k_setup(
    const int* timei, const float* attn,
    const float* te_w1, const float* te_b1,
    const float* te_w2, const float* te_b2,
    const float* bt_w1, const float* bt_b1,
    const float* bt_w2, const float* bt_b2,
    float* t_all, float* a9) {
  __shared__ float te0[Bv][32];
  __shared__ float te1[Bv][64];
  __shared__ float te2[Bv][64];
  __shared__ float su[64][8];
  int t = threadIdx.x; // 512
  if (t < 256) {
    int b = t >> 5, k = t & 31;
    int d = k & 15;
    float e = (float)timei[b] * POW10Q[d];   // f32 rounding as in numpy
    te0[b][k] = (k < 16) ? (float)sin((double)e) : (float)cos((double)e);
  }
  __syncthreads();
  {
    int b = t >> 6, j = t & 63;   // 512 outputs
    float s = te_b1[j];
    for (int k = 0; k < 32; ++k) s += te0[b][k] * te_w1[k * 64 + j];
    te1[b][j] = s / (1.0f + expf(-s));       // silu
  }
  __syncthreads();
  {
    int b = t >> 6, j = t & 63;
    float s = te_b2[j];
    for (int k = 0; k < 64; ++k) s += te1[b][k] * te_w2[k * 64 + j];
    te2[b][j] = s / (1.0f + expf(-s));
  }
  __syncthreads();
  {
    int ib = t >> 3, j = t & 7;   // ib = i*8+b, 64 pairs x 8 hidden
    int i = ib >> 3, b = ib & 7;
    float s = bt_b1[i * Hv + j];
    for (int k = 0; k < TD1v; ++k) s += te2[b][k] * bt_w1[(i * TD1v + k) * Hv + j];
    su[ib][j] = fmaxf(s, 0.0f);
  }
  __syncthreads();
  {
    int ib = t >> 3, ch = t & 7;
    int i = ib >> 3, b = ib & 7;
    float s = bt_b2[i * Hv + ch];
    #pragma unroll
    for (int j = 0; j < 8; ++j) s += su[ib][j] * bt_w2[(i * Hv + j) * Hv + ch];
    t_all[(i * Bv + b) * Hv + ch] = s;
  }
  if (t == 0) {
    float m = attn[0];
    for (int i = 1; i < 9; ++i) m = fmaxf(m, attn[i]);
    float s = 0.f, ex[9];
    for (int i = 0; i < 9; ++i) { ex[i] = expf(attn[i] - m); s += ex[i]; }
    for (int i = 0; i < 9; ++i) a9[i] = ex[i] / s;
  }
}

// ---------------- positional projection, once: posp[n][ch]
__global__ void k_posp(const float* pos, const float* pw1, const float* pb1,
                       const float* pw2, const float* pb2, float* posp) {
  int n = blockIdx.x * blockDim.x + threadIdx.x;
  if (n >= Nv) return;
  const float4* pr = (const float4*)(pos + (size_t)n * Hv);
  float4 r0 = pr[0], r1 = pr[1];
  float x[8] = {r0.x, r0.y, r0.z, r0.w, r1.x, r1.y, r1.z, r1.w};
  float u[8];
  #pragma unroll
  for (int j = 0; j < 8; ++j) {
    float s = pb1[j];
    #pragma unroll
    for (int k = 0; k < 8; ++k) s += x[k] * pw1[k * 8 + j];
    u[j] = fmaxf(s, 0.f);
  }
  float o[8];
  #pragma unroll
  for (int ch = 0; ch < 8; ++ch) {
    float s = pb2[ch];
    #pragma unroll
    for (int j = 0; j < 8; ++j) s += u[j] * pw2[j * 8 + ch];
    o[ch] = s;
  }
  float4* po = (float4*)(posp + (size_t)n * Hv);
  po[0] = make_float4(o[0], o[1], o[2], o[3]);
  po[1] = make_float4(o[4], o[5], o[6], o[7]);
}

// zero deg/cursor + all stats slots
__global__ void k_zero(float* deg, int* cursor, float* stats) {
  int i = blockIdx.x * blockDim.x + threadIdx.x;
  if (i < Nv) { deg[i] = 0.f; cursor[i] = 0; }
  if (i < NBv * 2 * NIMG * 2) stats[i] = 0.f;
}

__global__ void k_deg(const int* eidx, float* deg) {
  int e = blockIdx.x * blockDim.x + threadIdx.x;
  if (e < Ev) atomicAdd(&deg[eidx[Ev + e]], 1.0f);
}

__global__ void k_dinv(const float* deg, float* dinv) {
  int n = blockIdx.x * blockDim.x + threadIdx.x;
  if (n < Nv) {
    float d = deg[n];
    dinv[n] = d > 0.f ? (float)(1.0 / sqrt((double)d)) : 0.f;
  }
}

// single-block Hillis-Steele scan of per-dst counts -> row_ptr[0..Nv]
__global__ void k_scan(const float* deg, int* row_ptr) {
  __shared__ int buf[1024];
  __shared__ int base_s;
  int t = threadIdx.x;
  if (t == 0) { base_s = 0; row_ptr[0] = 0; }
  __syncthreads();
  for (int c = 0; c < 5; ++c) {
    int i = c * 1024 + t;
    int v = (i < Nv) ? (int)(deg[i] + 0.5f) : 0;
    buf[t] = v;
    __syncthreads();
    for (int off = 1; off < 1024; off <<= 1) {
      int add = (t >= off) ? buf[t - off] : 0;
      __syncthreads();
      buf[t] += add;
      __syncthreads();
    }
    int base = base_s;
    if (i < Nv) row_ptr[i + 1] = base + buf[t];
    __syncthreads();
    if (t == 1023) base_s = base + buf[1023];
    __syncthreads();
  }
}

// CSR fill: packed (src_bits, w) per edge
__global__ void k_csr(const int* eidx, const float* dinv, const int* row_ptr,
                      int* cursor, float2* epack) {
  int e = blockIdx.x * blockDim.x + threadIdx.x;
  if (e >= Ev) return;
  int s = eidx[e], d = eidx[Ev + e];
  int slot = atomicAdd(&cursor[d], 1);
  int pos = row_ptr[d] + slot;
  epack[pos] = make_float2(__int_as_float(s), dinv[s] * dinv[d]);
}

// ---------------- per block-iter, image-independent: Gw[i][n]=Σ w_e gnw_i[src], Gb likewise
__global__ __launch_bounds__(256) void k_gwb(
    const int* __restrict__ row_ptr, const float2* __restrict__ epack,
    const float* __restrict__ gn_w, const float* __restrict__ gn_b,
    float* __restrict__ Gw, float* __restrict__ Gb) {
  int id = blockIdx.x * 256 + threadIdx.x;
  if (id >= NBv * Nv) return;
  int i = id / Nv, n = id % Nv;
  const float* gw = gn_w + (size_t)i * Nv * Hv;
  const float* gb = gn_b + (size_t)i * Nv * Hv;
  float aw[8] = {0,0,0,0,0,0,0,0}, ab[8] = {0,0,0,0,0,0,0,0};
  int e0 = row_ptr[n], e1 = row_ptr[n + 1];
  for (int e = e0; e < e1; ++e) {
    float2 ep = epack[e];
    int s = __float_as_int(ep.x);
    float w = ep.y;
    const float4* wr = (const float4*)(gw + (size_t)s * Hv);
    const float4* br = (const float4*)(gb + (size_t)s * Hv);
    float4 w0 = wr[0], w1 = wr[1], b0 = br[0], b1 = br[1];
    aw[0] += w * w0.x; aw[1] += w * w0.y; aw[2] += w * w0.z; aw[3] += w * w0.w;
    aw[4] += w * w1.x; aw[5] += w * w1.y; aw[6] += w * w1.z; aw[7] += w * w1.w;
    ab[0] += w * b0.x; ab[1] += w * b0.y; ab[2] += w * b0.z; ab[3] += w * b0.w;
    ab[4] += w * b1.x; ab[5] += w * b1.y; ab[6] += w * b1.z; ab[7] += w * b1.w;
  }
  float4* wo = (float4*)(Gw + (size_t)id * Hv);
  wo[0] = make_float4(aw[0], aw[1], aw[2], aw[3]);
  wo[1] = make_float4(aw[4], aw[5], aw[6], aw[7]);
  float4* bo = (float4*)(Gb + (size_t)id * Hv);
  bo[0] = make_float4(ab[0], ab[1], ab[2], ab[3]);
  bo[1] = make_float4(ab[4], ab[5], ab[6], ab[7]);
}

// block-level reduce of (s1,s2) over 256 threads, then one atomicAdd pair.
// Safe to call repeatedly (trailing barrier). ALL threads must call.
__device__ inline void partial_to_stats(float s1, float s2, float* stats_g) {
  #pragma unroll
  for (int off = 32; off > 0; off >>= 1) {
    s1 += __shfl_down(s1, off, 64);
    s2 += __shfl_down(s2, off, 64);
  }
  __shared__ float r1[4], r2[4];
  int wid = threadIdx.x >> 6, lane = threadIdx.x & 63;
  if (lane == 0) { r1[wid] = s1; r2[wid] = s2; }
  __syncthreads();
  if (threadIdx.x == 0) {
    float a = r1[0] + r1[1] + r1[2] + r1[3];
    float b = r2[0] + r2[1] + r2[2] + r2[3];
    atomicAdd(&stats_g[0], a);
    atomicAdd(&stats_g[1], b);
  }
  __syncthreads();
}

// XCD-locality swizzle: blockIdx%8 = XCD; image g = xcd*12 + local/20 (XCD x owns batch x)
__device__ inline void img_swizzle(int bx, int& g, int& chunk) {
  int xcd = bx & 7;
  int local = bx >> 3;
  g = xcd * 12 + local / BLKS_PER_IMG;
  chunk = local % BLKS_PER_IMG;
}

// ---------------- stage 1 (i>=1): v1 = h + proj(cond); vt = gnw ⊙ v1; stats over v1
__global__ __launch_bounds__(256) void k_stage1(
    const float* __restrict__ h, const float* __restrict__ cond,
    const float* w1, const float* b1, const float* w2, const float* b2,
    const float* __restrict__ gnw,
    float* __restrict__ vt, float* stats1) {
  __shared__ float lw1[64], lw2[64], lb1[8], lb2[8];
  int t = threadIdx.x;
  if (t < 64) lw1[t] = w1[t];
  else if (t < 128) lw2[t - 64] = w2[t - 64];
  else if (t < 136) lb1[t - 128] = b1[t - 128];
  else if (t < 144) lb2[t - 136] = b2[t - 136];
  __syncthreads();
  int g, chunk;
  img_swizzle(blockIdx.x, g, chunk);
  int n = chunk * 256 + t;
  float s1 = 0.f, s2 = 0.f;
  if (n < Nv) {
    size_t row = ((size_t)g * Nv + n) * Hv;
    float4 c0 = nt_load4(cond + row);
    float4 c1 = nt_load4(cond + row + 4);
    float xc[8] = {c0.x, c0.y, c0.z, c0.w, c1.x, c1.y, c1.z, c1.w};
    float u[8];
    #pragma unroll
    for (int j = 0; j < 8; ++j) {
      float s = lb1[j];
      #pragma unroll
      for (int k = 0; k < 8; ++k) s += xc[k] * lw1[k * 8 + j];
      u[j] = fmaxf(s, 0.f);
    }
    const float4* hr = (const float4*)(h + row);
    float4 h0 = hr[0], h1 = hr[1];
    float hv[8] = {h0.x, h0.y, h0.z, h0.w, h1.x, h1.y, h1.z, h1.w};
    const float4* gr = (const float4*)(gnw + (size_t)n * Hv);
    float4 g0 = gr[0], g1 = gr[1];
    float gv[8] = {g0.x, g0.y, g0.z, g0.w, g1.x, g1.y, g1.z, g1.w};
    float o[8];
    #pragma unroll
    for (int ch = 0; ch < 8; ++ch) {
      float s = lb2[ch];
      #pragma unroll
      for (int j = 0; j < 8; ++j) s += u[j] * lw2[j * 8 + ch];
      float val = s + hv[ch];
      s1 += val; s2 += val * val;
      o[ch] = val * gv[ch];
    }
    float4* vo = (float4*)(vt + row);
    vo[0] = make_float4(o[0], o[1], o[2], o[3]);
    vo[1] = make_float4(o[4], o[5], o[6], o[7]);
  }
  partial_to_stats(s1, s2, stats1 + (size_t)g * 2);
}

// ---------------- fused k_init + stage1 for i=0: h computed in-registers from x/posp
__global__ __launch_bounds__(256) void k_stage1_init(
    const float* __restrict__ x, const float* __restrict__ posp,
    const float* iw1, const float* ib1, const float* iw2, const float* ib2,
    const float* __restrict__ cond,
    const float* w1, const float* b1, const float* w2, const float* b2,
    const float* __restrict__ gnw, const float* __restrict__ a9,
    float* __restrict__ acc,
    float* __restrict__ vt, float* stats1) {
  __shared__ float lw1[64], lw2[64], lb1[8], lb2[8];
  __shared__ float li1[8], li2[64], lib1[8], lib2[8];
  int t = threadIdx.x;
  if (t < 64) lw1[t] = w1[t];
  else if (t < 128) lw2[t - 64] = w2[t - 64];
  else if (t < 136) lb1[t - 128] = b1[t - 128];
  else if (t < 144) lb2[t - 136] = b2[t - 136];
  else if (t < 152) li1[t - 144] = iw1[t - 144];
  else if (t < 216) li2[t - 152] = iw2[t - 152];
  else if (t < 224) lib1[t - 216] = ib1[t - 216];
  else if (t < 232) lib2[t - 224] = ib2[t - 224];
  __syncthreads();
  int g, chunk;
  img_swizzle(blockIdx.x, g, chunk);
  int n = chunk * 256 + t;
  float s1 = 0.f, s2 = 0.f;
  if (n < Nv) {
    size_t row = ((size_t)g * Nv + n) * Hv;
    // ---- h = proj_in(x) + posp[n]
    float xv = __builtin_nontemporal_load(x + (size_t)g * Nv + n);
    float ui[8];
    #pragma unroll
    for (int j = 0; j < 8; ++j) ui[j] = fmaxf(xv * li1[j] + lib1[j], 0.f);
    const float4* pp = (const float4*)(posp + (size_t)n * Hv);
    float4 p0 = pp[0], p1 = pp[1];
    float pv[8] = {p0.x, p0.y, p0.z, p0.w, p1.x, p1.y, p1.z, p1.w};
    float hv[8];
    #pragma unroll
    for (int ch = 0; ch < 8; ++ch) {
      float s = lib2[ch];
      #pragma unroll
      for (int j = 0; j < 8; ++j) s += ui[j] * li2[j * 8 + ch];
      hv[ch] = s + pv[ch];
    }
    float a0 = a9[0];
    nt_store4(acc + row,     a0 * hv[0], a0 * hv[1], a0 * hv[2], a0 * hv[3]);
    nt_store4(acc + row + 4, a0 * hv[4], a0 * hv[5], a0 * hv[6], a0 * hv[7]);
    // ---- stage1 body
    float4 c0 = nt_load4(cond + row);
    float4 c1 = nt_load4(cond + row + 4);
    float xc[8] = {c0.x, c0.y, c0.z, c0.w, c1.x, c1.y, c1.z, c1.w};
    float u[8];
    #pragma unroll
    for (int j = 0; j < 8; ++j) {
      float s = lb1[j];
      #pragma unroll
      for (int k = 0; k < 8; ++k) s += xc[k] * lw1[k * 8 + j];
      u[j] = fmaxf(s, 0.f);
    }
    const float4* gr = (const float4*)(gnw + (size_t)n * Hv);
    float4 g0 = gr[0], g1 = gr[1];
    float gv[8] = {g0.x, g0.y, g0.z, g0.w, g1.x, g1.y, g1.z, g1.w};
    float o[8];
    #pragma unroll
    for (int ch = 0; ch < 8; ++ch) {
      float s = lb2[ch];
      #pragma unroll
      for (int j = 0; j < 8; ++j) s += u[j] * lw2[j * 8 + ch];
      float val = s + hv[ch];
      s1 += val; s2 += val * val;
      o[ch] = val * gv[ch];
    }
    float4* vo = (float4*)(vt + row);
    vo[0] = make_float4(o[0], o[1], o[2], o[3]);
    vo[1] = make_float4(o[4], o[5], o[6], o[7]);
  }
  partial_to_stats(s1, s2, stats1 + (size_t)g * 2);
}

// ---------------- stage 2: v2 = rstd*SpMM(vt) - mean*rstd*Gw + Gb + t; stats2
// IPT2=2 images/thread: grid 8 (xcd=b) * 6 (pair) * 20 (chunk) = 960 blocks.
__global__ __launch_bounds__(256) void k_stage2(
    const float* __restrict__ vt, float* __restrict__ v2,
    const int* __restrict__ row_ptr, const float2* __restrict__ epack,
    const float* __restrict__ Gw, const float* __restrict__ Gb,
    const float* __restrict__ stats1, float* stats2,
    const float* __restrict__ tvec) {
  __shared__ float2 se[ECAP];
  int t = threadIdx.x;
  int b = blockIdx.x & 7;
  int local = blockIdx.x >> 3;
  int pair = local % 6;
  int chunk = local / 6;
  int g0 = b * Pv + pair * IPT2;
  int nb0 = chunk * 256;
  int nb1 = nb0 + 256; if (nb1 > Nv) nb1 = Nv;
  int eb0 = row_ptr[nb0];
  int eb1 = row_ptr[nb1];
  int cnt = eb1 - eb0;
  const float2* eps;
  int ebase;
  if (cnt <= ECAP) {
    for (int k = t; k < cnt; k += 256) se[k] = epack[eb0 + k];
    eps = se; ebase = eb0;
  } else {
    eps = epack; ebase = 0;
  }
  __syncthreads();
  float mean[IPT2], rstd[IPT2], mrs[IPT2];
  #pragma unroll
  for (int j = 0; j < IPT2; ++j) {
    float m  = stats1[(g0 + j) * 2]     * (1.f / 40000.f);
    float m2 = stats1[(g0 + j) * 2 + 1] * (1.f / 40000.f);
    float var = m2 - m * m;
    mean[j] = m;
    rstd[j] = (float)(1.0 / sqrt((double)var + 1e-5));
    mrs[j]  = m * rstd[j];
  }
  int n = nb0 + t;
  float s1a[IPT2], s2a[IPT2];
  #pragma unroll
  for (int j = 0; j < IPT2; ++j) { s1a[j] = 0.f; s2a[j] = 0.f; }
  if (n < Nv) {
    const float* vt0 = vt + (size_t)(g0 + 0) * Nv * Hv;
    const float* vt1 = vt + (size_t)(g0 + 1) * Nv * Hv;
    float a[IPT2][8];
    #pragma unroll
    for (int j = 0; j < IPT2; ++j)
      #pragma unroll
      for (int ch = 0; ch < 8; ++ch) a[j][ch] = 0.f;
    int e0 = row_ptr[n] - ebase, e1 = row_ptr[n + 1] - ebase;
    int e = e0;
    for (; e + 2 <= e1; e += 2) {
      float2 p0 = eps[e], p1 = eps[e + 1];
      size_t so0 = (size_t)__float_as_int(p0.x) * Hv;
      size_t so1 = (size_t)__float_as_int(p1.x) * Hv;
      const float4* r00 = (const float4*)(vt0 + so0);
      const float4* r01 = (const float4*)(vt1 + so0);
      const float4* r10 = (const float4*)(vt0 + so1);
      const float4* r11 = (const float4*)(vt1 + so1);
      float4 x00a = r00[0], x00b = r00[1];
      float4 x01a = r01[0], x01b = r01[1];
      float4 x10a = r10[0], x10b = r10[1];
      float4 x11a = r11[0], x11b = r11[1];
      a[0][0] += p0.y*x00a.x + p1.y*x10a.x;
      a[0][1] += p0.y*x00a.y + p1.y*x10a.y;
      a[0][2] += p0.y*x00a.z + p1.y*x10a.z;
      a[0][3] += p0.y*x00a.w + p1.y*x10a.w;
      a[0][4] += p0.y*x00b.x + p1.y*x10b.x;
      a[0][5] += p0.y*x00b.y + p1.y*x10b.y;
      a[0][6] += p0.y*x00b.z + p1.y*x10b.z;
      a[0][7] += p0.y*x00b.w + p1.y*x10b.w;
      a[1][0] += p0.y*x01a.x + p1.y*x11a.x;
      a[1][1] += p0.y*x01a.y + p1.y*x11a.y;
      a[1][2] += p0.y*x01a.z + p1.y*x11a.z;
      a[1][3] += p0.y*x01a.w + p1.y*x11a.w;
      a[1][4] += p0.y*x01b.x + p1.y*x11b.x;
      a[1][5] += p0.y*x01b.y + p1.y*x11b.y;
      a[1][6] += p0.y*x01b.z + p1.y*x11b.z;
      a[1][7] += p0.y*x01b.w + p1.y*x11b.w;
    }
    for (; e < e1; ++e) {
      float2 ep = eps[e];
      float w = ep.y;
      size_t so = (size_t)__float_as_int(ep.x) * Hv;
      const float4* r0 = (const float4*)(vt0 + so);
      const float4* r1 = (const float4*)(vt1 + so);
      float4 xa = r0[0], xb = r0[1];
      float4 ya = r1[0], yb = r1[1];
      a[0][0] += w*xa.x; a[0][1] += w*xa.y; a[0][2] += w*xa.z; a[0][3] += w*xa.w;
      a[0][4] += w*xb.x; a[0][5] += w*xb.y; a[0][6] += w*xb.z; a[0][7] += w*xb.w;
      a[1][0] += w*ya.x; a[1][1] += w*ya.y; a[1][2] += w*ya.z; a[1][3] += w*ya.w;
      a[1][4] += w*yb.x; a[1][5] += w*yb.y; a[1][6] += w*yb.z; a[1][7] += w*yb.w;
    }
    size_t noff = (size_t)n * Hv;
    const float4* wr = (const float4*)(Gw + noff);
    const float4* br = (const float4*)(Gb + noff);
    float4 w0 = wr[0], w1 = wr[1], b0 = br[0], b1 = br[1];
    float gw8[8] = {w0.x, w0.y, w0.z, w0.w, w1.x, w1.y, w1.z, w1.w};
    float gb8[8] = {b0.x, b0.y, b0.z, b0.w, b1.x, b1.y, b1.z, b1.w};
    float tl[8];
    {
      const float4* tr = (const float4*)(tvec + b * Hv);
      float4 t0 = tr[0], t1 = tr[1];
      tl[0] = t0.x; tl[1] = t0.y; tl[2] = t0.z; tl[3] = t0.w;
      tl[4] = t1.x; tl[5] = t1.y; tl[6] = t1.z; tl[7] = t1.w;
    }
    #pragma unroll
    for (int j = 0; j < IPT2; ++j) {
      float o[8];
      #pragma unroll
      for (int ch = 0; ch < 8; ++ch) {
        float val = rstd[j] * a[j][ch] - mrs[j] * gw8[ch] + gb8[ch] + tl[ch];
        o[ch] = val;
        s1a[j] += val; s2a[j] += val * val;
      }
      float* vo = v2 + (size_t)(g0 + j) * Nv * Hv + noff;
      nt_store4(vo,     o[0], o[1], o[2], o[3]);
      nt_store4(vo + 4, o[4], o[5], o[6], o[7]);
    }
  }
  #pragma unroll
  for (int j = 0; j < IPT2; ++j)
    partial_to_stats(s1a[j], s2a[j], stats2 + (size_t)(g0 + j) * 2);
}

// ---------------- stage 3: LN(v2) + 12x12 conv over P (in-place) + skip acc.
// For iblk==NBv-1, fuse the output projection (pair-exchange acc halves) and
// skip the acc store + the separate k_out pass.
__global__ __launch_bounds__(256) void k_stage3(
    float* __restrict__ v2, float* __restrict__ acc,
    const float* __restrict__ stats2,
    const float* __restrict__ tnw, const float* __restrict__ tnb,
    const float* __restrict__ cw, const float* __restrict__ cb,
    const float* __restrict__ a9, int iblk,
    const float* __restrict__ ow1, const float* __restrict__ ob1,
    const float* __restrict__ ow2, const float* __restrict__ ob2,
    float* __restrict__ out) {
  __shared__ float scw[144], scb[12], smean[12], srstd[12];
  __shared__ float sow1[64], sob1[8], sow2[8], sob2[1];
  int t = threadIdx.x;
  int b = blockIdx.x & 7;
  int chunk = blockIdx.x >> 3;
  bool last = (iblk == NBv - 1);
  if (t < 144) scw[t] = cw[t];
  else if (t < 156) scb[t - 144] = cb[t - 144];
  else if (t < 168) {
    int p = t - 156;
    int g = b * Pv + p;
    float mean = stats2[g * 2]     * (1.f / 40000.f);
    float m2   = stats2[g * 2 + 1] * (1.f / 40000.f);
    float var  = m2 - mean * mean;
    smean[p] = mean;
    srstd[p] = (float)(1.0 / sqrt((double)var + 1e-5));
  } else if (last) {
    if (t < 232) sow1[t - 168] = ow1[t - 168];
    else if (t < 240) sob1[t - 232] = ob1[t - 232];
    else if (t < 248) sow2[t - 240] = ow2[t - 240];
    else if (t == 248) sob2[0] = ob2[0];
  }
  __syncthreads();
  int idx = chunk * 256 + t;
  if (idx >= Nv * 2) return;
  int n = idx >> 1, c4 = idx & 1;
  size_t noff = (size_t)n * Hv + c4 * 4;
  const float4 w4 = nt_load4(tnw + noff);
  const float4 b4 = nt_load4(tnb + noff);
  size_t strideP = (size_t)Nv * Hv;
  size_t base = (size_t)b * Pv * strideP + noff;
  float4 in[12];
  #pragma unroll
  for (int p = 0; p < 12; ++p) {
    float4 v = nt_load4(v2 + base + p * strideP);
    float mean = smean[p], rstd = srstd[p];
    in[p].x = (v.x - mean) * rstd * w4.x + b4.x;
    in[p].y = (v.y - mean) * rstd * w4.y + b4.y;
    in[p].z = (v.z - mean) * rstd * w4.z + b4.z;
    in[p].w = (v.w - mean) * rstd * w4.w + b4.w;
  }
  float ai = a9[iblk + 1];
  #pragma unroll
  for (int q = 0; q < 12; ++q) {
    float4 o = make_float4(scb[q], scb[q], scb[q], scb[q]);
    #pragma unroll
    for (int p = 0; p < 12; ++p) {
      float c = scw[q * 12 + p];
      o.x += c * in[p].x; o.y += c * in[p].y;
      o.z += c * in[p].z; o.w += c * in[p].w;
    }
    size_t off = base + q * strideP;
    float4 av = nt_load4(acc + off);
    float n0 = av.x + ai * o.x, n1 = av.y + ai * o.y;
    float n2 = av.z + ai * o.z, n3 = av.w + ai * o.w;
    if (!last) {
      *(float4*)(v2 + off) = o;      // live: next stage1 reads it
      nt_store4(acc + off, n0, n1, n2, n3);
    } else {
      // output projection: exchange halves with partner lane (same n, other c4)
      float e0 = __shfl_xor(n0, 1, 64);
      float e1 = __shfl_xor(n1, 1, 64);
      float e2 = __shfl_xor(n2, 1, 64);
      float e3 = __shfl_xor(n3, 1, 64);
      float a8[8];
      if (c4 == 0) {
        a8[0] = n0; a8[1] = n1; a8[2] = n2; a8[3] = n3;
        a8[4] = e0; a8[5] = e1; a8[6] = e2; a8[7] = e3;
      } else {
        a8[0] = e0; a8[1] = e1; a8[2] = e2; a8[3] = e3;
        a8[4] = n0; a8[5] = n1; a8[6] = n2; a8[7] = n3;
      }
      if (c4 == 0) {
        float oo = sob2[0];
        #pragma unroll
        for (int j = 0; j < 8; ++j) {
          float s = sob1[j];
          #pragma unroll
          for (int k = 0; k < 8; ++k) s += a8[k] * sow1[k * 8 + j];
          oo += fmaxf(s, 0.f) * sow2[j];
        }
        out[((size_t)b * Pv + q) * Nv + n] = oo;
      }
    }
  }
}

extern "C" void kernel_launch(void* const* d_in, const int* in_sizes, int n_in,
                              void* d_out, int out_size, void* d_ws, size_t ws_size,
                              hipStream_t stream) {
  const float* x      = (const float*)d_in[0];
  const float* cond   = (const float*)d_in[1];
  const float* pos    = (const float*)d_in[2];
  const int*   timei  = (const int*)  d_in[3];
  const int*   eidx   = (const int*)  d_in[4];
  const float* te_w1  = (const float*)d_in[5];
  const float* te_b1  = (const float*)d_in[6];
  const float* te_w2  = (const float*)d_in[7];
  const float* te_b2  = (const float*)d_in[8];
  const float* in_w1  = (const float*)d_in[9];
  const float* in_b1  = (const float*)d_in[10];
  const float* in_w2  = (const float*)d_in[11];
  const float* in_b2  = (const float*)d_in[12];
  const float* pos_w1 = (const float*)d_in[13];
  const float* pos_b1 = (const float*)d_in[14];
  const float* pos_w2 = (const float*)d_in[15];
  const float* pos_b2 = (const float*)d_in[16];
  const float* attn   = (const float*)d_in[17];
  const float* bt_w1  = (const float*)d_in[18];
  const float* bt_b1  = (const float*)d_in[19];
  const float* bt_w2  = (const float*)d_in[20];
  const float* bt_b2  = (const float*)d_in[21];
  const float* bc_w1  = (const float*)d_in[22];
  const float* bc_b1  = (const float*)d_in[23];
  const float* bc_w2  = (const float*)d_in[24];
  const float* bc_b2  = (const float*)d_in[25];
  const float* gn_w   = (const float*)d_in[26];
  const float* gn_b   = (const float*)d_in[27];
  const float* tn_w   = (const float*)d_in[28];
  const float* tn_b   = (const float*)d_in[29];
  const float* cv_w   = (const float*)d_in[30];
  const float* cv_b   = (const float*)d_in[31];
  const float* out_w1 = (const float*)d_in[32];
  const float* out_b1 = (const float*)d_in[33];
  const float* out_w2 = (const float*)d_in[34];
  const float* out_b2 = (const float*)d_in[35];
  float* out = (float*)d_out;

  const size_t HSZ = (size_t)Bv * Pv * Nv * Hv;  // 3,840,000
  float* ws    = (float*)d_ws;
  float* X     = ws;                 // v2 buffer
  float* Y     = X + HSZ;            // vt (= gnw ⊙ v1) buffer
  float* acc   = Y + HSZ;
  float* posp  = acc + HSZ;          // Nv*Hv
  float* deg   = posp + Nv * Hv;     // Nv
  float* dinv  = deg + Nv;           // Nv
  float* epack = dinv + Nv;          // 2*Ev floats
  float* t_all = epack + 2 * Ev;     // NBv*Bv*Hv = 512
  float* a9    = t_all + NBv * Bv * Hv;  // 16
  float* stats = a9 + 16;            // NBv*2*NIMG*2 = 3072
  float* Gw    = stats + NBv * 2 * NIMG * 2;  // NBv*Nv*Hv = 320000
  float* Gb    = Gw + NBv * Nv * Hv;          // 320000
  int* row_ptr = (int*)(Gb + NBv * Nv * Hv);  // Nv+8
  int* cursor  = row_ptr + Nv + 8;   // Nv+8

  k_setup<<<1, 512, 0, stream>>>(timei, attn, te_w1, te_b1, te_w2, te_b2,
                                 bt_w1, bt_b1, bt_w2, bt_b2, t_all, a9);
  k_posp<<<(Nv + 255) / 256, 256, 0, stream>>>(pos, pos_w1, pos_b1, pos_w2, pos_b2, posp);
  k_zero<<<(Nv + 255) / 256, 256, 0, stream>>>(deg, cursor, stats);
  k_deg<<<(Ev + 255) / 256, 256, 0, stream>>>(eidx, deg);
  k_dinv<<<(Nv + 255) / 256, 256, 0, stream>>>(deg, dinv);
  k_scan<<<1, 1024, 0, stream>>>(deg, row_ptr);
  k_csr<<<(Ev + 255) / 256, 256, 0, stream>>>(eidx, dinv, row_ptr, cursor, (float2*)epack);
  k_gwb<<<(NBv * Nv + 255) / 256, 256, 0, stream>>>(
      row_ptr, (const float2*)epack, gn_w, gn_b, Gw, Gb);

  for (int i = 0; i < NBv; ++i) {
    float* st1 = stats + (size_t)(i * 2 + 0) * NIMG * 2;
    float* st2 = stats + (size_t)(i * 2 + 1) * NIMG * 2;
    if (i == 0) {
      k_stage1_init<<<NIMG * BLKS_PER_IMG, 256, 0, stream>>>(
          x, posp, in_w1, in_b1, in_w2, in_b2,
          cond, bc_w1, bc_b1, bc_w2, bc_b2,
          gn_w, a9, acc, Y, st1);
    } else {
      k_stage1<<<NIMG * BLKS_PER_IMG, 256, 0, stream>>>(
          X, cond,
          bc_w1 + i * 64, bc_b1 + i * 8, bc_w2 + i * 64, bc_b2 + i * 8,
          gn_w + (size_t)i * Nv * Hv,
          Y, st1);
    }
    k_stage2<<<8 * 6 * BLKS_PER_IMG, 256, 0, stream>>>(
        Y, X, row_ptr, (const float2*)epack,
        Gw + (size_t)i * Nv * Hv, Gb + (size_t)i * Nv * Hv,
        st1, st2, t_all + i * Bv * Hv);
    k_stage3<<<8 * 40, 256, 0, stream>>>(
        X, acc, st2,
        tn_w + (size_t)i * Nv * Hv, tn_b + (size_t)i * Nv * Hv,
        cv_w + i * 144, cv_b + i * 12, a9, i,
        out_w1, out_b1, out_w2, out_b2, out);
  }
}

// Round 16
// 590.687 us; speedup vs baseline: 1.8564x; 1.0126x over previous
//
#include <hip/hip_runtime.h>
#include <math.h>

#define Bv 8
#define Pv 12
#define Nv 5000
#define Hv 8
#define Ev 50000
#define NBv 8
#define TD1v 64
#define NIMG (Bv * Pv)          // 96 images
#define BLKS_PER_IMG 20         // ceil(5000/256)
#define ECAP 3072               // LDS edge-stage capacity (24 KB)
#define IPT2 2                  // images per thread in stage2

typedef float f4v __attribute__((ext_vector_type(4)));

__device__ inline float4 nt_load4(const float* p) {
  f4v v = __builtin_nontemporal_load((const f4v*)p);
  return make_float4(v.x, v.y, v.z, v.w);
}
__device__ inline void nt_store4(float* p, float a, float b, float c, float d) {
  f4v v = {a, b, c, d};
  __builtin_nontemporal_store(v, (f4v*)p);
}

// correctly-rounded f32 of 10^(d/4), d=0..15 (matches numpy float32 powf)
__device__ __constant__ float POW10Q[16] = {
  1.0f, 1.7782794100389228f, 3.1622776601683795f, 5.623413251903491f,
  10.0f, 17.78279410038923f, 31.622776601683793f, 56.23413251903491f,
  100.0f, 177.82794100389228f, 316.22776601683796f, 562.341325190349f,
  1000.0f, 1778.2794100389228f, 3162.2776601683795f, 5623.413251903491f
};

// ---------------- setup (512 threads): time-embedding chain, t vectors, softmax(attn)
__global__ __launch_bounds__(512) void k_setup(
    const int* timei, const float* attn,
    const float* te_w1, const float* te_b1,
    const float* te_w2, const float* te_b2,
    const float* bt_w1, const float* bt_b1,
    const float* bt_w2, const float* bt_b2,
    float* t_all, float* a9) {
  __shared__ float te0[Bv][32];
  __shared__ float te1[Bv][64];
  __shared__ float te2[Bv][64];
  __shared__ float su[64][8];
  int t = threadIdx.x; // 512
  if (t < 256) {
    int b = t >> 5, k = t & 31;
    int d = k & 15;
    float e = (float)timei[b] * POW10Q[d];   // f32 rounding as in numpy
    te0[b][k] = (k < 16) ? (float)sin((double)e) : (float)cos((double)e);
  }
  __syncthreads();
  {
    int b = t >> 6, j = t & 63;   // 512 outputs
    float s = te_b1[j];
    for (int k = 0; k < 32; ++k) s += te0[b][k] * te_w1[k * 64 + j];
    te1[b][j] = s / (1.0f + expf(-s));       // silu
  }
  __syncthreads();
  {
    int b = t >> 6, j = t & 63;
    float s = te_b2[j];
    for (int k = 0; k < 64; ++k) s += te1[b][k] * te_w2[k * 64 + j];
    te2[b][j] = s / (1.0f + expf(-s));
  }
  __syncthreads();
  {
    int ib = t >> 3, j = t & 7;   // ib = i*8+b, 64 pairs x 8 hidden
    int i = ib >> 3, b = ib & 7;
    float s = bt_b1[i * Hv + j];
    for (int k = 0; k < TD1v; ++k) s += te2[b][k] * bt_w1[(i * TD1v + k) * Hv + j];
    su[ib][j] = fmaxf(s, 0.0f);
  }
  __syncthreads();
  {
    int ib = t >> 3, ch = t & 7;
    int i = ib >> 3, b = ib & 7;
    float s = bt_b2[i * Hv + ch];
    #pragma unroll
    for (int j = 0; j < 8; ++j) s += su[ib][j] * bt_w2[(i * Hv + j) * Hv + ch];
    t_all[(i * Bv + b) * Hv + ch] = s;
  }
  if (t == 0) {
    float m = attn[0];
    for (int i = 1; i < 9; ++i) m = fmaxf(m, attn[i]);
    float s = 0.f, ex[9];
    for (int i = 0; i < 9; ++i) { ex[i] = expf(attn[i] - m); s += ex[i]; }
    for (int i = 0; i < 9; ++i) a9[i] = ex[i] / s;
  }
}

// ---------------- merged: posp projection + zero(deg/cursor/stats)
__global__ void k_posp_zero(const float* pos, const float* pw1, const float* pb1,
                            const float* pw2, const float* pb2, float* posp,
                            float* deg, int* cursor, float* stats) {
  int n = blockIdx.x * blockDim.x + threadIdx.x;
  if (n < Nv) { deg[n] = 0.f; cursor[n] = 0; }
  if (n < NBv * 2 * NIMG * 2) stats[n] = 0.f;
  if (n >= Nv) return;
  const float4* pr = (const float4*)(pos + (size_t)n * Hv);
  float4 r0 = pr[0], r1 = pr[1];
  float x[8] = {r0.x, r0.y, r0.z, r0.w, r1.x, r1.y, r1.z, r1.w};
  float u[8];
  #pragma unroll
  for (int j = 0; j < 8; ++j) {
    float s = pb1[j];
    #pragma unroll
    for (int k = 0; k < 8; ++k) s += x[k] * pw1[k * 8 + j];
    u[j] = fmaxf(s, 0.f);
  }
  float o[8];
  #pragma unroll
  for (int ch = 0; ch < 8; ++ch) {
    float s = pb2[ch];
    #pragma unroll
    for (int j = 0; j < 8; ++j) s += u[j] * pw2[j * 8 + ch];
    o[ch] = s;
  }
  float4* po = (float4*)(posp + (size_t)n * Hv);
  po[0] = make_float4(o[0], o[1], o[2], o[3]);
  po[1] = make_float4(o[4], o[5], o[6], o[7]);
}

__global__ void k_deg(const int* eidx, float* deg) {
  int e = blockIdx.x * blockDim.x + threadIdx.x;
  if (e < Ev) atomicAdd(&deg[eidx[Ev + e]], 1.0f);
}

// single-block: dinv for all nodes + exclusive scan -> row_ptr[0..Nv]
// wave-level shfl scan (barrier-light)
__global__ __launch_bounds__(1024) void k_scan(const float* deg, float* dinv,
                                               int* row_ptr) {
  __shared__ int wsum[16];
  __shared__ int base_s;
  int t = threadIdx.x;
  int lane = t & 63, wid = t >> 6;
  if (t == 0) { base_s = 0; row_ptr[0] = 0; }
  __syncthreads();
  for (int c = 0; c < 5; ++c) {
    int i = c * 1024 + t;
    float dv = (i < Nv) ? deg[i] : 0.f;
    if (i < Nv)
      dinv[i] = dv > 0.f ? (float)(1.0 / sqrt((double)dv)) : 0.f;
    int v = (int)(dv + 0.5f);
    // inclusive wave scan via shfl
    int s = v;
    #pragma unroll
    for (int off = 1; off < 64; off <<= 1) {
      int up = __shfl_up(s, off, 64);
      if (lane >= off) s += up;
    }
    if (lane == 63) wsum[wid] = s;
    __syncthreads();
    if (wid == 0 && lane < 16) {
      int ws = wsum[lane];
      #pragma unroll
      for (int off = 1; off < 16; off <<= 1) {
        int up = __shfl_up(ws, off, 64);
        if (lane >= off) ws += up;
      }
      wsum[lane] = ws;
    }
    __syncthreads();
    int wbase = (wid > 0) ? wsum[wid - 1] : 0;
    int incl = base_s + wbase + s;
    if (i < Nv) row_ptr[i + 1] = incl;
    __syncthreads();
    if (t == 1023) base_s = incl;
    __syncthreads();
  }
}

// CSR fill: packed (src_bits, w) per edge
__global__ void k_csr(const int* eidx, const float* dinv, const int* row_ptr,
                      int* cursor, float2* epack) {
  int e = blockIdx.x * blockDim.x + threadIdx.x;
  if (e >= Ev) return;
  int s = eidx[e], d = eidx[Ev + e];
  int slot = atomicAdd(&cursor[d], 1);
  int pos = row_ptr[d] + slot;
  epack[pos] = make_float2(__int_as_float(s), dinv[s] * dinv[d]);
}

// ---------------- per block-iter, image-independent: Gw[i][n]=Σ w_e gnw_i[src], Gb likewise
__global__ __launch_bounds__(256) void k_gwb(
    const int* __restrict__ row_ptr, const float2* __restrict__ epack,
    const float* __restrict__ gn_w, const float* __restrict__ gn_b,
    float* __restrict__ Gw, float* __restrict__ Gb) {
  int id = blockIdx.x * 256 + threadIdx.x;
  if (id >= NBv * Nv) return;
  int i = id / Nv, n = id % Nv;
  const float* gw = gn_w + (size_t)i * Nv * Hv;
  const float* gb = gn_b + (size_t)i * Nv * Hv;
  float aw[8] = {0,0,0,0,0,0,0,0}, ab[8] = {0,0,0,0,0,0,0,0};
  int e0 = row_ptr[n], e1 = row_ptr[n + 1];
  for (int e = e0; e < e1; ++e) {
    float2 ep = epack[e];
    int s = __float_as_int(ep.x);
    float w = ep.y;
    const float4* wr = (const float4*)(gw + (size_t)s * Hv);
    const float4* br = (const float4*)(gb + (size_t)s * Hv);
    float4 w0 = wr[0], w1 = wr[1], b0 = br[0], b1 = br[1];
    aw[0] += w * w0.x; aw[1] += w * w0.y; aw[2] += w * w0.z; aw[3] += w * w0.w;
    aw[4] += w * w1.x; aw[5] += w * w1.y; aw[6] += w * w1.z; aw[7] += w * w1.w;
    ab[0] += w * b0.x; ab[1] += w * b0.y; ab[2] += w * b0.z; ab[3] += w * b0.w;
    ab[4] += w * b1.x; ab[5] += w * b1.y; ab[6] += w * b1.z; ab[7] += w * b1.w;
  }
  float4* wo = (float4*)(Gw + (size_t)id * Hv);
  wo[0] = make_float4(aw[0], aw[1], aw[2], aw[3]);
  wo[1] = make_float4(aw[4], aw[5], aw[6], aw[7]);
  float4* bo = (float4*)(Gb + (size_t)id * Hv);
  bo[0] = make_float4(ab[0], ab[1], ab[2], ab[3]);
  bo[1] = make_float4(ab[4], ab[5], ab[6], ab[7]);
}

// block-level reduce of (s1,s2) over 256 threads, then one atomicAdd pair.
__device__ inline void partial_to_stats(float s1, float s2, float* stats_g) {
  #pragma unroll
  for (int off = 32; off > 0; off >>= 1) {
    s1 += __shfl_down(s1, off, 64);
    s2 += __shfl_down(s2, off, 64);
  }
  __shared__ float r1[4], r2[4];
  int wid = threadIdx.x >> 6, lane = threadIdx.x & 63;
  if (lane == 0) { r1[wid] = s1; r2[wid] = s2; }
  __syncthreads();
  if (threadIdx.x == 0) {
    float a = r1[0] + r1[1] + r1[2] + r1[3];
    float b = r2[0] + r2[1] + r2[2] + r2[3];
    atomicAdd(&stats_g[0], a);
    atomicAdd(&stats_g[1], b);
  }
  __syncthreads();
}

// XCD-locality swizzle: blockIdx%8 = XCD; image g = xcd*12 + local/20
__device__ inline void img_swizzle(int bx, int& g, int& chunk) {
  int xcd = bx & 7;
  int local = bx >> 3;
  g = xcd * 12 + local / BLKS_PER_IMG;
  chunk = local % BLKS_PER_IMG;
}

// ---------------- stage 1 (i>=1): v1 = h + proj(cond); vt = gnw ⊙ v1; stats over v1
__global__ __launch_bounds__(256) void k_stage1(
    const float* __restrict__ h, const float* __restrict__ cond,
    const float* w1, const float* b1, const float* w2, const float* b2,
    const float* __restrict__ gnw,
    float* __restrict__ vt, float* stats1) {
  __shared__ float lw1[64], lw2[64], lb1[8], lb2[8];
  int t = threadIdx.x;
  if (t < 64) lw1[t] = w1[t];
  else if (t < 128) lw2[t - 64] = w2[t - 64];
  else if (t < 136) lb1[t - 128] = b1[t - 128];
  else if (t < 144) lb2[t - 136] = b2[t - 136];
  __syncthreads();
  int g, chunk;
  img_swizzle(blockIdx.x, g, chunk);
  int n = chunk * 256 + t;
  float s1 = 0.f, s2 = 0.f;
  if (n < Nv) {
    size_t row = ((size_t)g * Nv + n) * Hv;
    float4 c0 = nt_load4(cond + row);
    float4 c1 = nt_load4(cond + row + 4);
    float xc[8] = {c0.x, c0.y, c0.z, c0.w, c1.x, c1.y, c1.z, c1.w};
    float u[8];
    #pragma unroll
    for (int j = 0; j < 8; ++j) {
      float s = lb1[j];
      #pragma unroll
      for (int k = 0; k < 8; ++k) s += xc[k] * lw1[k * 8 + j];
      u[j] = fmaxf(s, 0.f);
    }
    const float4* hr = (const float4*)(h + row);
    float4 h0 = hr[0], h1 = hr[1];
    float hv[8] = {h0.x, h0.y, h0.z, h0.w, h1.x, h1.y, h1.z, h1.w};
    const float4* gr = (const float4*)(gnw + (size_t)n * Hv);
    float4 g0 = gr[0], g1 = gr[1];
    float gv[8] = {g0.x, g0.y, g0.z, g0.w, g1.x, g1.y, g1.z, g1.w};
    float o[8];
    #pragma unroll
    for (int ch = 0; ch < 8; ++ch) {
      float s = lb2[ch];
      #pragma unroll
      for (int j = 0; j < 8; ++j) s += u[j] * lw2[j * 8 + ch];
      float val = s + hv[ch];
      s1 += val; s2 += val * val;
      o[ch] = val * gv[ch];
    }
    float4* vo = (float4*)(vt + row);
    vo[0] = make_float4(o[0], o[1], o[2], o[3]);
    vo[1] = make_float4(o[4], o[5], o[6], o[7]);
  }
  partial_to_stats(s1, s2, stats1 + (size_t)g * 2);
}

// ---------------- fused k_init + stage1 for i=0
__global__ __launch_bounds__(256) void k_stage1_init(
    const float* __restrict__ x, const float* __restrict__ posp,
    const float* iw1, const float* ib1, const float* iw2, const float* ib2,
    const float* __restrict__ cond,
    const float* w1, const float* b1, const float* w2, const float* b2,
    const float* __restrict__ gnw, const float* __restrict__ a9,
    float* __restrict__ acc,
    float* __restrict__ vt, float* stats1) {
  __shared__ float lw1[64], lw2[64], lb1[8], lb2[8];
  __shared__ float li1[8], li2[64], lib1[8], lib2[8];
  int t = threadIdx.x;
  if (t < 64) lw1[t] = w1[t];
  else if (t < 128) lw2[t - 64] = w2[t - 64];
  else if (t < 136) lb1[t - 128] = b1[t - 128];
  else if (t < 144) lb2[t - 136] = b2[t - 136];
  else if (t < 152) li1[t - 144] = iw1[t - 144];
  else if (t < 216) li2[t - 152] = iw2[t - 152];
  else if (t < 224) lib1[t - 216] = ib1[t - 216];
  else if (t < 232) lib2[t - 224] = ib2[t - 224];
  __syncthreads();
  int g, chunk;
  img_swizzle(blockIdx.x, g, chunk);
  int n = chunk * 256 + t;
  float s1 = 0.f, s2 = 0.f;
  if (n < Nv) {
    size_t row = ((size_t)g * Nv + n) * Hv;
    float xv = __builtin_nontemporal_load(x + (size_t)g * Nv + n);
    float ui[8];
    #pragma unroll
    for (int j = 0; j < 8; ++j) ui[j] = fmaxf(xv * li1[j] + lib1[j], 0.f);
    const float4* pp = (const float4*)(posp + (size_t)n * Hv);
    float4 p0 = pp[0], p1 = pp[1];
    float pv[8] = {p0.x, p0.y, p0.z, p0.w, p1.x, p1.y, p1.z, p1.w};
    float hv[8];
    #pragma unroll
    for (int ch = 0; ch < 8; ++ch) {
      float s = lib2[ch];
      #pragma unroll
      for (int j = 0; j < 8; ++j) s += ui[j] * li2[j * 8 + ch];
      hv[ch] = s + pv[ch];
    }
    float a0 = a9[0];
    nt_store4(acc + row,     a0 * hv[0], a0 * hv[1], a0 * hv[2], a0 * hv[3]);
    nt_store4(acc + row + 4, a0 * hv[4], a0 * hv[5], a0 * hv[6], a0 * hv[7]);
    float4 c0 = nt_load4(cond + row);
    float4 c1 = nt_load4(cond + row + 4);
    float xc[8] = {c0.x, c0.y, c0.z, c0.w, c1.x, c1.y, c1.z, c1.w};
    float u[8];
    #pragma unroll
    for (int j = 0; j < 8; ++j) {
      float s = lb1[j];
      #pragma unroll
      for (int k = 0; k < 8; ++k) s += xc[k] * lw1[k * 8 + j];
      u[j] = fmaxf(s, 0.f);
    }
    const float4* gr = (const float4*)(gnw + (size_t)n * Hv);
    float4 g0 = gr[0], g1 = gr[1];
    float gv[8] = {g0.x, g0.y, g0.z, g0.w, g1.x, g1.y, g1.z, g1.w};
    float o[8];
    #pragma unroll
    for (int ch = 0; ch < 8; ++ch) {
      float s = lb2[ch];
      #pragma unroll
      for (int j = 0; j < 8; ++j) s += u[j] * lw2[j * 8 + ch];
      float val = s + hv[ch];
      s1 += val; s2 += val * val;
      o[ch] = val * gv[ch];
    }
    float4* vo = (float4*)(vt + row);
    vo[0] = make_float4(o[0], o[1], o[2], o[3]);
    vo[1] = make_float4(o[4], o[5], o[6], o[7]);
  }
  partial_to_stats(s1, s2, stats1 + (size_t)g * 2);
}

// ---------------- stage 2: v2 = rstd*SpMM(vt) - mean*rstd*Gw + Gb + t; stats2
__global__ __launch_bounds__(256) void k_stage2(
    const float* __restrict__ vt, float* __restrict__ v2,
    const int* __restrict__ row_ptr, const float2* __restrict__ epack,
    const float* __restrict__ Gw, const float* __restrict__ Gb,
    const float* __restrict__ stats1, float* stats2,
    const float* __restrict__ tvec) {
  __shared__ float2 se[ECAP];
  int t = threadIdx.x;
  int b = blockIdx.x & 7;
  int local = blockIdx.x >> 3;
  int pair = local % 6;
  int chunk = local / 6;
  int g0 = b * Pv + pair * IPT2;
  int nb0 = chunk * 256;
  int nb1 = nb0 + 256; if (nb1 > Nv) nb1 = Nv;
  int eb0 = row_ptr[nb0];
  int eb1 = row_ptr[nb1];
  int cnt = eb1 - eb0;
  const float2* eps;
  int ebase;
  if (cnt <= ECAP) {
    for (int k = t; k < cnt; k += 256) se[k] = epack[eb0 + k];
    eps = se; ebase = eb0;
  } else {
    eps = epack; ebase = 0;
  }
  __syncthreads();
  float mean[IPT2], rstd[IPT2], mrs[IPT2];
  #pragma unroll
  for (int j = 0; j < IPT2; ++j) {
    float m  = stats1[(g0 + j) * 2]     * (1.f / 40000.f);
    float m2 = stats1[(g0 + j) * 2 + 1] * (1.f / 40000.f);
    float var = m2 - m * m;
    mean[j] = m;
    rstd[j] = (float)(1.0 / sqrt((double)var + 1e-5));
    mrs[j]  = m * rstd[j];
  }
  int n = nb0 + t;
  float s1a[IPT2], s2a[IPT2];
  #pragma unroll
  for (int j = 0; j < IPT2; ++j) { s1a[j] = 0.f; s2a[j] = 0.f; }
  if (n < Nv) {
    const float* vt0 = vt + (size_t)(g0 + 0) * Nv * Hv;
    const float* vt1 = vt + (size_t)(g0 + 1) * Nv * Hv;
    float a[IPT2][8];
    #pragma unroll
    for (int j = 0; j < IPT2; ++j)
      #pragma unroll
      for (int ch = 0; ch < 8; ++ch) a[j][ch] = 0.f;
    int e0 = row_ptr[n] - ebase, e1 = row_ptr[n + 1] - ebase;
    int e = e0;
    for (; e + 2 <= e1; e += 2) {
      float2 p0 = eps[e], p1 = eps[e + 1];
      size_t so0 = (size_t)__float_as_int(p0.x) * Hv;
      size_t so1 = (size_t)__float_as_int(p1.x) * Hv;
      const float4* r00 = (const float4*)(vt0 + so0);
      const float4* r01 = (const float4*)(vt1 + so0);
      const float4* r10 = (const float4*)(vt0 + so1);
      const float4* r11 = (const float4*)(vt1 + so1);
      float4 x00a = r00[0], x00b = r00[1];
      float4 x01a = r01[0], x01b = r01[1];
      float4 x10a = r10[0], x10b = r10[1];
      float4 x11a = r11[0], x11b = r11[1];
      a[0][0] += p0.y*x00a.x + p1.y*x10a.x;
      a[0][1] += p0.y*x00a.y + p1.y*x10a.y;
      a[0][2] += p0.y*x00a.z + p1.y*x10a.z;
      a[0][3] += p0.y*x00a.w + p1.y*x10a.w;
      a[0][4] += p0.y*x00b.x + p1.y*x10b.x;
      a[0][5] += p0.y*x00b.y + p1.y*x10b.y;
      a[0][6] += p0.y*x00b.z + p1.y*x10b.z;
      a[0][7] += p0.y*x00b.w + p1.y*x10b.w;
      a[1][0] += p0.y*x01a.x + p1.y*x11a.x;
      a[1][1] += p0.y*x01a.y + p1.y*x11a.y;
      a[1][2] += p0.y*x01a.z + p1.y*x11a.z;
      a[1][3] += p0.y*x01a.w + p1.y*x11a.w;
      a[1][4] += p0.y*x01b.x + p1.y*x11b.x;
      a[1][5] += p0.y*x01b.y + p1.y*x11b.y;
      a[1][6] += p0.y*x01b.z + p1.y*x11b.z;
      a[1][7] += p0.y*x01b.w + p1.y*x11b.w;
    }
    for (; e < e1; ++e) {
      float2 ep = eps[e];
      float w = ep.y;
      size_t so = (size_t)__float_as_int(ep.x) * Hv;
      const float4* r0 = (const float4*)(vt0 + so);
      const float4* r1 = (const float4*)(vt1 + so);
      float4 xa = r0[0], xb = r0[1];
      float4 ya = r1[0], yb = r1[1];
      a[0][0] += w*xa.x; a[0][1] += w*xa.y; a[0][2] += w*xa.z; a[0][3] += w*xa.w;
      a[0][4] += w*xb.x; a[0][5] += w*xb.y; a[0][6] += w*xb.z; a[0][7] += w*xb.w;
      a[1][0] += w*ya.x; a[1][1] += w*ya.y; a[1][2] += w*ya.z; a[1][3] += w*ya.w;
      a[1][4] += w*yb.x; a[1][5] += w*yb.y; a[1][6] += w*yb.z; a[1][7] += w*yb.w;
    }
    size_t noff = (size_t)n * Hv;
    const float4* wr = (const float4*)(Gw + noff);
    const float4* br = (const float4*)(Gb + noff);
    float4 w0 = wr[0], w1 = wr[1], b0 = br[0], b1 = br[1];
    float gw8[8] = {w0.x, w0.y, w0.z, w0.w, w1.x, w1.y, w1.z, w1.w};
    float gb8[8] = {b0.x, b0.y, b0.z, b0.w, b1.x, b1.y, b1.z, b1.w};
    float tl[8];
    {
      const float4* tr = (const float4*)(tvec + b * Hv);
      float4 t0 = tr[0], t1 = tr[1];
      tl[0] = t0.x; tl[1] = t0.y; tl[2] = t0.z; tl[3] = t0.w;
      tl[4] = t1.x; tl[5] = t1.y; tl[6] = t1.z; tl[7] = t1.w;
    }
    #pragma unroll
    for (int j = 0; j < IPT2; ++j) {
      float o[8];
      #pragma unroll
      for (int ch = 0; ch < 8; ++ch) {
        float val = rstd[j] * a[j][ch] - mrs[j] * gw8[ch] + gb8[ch] + tl[ch];
        o[ch] = val;
        s1a[j] += val; s2a[j] += val * val;
      }
      float* vo = v2 + (size_t)(g0 + j) * Nv * Hv + noff;
      nt_store4(vo,     o[0], o[1], o[2], o[3]);
      nt_store4(vo + 4, o[4], o[5], o[6], o[7]);
    }
  }
  #pragma unroll
  for (int j = 0; j < IPT2; ++j)
    partial_to_stats(s1a[j], s2a[j], stats2 + (size_t)(g0 + j) * 2);
}

// ---------------- stage 3: LN(v2) + conv + skip acc; last iter fuses output proj
__global__ __launch_bounds__(256) void k_stage3(
    float* __restrict__ v2, float* __restrict__ acc,
    const float* __restrict__ stats2,
    const float* __restrict__ tnw, const float* __restrict__ tnb,
    const float* __restrict__ cw, const float* __restrict__ cb,
    const float* __restrict__ a9, int iblk,
    const float* __restrict__ ow1, const float* __restrict__ ob1,
    const float* __restrict__ ow2, const float* __restrict__ ob2,
    float* __restrict__ out) {
  __shared__ float scw[144], scb[12], smean[12], srstd[12];
  __shared__ float sow1[64], sob1[8], sow2[8], sob2[1];
  int t = threadIdx.x;
  int b = blockIdx.x & 7;
  int chunk = blockIdx.x >> 3;
  bool last = (iblk == NBv - 1);
  if (t < 144) scw[t] = cw[t];
  else if (t < 156) scb[t - 144] = cb[t - 144];
  else if (t < 168) {
    int p = t - 156;
    int g = b * Pv + p;
    float mean = stats2[g * 2]     * (1.f / 40000.f);
    float m2   = stats2[g * 2 + 1] * (1.f / 40000.f);
    float var  = m2 - mean * mean;
    smean[p] = mean;
    srstd[p] = (float)(1.0 / sqrt((double)var + 1e-5));
  } else if (last) {
    if (t < 232) sow1[t - 168] = ow1[t - 168];
    else if (t < 240) sob1[t - 232] = ob1[t - 232];
    else if (t < 248) sow2[t - 240] = ow2[t - 240];
    else if (t == 248) sob2[0] = ob2[0];
  }
  __syncthreads();
  int idx = chunk * 256 + t;
  if (idx >= Nv * 2) return;
  int n = idx >> 1, c4 = idx & 1;
  size_t noff = (size_t)n * Hv + c4 * 4;
  const float4 w4 = nt_load4(tnw + noff);
  const float4 b4 = nt_load4(tnb + noff);
  size_t strideP = (size_t)Nv * Hv;
  size_t base = (size_t)b * Pv * strideP + noff;
  float4 in[12];
  #pragma unroll
  for (int p = 0; p < 12; ++p) {
    float4 v = nt_load4(v2 + base + p * strideP);
    float mean = smean[p], rstd = srstd[p];
    in[p].x = (v.x - mean) * rstd * w4.x + b4.x;
    in[p].y = (v.y - mean) * rstd * w4.y + b4.y;
    in[p].z = (v.z - mean) * rstd * w4.z + b4.z;
    in[p].w = (v.w - mean) * rstd * w4.w + b4.w;
  }
  float ai = a9[iblk + 1];
  #pragma unroll
  for (int q = 0; q < 12; ++q) {
    float4 o = make_float4(scb[q], scb[q], scb[q], scb[q]);
    #pragma unroll
    for (int p = 0; p < 12; ++p) {
      float c = scw[q * 12 + p];
      o.x += c * in[p].x; o.y += c * in[p].y;
      o.z += c * in[p].z; o.w += c * in[p].w;
    }
    size_t off = base + q * strideP;
    float4 av = nt_load4(acc + off);
    float n0 = av.x + ai * o.x, n1 = av.y + ai * o.y;
    float n2 = av.z + ai * o.z, n3 = av.w + ai * o.w;
    if (!last) {
      *(float4*)(v2 + off) = o;
      nt_store4(acc + off, n0, n1, n2, n3);
    } else {
      float e0 = __shfl_xor(n0, 1, 64);
      float e1 = __shfl_xor(n1, 1, 64);
      float e2 = __shfl_xor(n2, 1, 64);
      float e3 = __shfl_xor(n3, 1, 64);
      float a8[8];
      if (c4 == 0) {
        a8[0] = n0; a8[1] = n1; a8[2] = n2; a8[3] = n3;
        a8[4] = e0; a8[5] = e1; a8[6] = e2; a8[7] = e3;
      } else {
        a8[0] = e0; a8[1] = e1; a8[2] = e2; a8[3] = e3;
        a8[4] = n0; a8[5] = n1; a8[6] = n2; a8[7] = n3;
      }
      if (c4 == 0) {
        float oo = sob2[0];
        #pragma unroll
        for (int j = 0; j < 8; ++j) {
          float s = sob1[j];
          #pragma unroll
          for (int k = 0; k < 8; ++k) s += a8[k] * sow1[k * 8 + j];
          oo += fmaxf(s, 0.f) * sow2[j];
        }
        out[((size_t)b * Pv + q) * Nv + n] = oo;
      }
    }
  }
}

extern "C" void kernel_launch(void* const* d_in, const int* in_sizes, int n_in,
                              void* d_out, int out_size, void* d_ws, size_t ws_size,
                              hipStream_t stream) {
  const float* x      = (const float*)d_in[0];
  const float* cond   = (const float*)d_in[1];
  const float* pos    = (const float*)d_in[2];
  const int*   timei  = (const int*)  d_in[3];
  const int*   eidx   = (const int*)  d_in[4];
  const float* te_w1  = (const float*)d_in[5];
  const float* te_b1  = (const float*)d_in[6];
  const float* te_w2  = (const float*)d_in[7];
  const float* te_b2  = (const float*)d_in[8];
  const float* in_w1  = (const float*)d_in[9];
  const float* in_b1  = (const float*)d_in[10];
  const float* in_w2  = (const float*)d_in[11];
  const float* in_b2  = (const float*)d_in[12];
  const float* pos_w1 = (const float*)d_in[13];
  const float* pos_b1 = (const float*)d_in[14];
  const float* pos_w2 = (const float*)d_in[15];
  const float* pos_b2 = (const float*)d_in[16];
  const float* attn   = (const float*)d_in[17];
  const float* bt_w1  = (const float*)d_in[18];
  const float* bt_b1  = (const float*)d_in[19];
  const float* bt_w2  = (const float*)d_in[20];
  const float* bt_b2  = (const float*)d_in[21];
  const float* bc_w1  = (const float*)d_in[22];
  const float* bc_b1  = (const float*)d_in[23];
  const float* bc_w2  = (const float*)d_in[24];
  const float* bc_b2  = (const float*)d_in[25];
  const float* gn_w   = (const float*)d_in[26];
  const float* gn_b   = (const float*)d_in[27];
  const float* tn_w   = (const float*)d_in[28];
  const float* tn_b   = (const float*)d_in[29];
  const float* cv_w   = (const float*)d_in[30];
  const float* cv_b   = (const float*)d_in[31];
  const float* out_w1 = (const float*)d_in[32];
  const float* out_b1 = (const float*)d_in[33];
  const float* out_w2 = (const float*)d_in[34];
  const float* out_b2 = (const float*)d_in[35];
  float* out = (float*)d_out;

  const size_t HSZ = (size_t)Bv * Pv * Nv * Hv;  // 3,840,000
  float* ws    = (float*)d_ws;
  float* X     = ws;                 // v2 buffer
  float* Y     = X + HSZ;            // vt (= gnw ⊙ v1) buffer
  float* acc   = Y + HSZ;
  float* posp  = acc + HSZ;          // Nv*Hv
  float* deg   = posp + Nv * Hv;     // Nv
  float* dinv  = deg + Nv;           // Nv
  float* epack = dinv + Nv;          // 2*Ev floats
  float* t_all = epack + 2 * Ev;     // NBv*Bv*Hv = 512
  float* a9    = t_all + NBv * Bv * Hv;  // 16
  float* stats = a9 + 16;            // NBv*2*NIMG*2 = 3072
  float* Gw    = stats + NBv * 2 * NIMG * 2;  // NBv*Nv*Hv = 320000
  float* Gb    = Gw + NBv * Nv * Hv;          // 320000
  int* row_ptr = (int*)(Gb + NBv * Nv * Hv);  // Nv+8
  int* cursor  = row_ptr + Nv + 8;   // Nv+8

  k_setup<<<1, 512, 0, stream>>>(timei, attn, te_w1, te_b1, te_w2, te_b2,
                                 bt_w1, bt_b1, bt_w2, bt_b2, t_all, a9);
  k_posp_zero<<<(Nv + 255) / 256, 256, 0, stream>>>(
      pos, pos_w1, pos_b1, pos_w2, pos_b2, posp, deg, cursor, stats);
  k_deg<<<(Ev + 255) / 256, 256, 0, stream>>>(eidx, deg);
  k_scan<<<1, 1024, 0, stream>>>(deg, dinv, row_ptr);
  k_csr<<<(Ev + 255) / 256, 256, 0, stream>>>(eidx, dinv, row_ptr, cursor, (float2*)epack);
  k_gwb<<<(NBv * Nv + 255) / 256, 256, 0, stream>>>(
      row_ptr, (const float2*)epack, gn_w, gn_b, Gw, Gb);

  for (int i = 0; i < NBv; ++i) {
    float* st1 = stats + (size_t)(i * 2 + 0) * NIMG * 2;
    float* st2 = stats + (size_t)(i * 2 + 1) * NIMG * 2;
    if (i == 0) {
      k_stage1_init<<<NIMG * BLKS_PER_IMG, 256, 0, stream>>>(
          x, posp, in_w1, in_b1, in_w2, in_b2,
          cond, bc_w1, bc_b1, bc_w2, bc_b2,
          gn_w, a9, acc, Y, st1);
    } else {
      k_stage1<<<NIMG * BLKS_PER_IMG, 256, 0, stream>>>(
          X, cond,
          bc_w1 + i * 64, bc_b1 + i * 8, bc_w2 + i * 64, bc_b2 + i * 8,
          gn_w + (size_t)i * Nv * Hv,
          Y, st1);
    }
    k_stage2<<<8 * 6 * BLKS_PER_IMG, 256, 0, stream>>>(
        Y, X, row_ptr, (const float2*)epack,
        Gw + (size_t)i * Nv * Hv, Gb + (size_t)i * Nv * Hv,
        st1, st2, t_all + i * Bv * Hv);
    k_stage3<<<8 * 40, 256, 0, stream>>>(
        X, acc, st2,
        tn_w + (size_t)i * Nv * Hv, tn_b + (size_t)i * Nv * Hv,
        cv_w + i * 144, cv_b + i * 12, a9, i,
        out_w1, out_b1, out_w2, out_b2, out);
  }
}

// Round 17
// 574.405 us; speedup vs baseline: 1.9090x; 1.0283x over previous
//
#include <hip/hip_runtime.h>
#include <math.h>

#define Bv 8
#define Pv 12
#define Nv 5000
#define Hv 8
#define Ev 50000
#define NBv 8
#define TD1v 64
#define NIMG (Bv * Pv)          // 96 images
#define BLKS_PER_IMG 20         // ceil(5000/256)
#define ECAP 3072               // LDS edge-stage capacity (24 KB)
#define IPT2 2                  // images per thread in stage2

typedef float f4v __attribute__((ext_vector_type(4)));

__device__ inline float4 nt_load4(const float* p) {
  f4v v = __builtin_nontemporal_load((const f4v*)p);
  return make_float4(v.x, v.y, v.z, v.w);
}
__device__ inline void nt_store4(float* p, float a, float b, float c, float d) {
  f4v v = {a, b, c, d};
  __builtin_nontemporal_store(v, (f4v*)p);
}

// correctly-rounded f32 of 10^(d/4), d=0..15 (matches numpy float32 powf)
__device__ __constant__ float POW10Q[16] = {
  1.0f, 1.7782794100389228f, 3.1622776601683795f, 5.623413251903491f,
  10.0f, 17.78279410038923f, 31.622776601683793f, 56.23413251903491f,
  100.0f, 177.82794100389228f, 316.22776601683796f, 562.341325190349f,
  1000.0f, 1778.2794100389228f, 3162.2776601683795f, 5623.413251903491f
};

// ---------------- setup (512 threads): time-embedding chain, t vectors, softmax(attn)
__global__ __launch_bounds__(512) void k_setup(
    const int* timei, const float* attn,
    const float* te_w1, const float* te_b1,
    const float* te_w2, const float* te_b2,
    const float* bt_w1, const float* bt_b1,
    const float* bt_w2, const float* bt_b2,
    float* t_all, float* a9) {
  __shared__ float te0[Bv][32];
  __shared__ float te1[Bv][64];
  __shared__ float te2[Bv][64];
  __shared__ float su[64][8];
  int t = threadIdx.x; // 512
  if (t < 256) {
    int b = t >> 5, k = t & 31;
    int d = k & 15;
    float e = (float)timei[b] * POW10Q[d];   // f32 rounding as in numpy
    te0[b][k] = (k < 16) ? (float)sin((double)e) : (float)cos((double)e);
  }
  __syncthreads();
  {
    int b = t >> 6, j = t & 63;   // 512 outputs
    float s = te_b1[j];
    for (int k = 0; k < 32; ++k) s += te0[b][k] * te_w1[k * 64 + j];
    te1[b][j] = s / (1.0f + expf(-s));       // silu
  }
  __syncthreads();
  {
    int b = t >> 6, j = t & 63;
    float s = te_b2[j];
    for (int k = 0; k < 64; ++k) s += te1[b][k] * te_w2[k * 64 + j];
    te2[b][j] = s / (1.0f + expf(-s));
  }
  __syncthreads();
  {
    int ib = t >> 3, j = t & 7;   // ib = i*8+b, 64 pairs x 8 hidden
    int i = ib >> 3, b = ib & 7;
    float s = bt_b1[i * Hv + j];
    for (int k = 0; k < TD1v; ++k) s += te2[b][k] * bt_w1[(i * TD1v + k) * Hv + j];
    su[ib][j] = fmaxf(s, 0.0f);
  }
  __syncthreads();
  {
    int ib = t >> 3, ch = t & 7;
    int i = ib >> 3, b = ib & 7;
    float s = bt_b2[i * Hv + ch];
    #pragma unroll
    for (int j = 0; j < 8; ++j) s += su[ib][j] * bt_w2[(i * Hv + j) * Hv + ch];
    t_all[(i * Bv + b) * Hv + ch] = s;
  }
  if (t == 0) {
    float m = attn[0];
    for (int i = 1; i < 9; ++i) m = fmaxf(m, attn[i]);
    float s = 0.f, ex[9];
    for (int i = 0; i < 9; ++i) { ex[i] = expf(attn[i] - m); s += ex[i]; }
    for (int i = 0; i < 9; ++i) a9[i] = ex[i] / s;
  }
}

// ---------------- merged: posp projection + zero(deg/cursor/stats)
__global__ void k_posp_zero(const float* pos, const float* pw1, const float* pb1,
                            const float* pw2, const float* pb2, float* posp,
                            float* deg, int* cursor, float* stats) {
  int n = blockIdx.x * blockDim.x + threadIdx.x;
  if (n < Nv) { deg[n] = 0.f; cursor[n] = 0; }
  if (n < NBv * 2 * NIMG * 2) stats[n] = 0.f;
  if (n >= Nv) return;
  const float4* pr = (const float4*)(pos + (size_t)n * Hv);
  float4 r0 = pr[0], r1 = pr[1];
  float x[8] = {r0.x, r0.y, r0.z, r0.w, r1.x, r1.y, r1.z, r1.w};
  float u[8];
  #pragma unroll
  for (int j = 0; j < 8; ++j) {
    float s = pb1[j];
    #pragma unroll
    for (int k = 0; k < 8; ++k) s += x[k] * pw1[k * 8 + j];
    u[j] = fmaxf(s, 0.f);
  }
  float o[8];
  #pragma unroll
  for (int ch = 0; ch < 8; ++ch) {
    float s = pb2[ch];
    #pragma unroll
    for (int j = 0; j < 8; ++j) s += u[j] * pw2[j * 8 + ch];
    o[ch] = s;
  }
  float4* po = (float4*)(posp + (size_t)n * Hv);
  po[0] = make_float4(o[0], o[1], o[2], o[3]);
  po[1] = make_float4(o[4], o[5], o[6], o[7]);
}

__global__ void k_deg(const int* eidx, float* deg) {
  int e = blockIdx.x * blockDim.x + threadIdx.x;
  if (e < Ev) atomicAdd(&deg[eidx[Ev + e]], 1.0f);
}

// single-block: dinv + exclusive scan -> row_ptr[0..Nv] (wave shfl scan)
__global__ __launch_bounds__(1024) void k_scan(const float* deg, float* dinv,
                                               int* row_ptr) {
  __shared__ int wsum[16];
  __shared__ int base_s;
  int t = threadIdx.x;
  int lane = t & 63, wid = t >> 6;
  if (t == 0) { base_s = 0; row_ptr[0] = 0; }
  __syncthreads();
  for (int c = 0; c < 5; ++c) {
    int i = c * 1024 + t;
    float dv = (i < Nv) ? deg[i] : 0.f;
    if (i < Nv)
      dinv[i] = dv > 0.f ? (float)(1.0 / sqrt((double)dv)) : 0.f;
    int v = (int)(dv + 0.5f);
    int s = v;
    #pragma unroll
    for (int off = 1; off < 64; off <<= 1) {
      int up = __shfl_up(s, off, 64);
      if (lane >= off) s += up;
    }
    if (lane == 63) wsum[wid] = s;
    __syncthreads();
    if (wid == 0 && lane < 16) {
      int ws = wsum[lane];
      #pragma unroll
      for (int off = 1; off < 16; off <<= 1) {
        int up = __shfl_up(ws, off, 64);
        if (lane >= off) ws += up;
      }
      wsum[lane] = ws;
    }
    __syncthreads();
    int wbase = (wid > 0) ? wsum[wid - 1] : 0;
    int incl = base_s + wbase + s;
    if (i < Nv) row_ptr[i + 1] = incl;
    __syncthreads();
    if (t == 1023) base_s = incl;
    __syncthreads();
  }
}

// CSR fill: packed (src_bits, w) per edge
__global__ void k_csr(const int* eidx, const float* dinv, const int* row_ptr,
                      int* cursor, float2* epack) {
  int e = blockIdx.x * blockDim.x + threadIdx.x;
  if (e >= Ev) return;
  int s = eidx[e], d = eidx[Ev + e];
  int slot = atomicAdd(&cursor[d], 1);
  int pos = row_ptr[d] + slot;
  epack[pos] = make_float2(__int_as_float(s), dinv[s] * dinv[d]);
}

// ---------------- per block-iter, image-independent: Gw[i][n]=Σ w_e gnw_i[src], Gb likewise
__global__ __launch_bounds__(256) void k_gwb(
    const int* __restrict__ row_ptr, const float2* __restrict__ epack,
    const float* __restrict__ gn_w, const float* __restrict__ gn_b,
    float* __restrict__ Gw, float* __restrict__ Gb) {
  int id = blockIdx.x * 256 + threadIdx.x;
  if (id >= NBv * Nv) return;
  int i = id / Nv, n = id % Nv;
  const float* gw = gn_w + (size_t)i * Nv * Hv;
  const float* gb = gn_b + (size_t)i * Nv * Hv;
  float aw[8] = {0,0,0,0,0,0,0,0}, ab[8] = {0,0,0,0,0,0,0,0};
  int e0 = row_ptr[n], e1 = row_ptr[n + 1];
  for (int e = e0; e < e1; ++e) {
    float2 ep = epack[e];
    int s = __float_as_int(ep.x);
    float w = ep.y;
    const float4* wr = (const float4*)(gw + (size_t)s * Hv);
    const float4* br = (const float4*)(gb + (size_t)s * Hv);
    float4 w0 = wr[0], w1 = wr[1], b0 = br[0], b1 = br[1];
    aw[0] += w * w0.x; aw[1] += w * w0.y; aw[2] += w * w0.z; aw[3] += w * w0.w;
    aw[4] += w * w1.x; aw[5] += w * w1.y; aw[6] += w * w1.z; aw[7] += w * w1.w;
    ab[0] += w * b0.x; ab[1] += w * b0.y; ab[2] += w * b0.z; ab[3] += w * b0.w;
    ab[4] += w * b1.x; ab[5] += w * b1.y; ab[6] += w * b1.z; ab[7] += w * b1.w;
  }
  float4* wo = (float4*)(Gw + (size_t)id * Hv);
  wo[0] = make_float4(aw[0], aw[1], aw[2], aw[3]);
  wo[1] = make_float4(aw[4], aw[5], aw[6], aw[7]);
  float4* bo = (float4*)(Gb + (size_t)id * Hv);
  bo[0] = make_float4(ab[0], ab[1], ab[2], ab[3]);
  bo[1] = make_float4(ab[4], ab[5], ab[6], ab[7]);
}

// block-level reduce of (s1,s2) over 256 threads, then one atomicAdd pair.
__device__ inline void partial_to_stats(float s1, float s2, float* stats_g) {
  #pragma unroll
  for (int off = 32; off > 0; off >>= 1) {
    s1 += __shfl_down(s1, off, 64);
    s2 += __shfl_down(s2, off, 64);
  }
  __shared__ float r1[4], r2[4];
  int wid = threadIdx.x >> 6, lane = threadIdx.x & 63;
  if (lane == 0) { r1[wid] = s1; r2[wid] = s2; }
  __syncthreads();
  if (threadIdx.x == 0) {
    float a = r1[0] + r1[1] + r1[2] + r1[3];
    float b = r2[0] + r2[1] + r2[2] + r2[3];
    atomicAdd(&stats_g[0], a);
    atomicAdd(&stats_g[1], b);
  }
  __syncthreads();
}

// XCD-locality swizzle: blockIdx%8 = XCD; image g = xcd*12 + local/20
__device__ inline void img_swizzle(int bx, int& g, int& chunk) {
  int xcd = bx & 7;
  int local = bx >> 3;
  g = xcd * 12 + local / BLKS_PER_IMG;
  chunk = local % BLKS_PER_IMG;
}

// ---------------- stage 1 (i>=1): v1 = h + proj(cond); vt = gnw ⊙ v1; stats over v1
__global__ __launch_bounds__(256) void k_stage1(
    const float* __restrict__ h, const float* __restrict__ cond,
    const float* w1, const float* b1, const float* w2, const float* b2,
    const float* __restrict__ gnw,
    float* __restrict__ vt, float* stats1) {
  __shared__ float lw1[64], lw2[64], lb1[8], lb2[8];
  int t = threadIdx.x;
  if (t < 64) lw1[t] = w1[t];
  else if (t < 128) lw2[t - 64] = w2[t - 64];
  else if (t < 136) lb1[t - 128] = b1[t - 128];
  else if (t < 144) lb2[t - 136] = b2[t - 136];
  __syncthreads();
  int g, chunk;
  img_swizzle(blockIdx.x, g, chunk);
  int n = chunk * 256 + t;
  float s1 = 0.f, s2 = 0.f;
  if (n < Nv) {
    size_t row = ((size_t)g * Nv + n) * Hv;
    float4 c0 = nt_load4(cond + row);
    float4 c1 = nt_load4(cond + row + 4);
    float xc[8] = {c0.x, c0.y, c0.z, c0.w, c1.x, c1.y, c1.z, c1.w};
    float u[8];
    #pragma unroll
    for (int j = 0; j < 8; ++j) {
      float s = lb1[j];
      #pragma unroll
      for (int k = 0; k < 8; ++k) s += xc[k] * lw1[k * 8 + j];
      u[j] = fmaxf(s, 0.f);
    }
    const float4* hr = (const float4*)(h + row);
    float4 h0 = hr[0], h1 = hr[1];
    float hv[8] = {h0.x, h0.y, h0.z, h0.w, h1.x, h1.y, h1.z, h1.w};
    const float4* gr = (const float4*)(gnw + (size_t)n * Hv);
    float4 g0 = gr[0], g1 = gr[1];
    float gv[8] = {g0.x, g0.y, g0.z, g0.w, g1.x, g1.y, g1.z, g1.w};
    float o[8];
    #pragma unroll
    for (int ch = 0; ch < 8; ++ch) {
      float s = lb2[ch];
      #pragma unroll
      for (int j = 0; j < 8; ++j) s += u[j] * lw2[j * 8 + ch];
      float val = s + hv[ch];
      s1 += val; s2 += val * val;
      o[ch] = val * gv[ch];
    }
    float4* vo = (float4*)(vt + row);
    vo[0] = make_float4(o[0], o[1], o[2], o[3]);
    vo[1] = make_float4(o[4], o[5], o[6], o[7]);
  }
  partial_to_stats(s1, s2, stats1 + (size_t)g * 2);
}

// ---------------- fused k_init + stage1 for i=0
__global__ __launch_bounds__(256) void k_stage1_init(
    const float* __restrict__ x, const float* __restrict__ posp,
    const float* iw1, const float* ib1, const float* iw2, const float* ib2,
    const float* __restrict__ cond,
    const float* w1, const float* b1, const float* w2, const float* b2,
    const float* __restrict__ gnw, const float* __restrict__ a9,
    float* __restrict__ acc,
    float* __restrict__ vt, float* stats1) {
  __shared__ float lw1[64], lw2[64], lb1[8], lb2[8];
  __shared__ float li1[8], li2[64], lib1[8], lib2[8];
  int t = threadIdx.x;
  if (t < 64) lw1[t] = w1[t];
  else if (t < 128) lw2[t - 64] = w2[t - 64];
  else if (t < 136) lb1[t - 128] = b1[t - 128];
  else if (t < 144) lb2[t - 136] = b2[t - 136];
  else if (t < 152) li1[t - 144] = iw1[t - 144];
  else if (t < 216) li2[t - 152] = iw2[t - 152];
  else if (t < 224) lib1[t - 216] = ib1[t - 216];
  else if (t < 232) lib2[t - 224] = ib2[t - 224];
  __syncthreads();
  int g, chunk;
  img_swizzle(blockIdx.x, g, chunk);
  int n = chunk * 256 + t;
  float s1 = 0.f, s2 = 0.f;
  if (n < Nv) {
    size_t row = ((size_t)g * Nv + n) * Hv;
    float xv = __builtin_nontemporal_load(x + (size_t)g * Nv + n);
    float ui[8];
    #pragma unroll
    for (int j = 0; j < 8; ++j) ui[j] = fmaxf(xv * li1[j] + lib1[j], 0.f);
    const float4* pp = (const float4*)(posp + (size_t)n * Hv);
    float4 p0 = pp[0], p1 = pp[1];
    float pv[8] = {p0.x, p0.y, p0.z, p0.w, p1.x, p1.y, p1.z, p1.w};
    float hv[8];
    #pragma unroll
    for (int ch = 0; ch < 8; ++ch) {
      float s = lib2[ch];
      #pragma unroll
      for (int j = 0; j < 8; ++j) s += ui[j] * li2[j * 8 + ch];
      hv[ch] = s + pv[ch];
    }
    float a0 = a9[0];
    float4* ar = (float4*)(acc + row);           // acc cached (L2, XCD-local)
    ar[0] = make_float4(a0 * hv[0], a0 * hv[1], a0 * hv[2], a0 * hv[3]);
    ar[1] = make_float4(a0 * hv[4], a0 * hv[5], a0 * hv[6], a0 * hv[7]);
    float4 c0 = nt_load4(cond + row);
    float4 c1 = nt_load4(cond + row + 4);
    float xc[8] = {c0.x, c0.y, c0.z, c0.w, c1.x, c1.y, c1.z, c1.w};
    float u[8];
    #pragma unroll
    for (int j = 0; j < 8; ++j) {
      float s = lb1[j];
      #pragma unroll
      for (int k = 0; k < 8; ++k) s += xc[k] * lw1[k * 8 + j];
      u[j] = fmaxf(s, 0.f);
    }
    const float4* gr = (const float4*)(gnw + (size_t)n * Hv);
    float4 g0 = gr[0], g1 = gr[1];
    float gv[8] = {g0.x, g0.y, g0.z, g0.w, g1.x, g1.y, g1.z, g1.w};
    float o[8];
    #pragma unroll
    for (int ch = 0; ch < 8; ++ch) {
      float s = lb2[ch];
      #pragma unroll
      for (int j = 0; j < 8; ++j) s += u[j] * lw2[j * 8 + ch];
      float val = s + hv[ch];
      s1 += val; s2 += val * val;
      o[ch] = val * gv[ch];
    }
    float4* vo = (float4*)(vt + row);
    vo[0] = make_float4(o[0], o[1], o[2], o[3]);
    vo[1] = make_float4(o[4], o[5], o[6], o[7]);
  }
  partial_to_stats(s1, s2, stats1 + (size_t)g * 2);
}

// ---------------- stage 2: v2 = rstd*SpMM(vt) - mean*rstd*Gw + Gb + t; stats2
// IPT2=2 images/thread, 4-edge unroll: 8 independent 32B gathers in flight.
__global__ __launch_bounds__(256) void k_stage2(
    const float* __restrict__ vt, float* __restrict__ v2,
    const int* __restrict__ row_ptr, const float2* __restrict__ epack,
    const float* __restrict__ Gw, const float* __restrict__ Gb,
    const float* __restrict__ stats1, float* stats2,
    const float* __restrict__ tvec) {
  __shared__ float2 se[ECAP];
  int t = threadIdx.x;
  int b = blockIdx.x & 7;
  int local = blockIdx.x >> 3;
  int pair = local % 6;
  int chunk = local / 6;
  int g0 = b * Pv + pair * IPT2;
  int nb0 = chunk * 256;
  int nb1 = nb0 + 256; if (nb1 > Nv) nb1 = Nv;
  int eb0 = row_ptr[nb0];
  int eb1 = row_ptr[nb1];
  int cnt = eb1 - eb0;
  const float2* eps;
  int ebase;
  if (cnt <= ECAP) {
    for (int k = t; k < cnt; k += 256) se[k] = epack[eb0 + k];
    eps = se; ebase = eb0;
  } else {
    eps = epack; ebase = 0;
  }
  __syncthreads();
  float mean[IPT2], rstd[IPT2], mrs[IPT2];
  #pragma unroll
  for (int j = 0; j < IPT2; ++j) {
    float m  = stats1[(g0 + j) * 2]     * (1.f / 40000.f);
    float m2 = stats1[(g0 + j) * 2 + 1] * (1.f / 40000.f);
    float var = m2 - m * m;
    mean[j] = m;
    rstd[j] = (float)(1.0 / sqrt((double)var + 1e-5));
    mrs[j]  = m * rstd[j];
  }
  int n = nb0 + t;
  float s1a[IPT2], s2a[IPT2];
  #pragma unroll
  for (int j = 0; j < IPT2; ++j) { s1a[j] = 0.f; s2a[j] = 0.f; }
  if (n < Nv) {
    const float* vt0 = vt + (size_t)(g0 + 0) * Nv * Hv;
    const float* vt1 = vt + (size_t)(g0 + 1) * Nv * Hv;
    float a[IPT2][8];
    #pragma unroll
    for (int j = 0; j < IPT2; ++j)
      #pragma unroll
      for (int ch = 0; ch < 8; ++ch) a[j][ch] = 0.f;
    int e0 = row_ptr[n] - ebase, e1 = row_ptr[n + 1] - ebase;
    int e = e0;
    for (; e + 4 <= e1; e += 4) {
      float2 p0 = eps[e], p1 = eps[e + 1], p2 = eps[e + 2], p3 = eps[e + 3];
      size_t so0 = (size_t)__float_as_int(p0.x) * Hv;
      size_t so1 = (size_t)__float_as_int(p1.x) * Hv;
      size_t so2 = (size_t)__float_as_int(p2.x) * Hv;
      size_t so3 = (size_t)__float_as_int(p3.x) * Hv;
      const float4* q00 = (const float4*)(vt0 + so0);
      const float4* q01 = (const float4*)(vt1 + so0);
      const float4* q10 = (const float4*)(vt0 + so1);
      const float4* q11 = (const float4*)(vt1 + so1);
      const float4* q20 = (const float4*)(vt0 + so2);
      const float4* q21 = (const float4*)(vt1 + so2);
      const float4* q30 = (const float4*)(vt0 + so3);
      const float4* q31 = (const float4*)(vt1 + so3);
      float4 a00 = q00[0], b00 = q00[1];
      float4 a01 = q01[0], b01 = q01[1];
      float4 a10 = q10[0], b10 = q10[1];
      float4 a11 = q11[0], b11 = q11[1];
      float4 a20 = q20[0], b20 = q20[1];
      float4 a21 = q21[0], b21 = q21[1];
      float4 a30 = q30[0], b30 = q30[1];
      float4 a31 = q31[0], b31 = q31[1];
      a[0][0] += p0.y*a00.x + p1.y*a10.x + p2.y*a20.x + p3.y*a30.x;
      a[0][1] += p0.y*a00.y + p1.y*a10.y + p2.y*a20.y + p3.y*a30.y;
      a[0][2] += p0.y*a00.z + p1.y*a10.z + p2.y*a20.z + p3.y*a30.z;
      a[0][3] += p0.y*a00.w + p1.y*a10.w + p2.y*a20.w + p3.y*a30.w;
      a[0][4] += p0.y*b00.x + p1.y*b10.x + p2.y*b20.x + p3.y*b30.x;
      a[0][5] += p0.y*b00.y + p1.y*b10.y + p2.y*b20.y + p3.y*b30.y;
      a[0][6] += p0.y*b00.z + p1.y*b10.z + p2.y*b20.z + p3.y*b30.z;
      a[0][7] += p0.y*b00.w + p1.y*b10.w + p2.y*b20.w + p3.y*b30.w;
      a[1][0] += p0.y*a01.x + p1.y*a11.x + p2.y*a21.x + p3.y*a31.x;
      a[1][1] += p0.y*a01.y + p1.y*a11.y + p2.y*a21.y + p3.y*a31.y;
      a[1][2] += p0.y*a01.z + p1.y*a11.z + p2.y*a21.z + p3.y*a31.z;
      a[1][3] += p0.y*a01.w + p1.y*a11.w + p2.y*a21.w + p3.y*a31.w;
      a[1][4] += p0.y*b01.x + p1.y*b11.x + p2.y*b21.x + p3.y*b31.x;
      a[1][5] += p0.y*b01.y + p1.y*b11.y + p2.y*b21.y + p3.y*b31.y;
      a[1][6] += p0.y*b01.z + p1.y*b11.z + p2.y*b21.z + p3.y*b31.z;
      a[1][7] += p0.y*b01.w + p1.y*b11.w + p2.y*b21.w + p3.y*b31.w;
    }
    for (; e < e1; ++e) {
      float2 ep = eps[e];
      float w = ep.y;
      size_t so = (size_t)__float_as_int(ep.x) * Hv;
      const float4* r0 = (const float4*)(vt0 + so);
      const float4* r1 = (const float4*)(vt1 + so);
      float4 xa = r0[0], xb = r0[1];
      float4 ya = r1[0], yb = r1[1];
      a[0][0] += w*xa.x; a[0][1] += w*xa.y; a[0][2] += w*xa.z; a[0][3] += w*xa.w;
      a[0][4] += w*xb.x; a[0][5] += w*xb.y; a[0][6] += w*xb.z; a[0][7] += w*xb.w;
      a[1][0] += w*ya.x; a[1][1] += w*ya.y; a[1][2] += w*ya.z; a[1][3] += w*ya.w;
      a[1][4] += w*yb.x; a[1][5] += w*yb.y; a[1][6] += w*yb.z; a[1][7] += w*yb.w;
    }
    size_t noff = (size_t)n * Hv;
    const float4* wr = (const float4*)(Gw + noff);
    const float4* br = (const float4*)(Gb + noff);
    float4 w0 = wr[0], w1 = wr[1], b0 = br[0], b1 = br[1];
    float gw8[8] = {w0.x, w0.y, w0.z, w0.w, w1.x, w1.y, w1.z, w1.w};
    float gb8[8] = {b0.x, b0.y, b0.z, b0.w, b1.x, b1.y, b1.z, b1.w};
    float tl[8];
    {
      const float4* tr = (const float4*)(tvec + b * Hv);
      float4 t0 = tr[0], t1 = tr[1];
      tl[0] = t0.x; tl[1] = t0.y; tl[2] = t0.z; tl[3] = t0.w;
      tl[4] = t1.x; tl[5] = t1.y; tl[6] = t1.z; tl[7] = t1.w;
    }
    #pragma unroll
    for (int j = 0; j < IPT2; ++j) {
      float o[8];
      #pragma unroll
      for (int ch = 0; ch < 8; ++ch) {
        float val = rstd[j] * a[j][ch] - mrs[j] * gw8[ch] + gb8[ch] + tl[ch];
        o[ch] = val;
        s1a[j] += val; s2a[j] += val * val;
      }
      float* vo = v2 + (size_t)(g0 + j) * Nv * Hv + noff;
      nt_store4(vo,     o[0], o[1], o[2], o[3]);
      nt_store4(vo + 4, o[4], o[5], o[6], o[7]);
    }
  }
  #pragma unroll
  for (int j = 0; j < IPT2; ++j)
    partial_to_stats(s1a[j], s2a[j], stats2 + (size_t)(g0 + j) * 2);
}

// ---------------- stage 3: LN(v2) + conv + skip acc (cached); last iter fuses output proj
__global__ __launch_bounds__(256) void k_stage3(
    float* __restrict__ v2, float* __restrict__ acc,
    const float* __restrict__ stats2,
    const float* __restrict__ tnw, const float* __restrict__ tnb,
    const float* __restrict__ cw, const float* __restrict__ cb,
    const float* __restrict__ a9, int iblk,
    const float* __restrict__ ow1, const float* __restrict__ ob1,
    const float* __restrict__ ow2, const float* __restrict__ ob2,
    float* __restrict__ out) {
  __shared__ float scw[144], scb[12], smean[12], srstd[12];
  __shared__ float sow1[64], sob1[8], sow2[8], sob2[1];
  int t = threadIdx.x;
  int b = blockIdx.x & 7;
  int chunk = blockIdx.x >> 3;
  bool last = (iblk == NBv - 1);
  if (t < 144) scw[t] = cw[t];
  else if (t < 156) scb[t - 144] = cb[t - 144];
  else if (t < 168) {
    int p = t - 156;
    int g = b * Pv + p;
    float mean = stats2[g * 2]     * (1.f / 40000.f);
    float m2   = stats2[g * 2 + 1] * (1.f / 40000.f);
    float var  = m2 - mean * mean;
    smean[p] = mean;
    srstd[p] = (float)(1.0 / sqrt((double)var + 1e-5));
  } else if (last) {
    if (t < 232) sow1[t - 168] = ow1[t - 168];
    else if (t < 240) sob1[t - 232] = ob1[t - 232];
    else if (t < 248) sow2[t - 240] = ow2[t - 240];
    else if (t == 248) sob2[0] = ob2[0];
  }
  __syncthreads();
  int idx = chunk * 256 + t;
  if (idx >= Nv * 2) return;
  int n = idx >> 1, c4 = idx & 1;
  size_t noff = (size_t)n * Hv + c4 * 4;
  const float4 w4 = nt_load4(tnw + noff);
  const float4 b4 = nt_load4(tnb + noff);
  size_t strideP = (size_t)Nv * Hv;
  size_t base = (size_t)b * Pv * strideP + noff;
  float4 in[12];
  #pragma unroll
  for (int p = 0; p < 12; ++p) {
    float4 v = nt_load4(v2 + base + p * strideP);
    float mean = smean[p], rstd = srstd[p];
    in[p].x = (v.x - mean) * rstd * w4.x + b4.x;
    in[p].y = (v.y - mean) * rstd * w4.y + b4.y;
    in[p].z = (v.z - mean) * rstd * w4.z + b4.z;
    in[p].w = (v.w - mean) * rstd * w4.w + b4.w;
  }
  float ai = a9[iblk + 1];
  #pragma unroll
  for (int q = 0; q < 12; ++q) {
    float4 o = make_float4(scb[q], scb[q], scb[q], scb[q]);
    #pragma unroll
    for (int p = 0; p < 12; ++p) {
      float c = scw[q * 12 + p];
      o.x += c * in[p].x; o.y += c * in[p].y;
      o.z += c * in[p].z; o.w += c * in[p].w;
    }
    size_t off = base + q * strideP;
    float4* ap = (float4*)(acc + off);   // acc cached: XCD-local, fits L2
    float4 av = *ap;
    float n0 = av.x + ai * o.x, n1 = av.y + ai * o.y;
    float n2 = av.z + ai * o.z, n3 = av.w + ai * o.w;
    if (!last) {
      *(float4*)(v2 + off) = o;
      *ap = make_float4(n0, n1, n2, n3);
    } else {
      float e0 = __shfl_xor(n0, 1, 64);
      float e1 = __shfl_xor(n1, 1, 64);
      float e2 = __shfl_xor(n2, 1, 64);
      float e3 = __shfl_xor(n3, 1, 64);
      float a8[8];
      if (c4 == 0) {
        a8[0] = n0; a8[1] = n1; a8[2] = n2; a8[3] = n3;
        a8[4] = e0; a8[5] = e1; a8[6] = e2; a8[7] = e3;
      } else {
        a8[0] = e0; a8[1] = e1; a8[2] = e2; a8[3] = e3;
        a8[4] = n0; a8[5] = n1; a8[6] = n2; a8[7] = n3;
      }
      if (c4 == 0) {
        float oo = sob2[0];
        #pragma unroll
        for (int j = 0; j < 8; ++j) {
          float s = sob1[j];
          #pragma unroll
          for (int k = 0; k < 8; ++k) s += a8[k] * sow1[k * 8 + j];
          oo += fmaxf(s, 0.f) * sow2[j];
        }
        out[((size_t)b * Pv + q) * Nv + n] = oo;
      }
    }
  }
}

extern "C" void kernel_launch(void* const* d_in, const int* in_sizes, int n_in,
                              void* d_out, int out_size, void* d_ws, size_t ws_size,
                              hipStream_t stream) {
  const float* x      = (const float*)d_in[0];
  const float* cond   = (const float*)d_in[1];
  const float* pos    = (const float*)d_in[2];
  const int*   timei  = (const int*)  d_in[3];
  const int*   eidx   = (const int*)  d_in[4];
  const float* te_w1  = (const float*)d_in[5];
  const float* te_b1  = (const float*)d_in[6];
  const float* te_w2  = (const float*)d_in[7];
  const float* te_b2  = (const float*)d_in[8];
  const float* in_w1  = (const float*)d_in[9];
  const float* in_b1  = (const float*)d_in[10];
  const float* in_w2  = (const float*)d_in[11];
  const float* in_b2  = (const float*)d_in[12];
  const float* pos_w1 = (const float*)d_in[13];
  const float* pos_b1 = (const float*)d_in[14];
  const float* pos_w2 = (const float*)d_in[15];
  const float* pos_b2 = (const float*)d_in[16];
  const float* attn   = (const float*)d_in[17];
  const float* bt_w1  = (const float*)d_in[18];
  const float* bt_b1  = (const float*)d_in[19];
  const float* bt_w2  = (const float*)d_in[20];
  const float* bt_b2  = (const float*)d_in[21];
  const float* bc_w1  = (const float*)d_in[22];
  const float* bc_b1  = (const float*)d_in[23];
  const float* bc_w2  = (const float*)d_in[24];
  const float* bc_b2  = (const float*)d_in[25];
  const float* gn_w   = (const float*)d_in[26];
  const float* gn_b   = (const float*)d_in[27];
  const float* tn_w   = (const float*)d_in[28];
  const float* tn_b   = (const float*)d_in[29];
  const float* cv_w   = (const float*)d_in[30];
  const float* cv_b   = (const float*)d_in[31];
  const float* out_w1 = (const float*)d_in[32];
  const float* out_b1 = (const float*)d_in[33];
  const float* out_w2 = (const float*)d_in[34];
  const float* out_b2 = (const float*)d_in[35];
  float* out = (float*)d_out;

  const size_t HSZ = (size_t)Bv * Pv * Nv * Hv;  // 3,840,000
  float* ws    = (float*)d_ws;
  float* X     = ws;                 // v2 buffer
  float* Y     = X + HSZ;            // vt (= gnw ⊙ v1) buffer
  float* acc   = Y + HSZ;
  float* posp  = acc + HSZ;          // Nv*Hv
  float* deg   = posp + Nv * Hv;     // Nv
  float* dinv  = deg + Nv;           // Nv
  float* epack = dinv + Nv;          // 2*Ev floats
  float* t_all = epack + 2 * Ev;     // NBv*Bv*Hv = 512
  float* a9    = t_all + NBv * Bv * Hv;  // 16
  float* stats = a9 + 16;            // NBv*2*NIMG*2 = 3072
  float* Gw    = stats + NBv * 2 * NIMG * 2;  // NBv*Nv*Hv = 320000
  float* Gb    = Gw + NBv * Nv * Hv;          // 320000
  int* row_ptr = (int*)(Gb + NBv * Nv * Hv);  // Nv+8
  int* cursor  = row_ptr + Nv + 8;   // Nv+8

  k_setup<<<1, 512, 0, stream>>>(timei, attn, te_w1, te_b1, te_w2, te_b2,
                                 bt_w1, bt_b1, bt_w2, bt_b2, t_all, a9);
  k_posp_zero<<<(Nv + 255) / 256, 256, 0, stream>>>(
      pos, pos_w1, pos_b1, pos_w2, pos_b2, posp, deg, cursor, stats);
  k_deg<<<(Ev + 255) / 256, 256, 0, stream>>>(eidx, deg);
  k_scan<<<1, 1024, 0, stream>>>(deg, dinv, row_ptr);
  k_csr<<<(Ev + 255) / 256, 256, 0, stream>>>(eidx, dinv, row_ptr, cursor, (float2*)epack);
  k_gwb<<<(NBv * Nv + 255) / 256, 256, 0, stream>>>(
      row_ptr, (const float2*)epack, gn_w, gn_b, Gw, Gb);

  for (int i = 0; i < NBv; ++i) {
    float* st1 = stats + (size_t)(i * 2 + 0) * NIMG * 2;
    float* st2 = stats + (size_t)(i * 2 + 1) * NIMG * 2;
    if (i == 0) {
      k_stage1_init<<<NIMG * BLKS_PER_IMG, 256, 0, stream>>>(
          x, posp, in_w1, in_b1, in_w2, in_b2,
          cond, bc_w1, bc_b1, bc_w2, bc_b2,
          gn_w, a9, acc, Y, st1);
    } else {
      k_stage1<<<NIMG * BLKS_PER_IMG, 256, 0, stream>>>(
          X, cond,
          bc_w1 + i * 64, bc_b1 + i * 8, bc_w2 + i * 64, bc_b2 + i * 8,
          gn_w + (size_t)i * Nv * Hv,
          Y, st1);
    }
    k_stage2<<<8 * 6 * BLKS_PER_IMG, 256, 0, stream>>>(
        Y, X, row_ptr, (const float2*)epack,
        Gw + (size_t)i * Nv * Hv, Gb + (size_t)i * Nv * Hv,
        st1, st2, t_all + i * Bv * Hv);
    k_stage3<<<8 * 40, 256, 0, stream>>>(
        X, acc, st2,
        tn_w + (size_t)i * Nv * Hv, tn_b + (size_t)i * Nv * Hv,
        cv_w + i * 144, cv_b + i * 12, a9, i,
        out_w1, out_b1, out_w2, out_b2, out);
  }
}

// Round 18
// 553.840 us; speedup vs baseline: 1.9799x; 1.0371x over previous
//
#include <hip/hip_runtime.h>
#include <math.h>

#define Bv 8
#define Pv 12
#define Nv 5000
#define Hv 8
#define Ev 50000
#define NBv 8
#define TD1v 64
#define NIMG (Bv * Pv)          // 96 images
#define BLKS_PER_IMG 20         // ceil(5000/256)
#define CHUNKS1 10              // stage1: 512-node chunks
#define ECAP 3072               // LDS edge-stage capacity (24 KB)
#define IPT2 2                  // images per thread in stage2
#define EU 8                    // stage2 edge unroll

typedef float f4v __attribute__((ext_vector_type(4)));

__device__ inline float4 nt_load4(const float* p) {
  f4v v = __builtin_nontemporal_load((const f4v*)p);
  return make_float4(v.x, v.y, v.z, v.w);
}
__device__ inline void nt_store4(float* p, float a, float b, float c, float d) {
  f4v v = {a, b, c, d};
  __builtin_nontemporal_store(v, (f4v*)p);
}

// correctly-rounded f32 of 10^(d/4), d=0..15 (matches numpy float32 powf)
__device__ __constant__ float POW10Q[16] = {
  1.0f, 1.7782794100389228f, 3.1622776601683795f, 5.623413251903491f,
  10.0f, 17.78279410038923f, 31.622776601683793f, 56.23413251903491f,
  100.0f, 177.82794100389228f, 316.22776601683796f, 562.341325190349f,
  1000.0f, 1778.2794100389228f, 3162.2776601683795f, 5623.413251903491f
};

// ---------------- setup (512 threads)
__global__ __launch_bounds__(512) void k_setup(
    const int* timei, const float* attn,
    const float* te_w1, const float* te_b1,
    const float* te_w2, const float* te_b2,
    const float* bt_w1, const float* bt_b1,
    const float* bt_w2, const float* bt_b2,
    float* t_all, float* a9) {
  __shared__ float te0[Bv][32];
  __shared__ float te1[Bv][64];
  __shared__ float te2[Bv][64];
  __shared__ float su[64][8];
  int t = threadIdx.x; // 512
  if (t < 256) {
    int b = t >> 5, k = t & 31;
    int d = k & 15;
    float e = (float)timei[b] * POW10Q[d];
    te0[b][k] = (k < 16) ? (float)sin((double)e) : (float)cos((double)e);
  }
  __syncthreads();
  {
    int b = t >> 6, j = t & 63;
    float s = te_b1[j];
    for (int k = 0; k < 32; ++k) s += te0[b][k] * te_w1[k * 64 + j];
    te1[b][j] = s / (1.0f + expf(-s));
  }
  __syncthreads();
  {
    int b = t >> 6, j = t & 63;
    float s = te_b2[j];
    for (int k = 0; k < 64; ++k) s += te1[b][k] * te_w2[k * 64 + j];
    te2[b][j] = s / (1.0f + expf(-s));
  }
  __syncthreads();
  {
    int ib = t >> 3, j = t & 7;
    int i = ib >> 3, b = ib & 7;
    float s = bt_b1[i * Hv + j];
    for (int k = 0; k < TD1v; ++k) s += te2[b][k] * bt_w1[(i * TD1v + k) * Hv + j];
    su[ib][j] = fmaxf(s, 0.0f);
  }
  __syncthreads();
  {
    int ib = t >> 3, ch = t & 7;
    int i = ib >> 3, b = ib & 7;
    float s = bt_b2[i * Hv + ch];
    #pragma unroll
    for (int j = 0; j < 8; ++j) s += su[ib][j] * bt_w2[(i * Hv + j) * Hv + ch];
    t_all[(i * Bv + b) * Hv + ch] = s;
  }
  if (t == 0) {
    float m = attn[0];
    for (int i = 1; i < 9; ++i) m = fmaxf(m, attn[i]);
    float s = 0.f, ex[9];
    for (int i = 0; i < 9; ++i) { ex[i] = expf(attn[i] - m); s += ex[i]; }
    for (int i = 0; i < 9; ++i) a9[i] = ex[i] / s;
  }
}

// ---------------- merged: posp projection + zero(deg/cursor/stats)
__global__ void k_posp_zero(const float* pos, const float* pw1, const float* pb1,
                            const float* pw2, const float* pb2, float* posp,
                            float* deg, int* cursor, float* stats) {
  int n = blockIdx.x * blockDim.x + threadIdx.x;
  if (n < Nv) { deg[n] = 0.f; cursor[n] = 0; }
  if (n < NBv * 2 * NIMG * 2) stats[n] = 0.f;
  if (n >= Nv) return;
  const float4* pr = (const float4*)(pos + (size_t)n * Hv);
  float4 r0 = pr[0], r1 = pr[1];
  float x[8] = {r0.x, r0.y, r0.z, r0.w, r1.x, r1.y, r1.z, r1.w};
  float u[8];
  #pragma unroll
  for (int j = 0; j < 8; ++j) {
    float s = pb1[j];
    #pragma unroll
    for (int k = 0; k < 8; ++k) s += x[k] * pw1[k * 8 + j];
    u[j] = fmaxf(s, 0.f);
  }
  float o[8];
  #pragma unroll
  for (int ch = 0; ch < 8; ++ch) {
    float s = pb2[ch];
    #pragma unroll
    for (int j = 0; j < 8; ++j) s += u[j] * pw2[j * 8 + ch];
    o[ch] = s;
  }
  float4* po = (float4*)(posp + (size_t)n * Hv);
  po[0] = make_float4(o[0], o[1], o[2], o[3]);
  po[1] = make_float4(o[4], o[5], o[6], o[7]);
}

__global__ void k_deg(const int* eidx, float* deg) {
  int e = blockIdx.x * blockDim.x + threadIdx.x;
  if (e < Ev) atomicAdd(&deg[eidx[Ev + e]], 1.0f);
}

// single-block: dinv + exclusive scan -> row_ptr[0..Nv] (wave shfl scan)
__global__ __launch_bounds__(1024) void k_scan(const float* deg, float* dinv,
                                               int* row_ptr) {
  __shared__ int wsum[16];
  __shared__ int base_s;
  int t = threadIdx.x;
  int lane = t & 63, wid = t >> 6;
  if (t == 0) { base_s = 0; row_ptr[0] = 0; }
  __syncthreads();
  for (int c = 0; c < 5; ++c) {
    int i = c * 1024 + t;
    float dv = (i < Nv) ? deg[i] : 0.f;
    if (i < Nv)
      dinv[i] = dv > 0.f ? (float)(1.0 / sqrt((double)dv)) : 0.f;
    int v = (int)(dv + 0.5f);
    int s = v;
    #pragma unroll
    for (int off = 1; off < 64; off <<= 1) {
      int up = __shfl_up(s, off, 64);
      if (lane >= off) s += up;
    }
    if (lane == 63) wsum[wid] = s;
    __syncthreads();
    if (wid == 0 && lane < 16) {
      int ws = wsum[lane];
      #pragma unroll
      for (int off = 1; off < 16; off <<= 1) {
        int up = __shfl_up(ws, off, 64);
        if (lane >= off) ws += up;
      }
      wsum[lane] = ws;
    }
    __syncthreads();
    int wbase = (wid > 0) ? wsum[wid - 1] : 0;
    int incl = base_s + wbase + s;
    if (i < Nv) row_ptr[i + 1] = incl;
    __syncthreads();
    if (t == 1023) base_s = incl;
    __syncthreads();
  }
}

// CSR fill: packed (src_bits, w) per edge
__global__ void k_csr(const int* eidx, const float* dinv, const int* row_ptr,
                      int* cursor, float2* epack) {
  int e = blockIdx.x * blockDim.x + threadIdx.x;
  if (e >= Ev) return;
  int s = eidx[e], d = eidx[Ev + e];
  int slot = atomicAdd(&cursor[d], 1);
  int pos = row_ptr[d] + slot;
  epack[pos] = make_float2(__int_as_float(s), dinv[s] * dinv[d]);
}

// ---------------- per block-iter: Gw[i][n]=Σ w_e gnw_i[src], Gb likewise
__global__ __launch_bounds__(256) void k_gwb(
    const int* __restrict__ row_ptr, const float2* __restrict__ epack,
    const float* __restrict__ gn_w, const float* __restrict__ gn_b,
    float* __restrict__ Gw, float* __restrict__ Gb) {
  int id = blockIdx.x * 256 + threadIdx.x;
  if (id >= NBv * Nv) return;
  int i = id / Nv, n = id % Nv;
  const float* gw = gn_w + (size_t)i * Nv * Hv;
  const float* gb = gn_b + (size_t)i * Nv * Hv;
  float aw[8] = {0,0,0,0,0,0,0,0}, ab[8] = {0,0,0,0,0,0,0,0};
  int e0 = row_ptr[n], e1 = row_ptr[n + 1];
  for (int e = e0; e < e1; ++e) {
    float2 ep = epack[e];
    int s = __float_as_int(ep.x);
    float w = ep.y;
    const float4* wr = (const float4*)(gw + (size_t)s * Hv);
    const float4* br = (const float4*)(gb + (size_t)s * Hv);
    float4 w0 = wr[0], w1 = wr[1], b0 = br[0], b1 = br[1];
    aw[0] += w * w0.x; aw[1] += w * w0.y; aw[2] += w * w0.z; aw[3] += w * w0.w;
    aw[4] += w * w1.x; aw[5] += w * w1.y; aw[6] += w * w1.z; aw[7] += w * w1.w;
    ab[0] += w * b0.x; ab[1] += w * b0.y; ab[2] += w * b0.z; ab[3] += w * b0.w;
    ab[4] += w * b1.x; ab[5] += w * b1.y; ab[6] += w * b1.z; ab[7] += w * b1.w;
  }
  float4* wo = (float4*)(Gw + (size_t)id * Hv);
  wo[0] = make_float4(aw[0], aw[1], aw[2], aw[3]);
  wo[1] = make_float4(aw[4], aw[5], aw[6], aw[7]);
  float4* bo = (float4*)(Gb + (size_t)id * Hv);
  bo[0] = make_float4(ab[0], ab[1], ab[2], ab[3]);
  bo[1] = make_float4(ab[4], ab[5], ab[6], ab[7]);
}

// block-level reduce of (s1,s2) over 256 threads, then one atomicAdd pair.
__device__ inline void partial_to_stats(float s1, float s2, float* stats_g) {
  #pragma unroll
  for (int off = 32; off > 0; off >>= 1) {
    s1 += __shfl_down(s1, off, 64);
    s2 += __shfl_down(s2, off, 64);
  }
  __shared__ float r1[4], r2[4];
  int wid = threadIdx.x >> 6, lane = threadIdx.x & 63;
  if (lane == 0) { r1[wid] = s1; r2[wid] = s2; }
  __syncthreads();
  if (threadIdx.x == 0) {
    float a = r1[0] + r1[1] + r1[2] + r1[3];
    float b = r2[0] + r2[1] + r2[2] + r2[3];
    atomicAdd(&stats_g[0], a);
    atomicAdd(&stats_g[1], b);
  }
  __syncthreads();
}

// ---------------- stage 1 (i>=1): 2 nodes/thread; vt = gnw ⊙ (h + proj(cond))
// grid: 8 (xcd=b) * 12 (img) * 10 (512-node chunk) = 960 blocks
__global__ __launch_bounds__(256) void k_stage1(
    const float* __restrict__ h, const float* __restrict__ cond,
    const float* w1, const float* b1, const float* w2, const float* b2,
    const float* __restrict__ gnw,
    float* __restrict__ vt, float* stats1) {
  __shared__ float lw1[64], lw2[64], lb1[8], lb2[8];
  int t = threadIdx.x;
  if (t < 64) lw1[t] = w1[t];
  else if (t < 128) lw2[t - 64] = w2[t - 64];
  else if (t < 136) lb1[t - 128] = b1[t - 128];
  else if (t < 144) lb2[t - 136] = b2[t - 136];
  __syncthreads();
  int xcd = blockIdx.x & 7;
  int local = blockIdx.x >> 3;
  int g = xcd * 12 + local / CHUNKS1;
  int chunk = local % CHUNKS1;
  int n0 = chunk * 512 + t;
  float s1 = 0.f, s2 = 0.f;
  #pragma unroll
  for (int r = 0; r < 2; ++r) {
    int n = n0 + r * 256;
    if (n < Nv) {
      size_t row = ((size_t)g * Nv + n) * Hv;
      float4 c0 = nt_load4(cond + row);
      float4 c1 = nt_load4(cond + row + 4);
      float xc[8] = {c0.x, c0.y, c0.z, c0.w, c1.x, c1.y, c1.z, c1.w};
      float u[8];
      #pragma unroll
      for (int j = 0; j < 8; ++j) {
        float s = lb1[j];
        #pragma unroll
        for (int k = 0; k < 8; ++k) s += xc[k] * lw1[k * 8 + j];
        u[j] = fmaxf(s, 0.f);
      }
      const float4* hr = (const float4*)(h + row);
      float4 h0 = hr[0], h1 = hr[1];
      float hv[8] = {h0.x, h0.y, h0.z, h0.w, h1.x, h1.y, h1.z, h1.w};
      const float4* gr = (const float4*)(gnw + (size_t)n * Hv);
      float4 g0 = gr[0], g1 = gr[1];
      float gv[8] = {g0.x, g0.y, g0.z, g0.w, g1.x, g1.y, g1.z, g1.w};
      float o[8];
      #pragma unroll
      for (int ch = 0; ch < 8; ++ch) {
        float s = lb2[ch];
        #pragma unroll
        for (int j = 0; j < 8; ++j) s += u[j] * lw2[j * 8 + ch];
        float val = s + hv[ch];
        s1 += val; s2 += val * val;
        o[ch] = val * gv[ch];
      }
      float4* vo = (float4*)(vt + row);
      vo[0] = make_float4(o[0], o[1], o[2], o[3]);
      vo[1] = make_float4(o[4], o[5], o[6], o[7]);
    }
  }
  partial_to_stats(s1, s2, stats1 + (size_t)g * 2);
}

// ---------------- fused k_init + stage1 for i=0 (1 node/thread, 1920 blocks)
__global__ __launch_bounds__(256) void k_stage1_init(
    const float* __restrict__ x, const float* __restrict__ posp,
    const float* iw1, const float* ib1, const float* iw2, const float* ib2,
    const float* __restrict__ cond,
    const float* w1, const float* b1, const float* w2, const float* b2,
    const float* __restrict__ gnw, const float* __restrict__ a9,
    float* __restrict__ acc,
    float* __restrict__ vt, float* stats1) {
  __shared__ float lw1[64], lw2[64], lb1[8], lb2[8];
  __shared__ float li1[8], li2[64], lib1[8], lib2[8];
  int t = threadIdx.x;
  if (t < 64) lw1[t] = w1[t];
  else if (t < 128) lw2[t - 64] = w2[t - 64];
  else if (t < 136) lb1[t - 128] = b1[t - 128];
  else if (t < 144) lb2[t - 136] = b2[t - 136];
  else if (t < 152) li1[t - 144] = iw1[t - 144];
  else if (t < 216) li2[t - 152] = iw2[t - 152];
  else if (t < 224) lib1[t - 216] = ib1[t - 216];
  else if (t < 232) lib2[t - 224] = ib2[t - 224];
  __syncthreads();
  int xcd = blockIdx.x & 7;
  int local = blockIdx.x >> 3;
  int g = xcd * 12 + local / BLKS_PER_IMG;
  int chunk = local % BLKS_PER_IMG;
  int n = chunk * 256 + t;
  float s1 = 0.f, s2 = 0.f;
  if (n < Nv) {
    size_t row = ((size_t)g * Nv + n) * Hv;
    float xv = __builtin_nontemporal_load(x + (size_t)g * Nv + n);
    float ui[8];
    #pragma unroll
    for (int j = 0; j < 8; ++j) ui[j] = fmaxf(xv * li1[j] + lib1[j], 0.f);
    const float4* pp = (const float4*)(posp + (size_t)n * Hv);
    float4 p0 = pp[0], p1 = pp[1];
    float pv[8] = {p0.x, p0.y, p0.z, p0.w, p1.x, p1.y, p1.z, p1.w};
    float hv[8];
    #pragma unroll
    for (int ch = 0; ch < 8; ++ch) {
      float s = lib2[ch];
      #pragma unroll
      for (int j = 0; j < 8; ++j) s += ui[j] * li2[j * 8 + ch];
      hv[ch] = s + pv[ch];
    }
    float a0 = a9[0];
    float4* ar = (float4*)(acc + row);
    ar[0] = make_float4(a0 * hv[0], a0 * hv[1], a0 * hv[2], a0 * hv[3]);
    ar[1] = make_float4(a0 * hv[4], a0 * hv[5], a0 * hv[6], a0 * hv[7]);
    float4 c0 = nt_load4(cond + row);
    float4 c1 = nt_load4(cond + row + 4);
    float xc[8] = {c0.x, c0.y, c0.z, c0.w, c1.x, c1.y, c1.z, c1.w};
    float u[8];
    #pragma unroll
    for (int j = 0; j < 8; ++j) {
      float s = lb1[j];
      #pragma unroll
      for (int k = 0; k < 8; ++k) s += xc[k] * lw1[k * 8 + j];
      u[j] = fmaxf(s, 0.f);
    }
    const float4* gr = (const float4*)(gnw + (size_t)n * Hv);
    float4 g0 = gr[0], g1 = gr[1];
    float gv[8] = {g0.x, g0.y, g0.z, g0.w, g1.x, g1.y, g1.z, g1.w};
    float o[8];
    #pragma unroll
    for (int ch = 0; ch < 8; ++ch) {
      float s = lb2[ch];
      #pragma unroll
      for (int j = 0; j < 8; ++j) s += u[j] * lw2[j * 8 + ch];
      float val = s + hv[ch];
      s1 += val; s2 += val * val;
      o[ch] = val * gv[ch];
    }
    float4* vo = (float4*)(vt + row);
    vo[0] = make_float4(o[0], o[1], o[2], o[3]);
    vo[1] = make_float4(o[4], o[5], o[6], o[7]);
  }
  partial_to_stats(s1, s2, stats1 + (size_t)g * 2);
}

// ---------------- stage 2: IPT2 images/thread, EU-edge unroll (16 gathers in flight)
__global__ __launch_bounds__(256) void k_stage2(
    const float* __restrict__ vt, float* __restrict__ v2,
    const int* __restrict__ row_ptr, const float2* __restrict__ epack,
    const float* __restrict__ Gw, const float* __restrict__ Gb,
    const float* __restrict__ stats1, float* stats2,
    const float* __restrict__ tvec) {
  __shared__ float2 se[ECAP];
  int t = threadIdx.x;
  int b = blockIdx.x & 7;
  int local = blockIdx.x >> 3;
  int pair = local % 6;
  int chunk = local / 6;
  int g0 = b * Pv + pair * IPT2;
  int nb0 = chunk * 256;
  int nb1 = nb0 + 256; if (nb1 > Nv) nb1 = Nv;
  int eb0 = row_ptr[nb0];
  int eb1 = row_ptr[nb1];
  int cnt = eb1 - eb0;
  const float2* eps;
  int ebase;
  if (cnt <= ECAP) {
    for (int k = t; k < cnt; k += 256) se[k] = epack[eb0 + k];
    eps = se; ebase = eb0;
  } else {
    eps = epack; ebase = 0;
  }
  __syncthreads();
  float mean[IPT2], rstd[IPT2], mrs[IPT2];
  #pragma unroll
  for (int j = 0; j < IPT2; ++j) {
    float m  = stats1[(g0 + j) * 2]     * (1.f / 40000.f);
    float m2 = stats1[(g0 + j) * 2 + 1] * (1.f / 40000.f);
    float var = m2 - m * m;
    mean[j] = m;
    rstd[j] = (float)(1.0 / sqrt((double)var + 1e-5));
    mrs[j]  = m * rstd[j];
  }
  int n = nb0 + t;
  float s1a[IPT2], s2a[IPT2];
  #pragma unroll
  for (int j = 0; j < IPT2; ++j) { s1a[j] = 0.f; s2a[j] = 0.f; }
  if (n < Nv) {
    const float* vt0 = vt + (size_t)(g0 + 0) * Nv * Hv;
    const float* vt1 = vt + (size_t)(g0 + 1) * Nv * Hv;
    float a[IPT2][8];
    #pragma unroll
    for (int j = 0; j < IPT2; ++j)
      #pragma unroll
      for (int ch = 0; ch < 8; ++ch) a[j][ch] = 0.f;
    int e0 = row_ptr[n] - ebase, e1 = row_ptr[n + 1] - ebase;
    int e = e0;
    for (; e + EU <= e1; e += EU) {
      float2 pp[EU];
      float4 A0[EU], B0[EU], A1[EU], B1[EU];
      #pragma unroll
      for (int k = 0; k < EU; ++k) pp[k] = eps[e + k];
      #pragma unroll
      for (int k = 0; k < EU; ++k) {
        size_t so = (size_t)__float_as_int(pp[k].x) * Hv;
        const float4* r0 = (const float4*)(vt0 + so);
        const float4* r1 = (const float4*)(vt1 + so);
        A0[k] = r0[0]; B0[k] = r0[1];
        A1[k] = r1[0]; B1[k] = r1[1];
      }
      #pragma unroll
      for (int k = 0; k < EU; ++k) {
        float w = pp[k].y;
        a[0][0] += w * A0[k].x; a[0][1] += w * A0[k].y;
        a[0][2] += w * A0[k].z; a[0][3] += w * A0[k].w;
        a[0][4] += w * B0[k].x; a[0][5] += w * B0[k].y;
        a[0][6] += w * B0[k].z; a[0][7] += w * B0[k].w;
        a[1][0] += w * A1[k].x; a[1][1] += w * A1[k].y;
        a[1][2] += w * A1[k].z; a[1][3] += w * A1[k].w;
        a[1][4] += w * B1[k].x; a[1][5] += w * B1[k].y;
        a[1][6] += w * B1[k].z; a[1][7] += w * B1[k].w;
      }
    }
    for (; e < e1; ++e) {
      float2 ep = eps[e];
      float w = ep.y;
      size_t so = (size_t)__float_as_int(ep.x) * Hv;
      const float4* r0 = (const float4*)(vt0 + so);
      const float4* r1 = (const float4*)(vt1 + so);
      float4 xa = r0[0], xb = r0[1];
      float4 ya = r1[0], yb = r1[1];
      a[0][0] += w*xa.x; a[0][1] += w*xa.y; a[0][2] += w*xa.z; a[0][3] += w*xa.w;
      a[0][4] += w*xb.x; a[0][5] += w*xb.y; a[0][6] += w*xb.z; a[0][7] += w*xb.w;
      a[1][0] += w*ya.x; a[1][1] += w*ya.y; a[1][2] += w*ya.z; a[1][3] += w*ya.w;
      a[1][4] += w*yb.x; a[1][5] += w*yb.y; a[1][6] += w*yb.z; a[1][7] += w*yb.w;
    }
    size_t noff = (size_t)n * Hv;
    const float4* wr = (const float4*)(Gw + noff);
    const float4* br = (const float4*)(Gb + noff);
    float4 w0 = wr[0], w1 = wr[1], b0 = br[0], b1 = br[1];
    float gw8[8] = {w0.x, w0.y, w0.z, w0.w, w1.x, w1.y, w1.z, w1.w};
    float gb8[8] = {b0.x, b0.y, b0.z, b0.w, b1.x, b1.y, b1.z, b1.w};
    float tl[8];
    {
      const float4* tr = (const float4*)(tvec + b * Hv);
      float4 t0 = tr[0], t1 = tr[1];
      tl[0] = t0.x; tl[1] = t0.y; tl[2] = t0.z; tl[3] = t0.w;
      tl[4] = t1.x; tl[5] = t1.y; tl[6] = t1.z; tl[7] = t1.w;
    }
    #pragma unroll
    for (int j = 0; j < IPT2; ++j) {
      float o[8];
      #pragma unroll
      for (int ch = 0; ch < 8; ++ch) {
        float val = rstd[j] * a[j][ch] - mrs[j] * gw8[ch] + gb8[ch] + tl[ch];
        o[ch] = val;
        s1a[j] += val; s2a[j] += val * val;
      }
      float* vo = v2 + (size_t)(g0 + j) * Nv * Hv + noff;
      nt_store4(vo,     o[0], o[1], o[2], o[3]);
      nt_store4(vo + 4, o[4], o[5], o[6], o[7]);
    }
  }
  #pragma unroll
  for (int j = 0; j < IPT2; ++j)
    partial_to_stats(s1a[j], s2a[j], stats2 + (size_t)(g0 + j) * 2);
}

// ---------------- stage 3: LN(v2) + conv + skip acc (cached); last iter fuses out proj
__global__ __launch_bounds__(256) void k_stage3(
    float* __restrict__ v2, float* __restrict__ acc,
    const float* __restrict__ stats2,
    const float* __restrict__ tnw, const float* __restrict__ tnb,
    const float* __restrict__ cw, const float* __restrict__ cb,
    const float* __restrict__ a9, int iblk,
    const float* __restrict__ ow1, const float* __restrict__ ob1,
    const float* __restrict__ ow2, const float* __restrict__ ob2,
    float* __restrict__ out) {
  __shared__ float scw[144], scb[12], smean[12], srstd[12];
  __shared__ float sow1[64], sob1[8], sow2[8], sob2[1];
  int t = threadIdx.x;
  int b = blockIdx.x & 7;
  int chunk = blockIdx.x >> 3;
  bool last = (iblk == NBv - 1);
  if (t < 144) scw[t] = cw[t];
  else if (t < 156) scb[t - 144] = cb[t - 144];
  else if (t < 168) {
    int p = t - 156;
    int g = b * Pv + p;
    float mean = stats2[g * 2]     * (1.f / 40000.f);
    float m2   = stats2[g * 2 + 1] * (1.f / 40000.f);
    float var  = m2 - mean * mean;
    smean[p] = mean;
    srstd[p] = (float)(1.0 / sqrt((double)var + 1e-5));
  } else if (last) {
    if (t < 232) sow1[t - 168] = ow1[t - 168];
    else if (t < 240) sob1[t - 232] = ob1[t - 232];
    else if (t < 248) sow2[t - 240] = ow2[t - 240];
    else if (t == 248) sob2[0] = ob2[0];
  }
  __syncthreads();
  int idx = chunk * 256 + t;
  if (idx >= Nv * 2) return;
  int n = idx >> 1, c4 = idx & 1;
  size_t noff = (size_t)n * Hv + c4 * 4;
  const float4 w4 = nt_load4(tnw + noff);
  const float4 b4 = nt_load4(tnb + noff);
  size_t strideP = (size_t)Nv * Hv;
  size_t base = (size_t)b * Pv * strideP + noff;
  float4 in[12];
  #pragma unroll
  for (int p = 0; p < 12; ++p) {
    float4 v = nt_load4(v2 + base + p * strideP);
    float mean = smean[p], rstd = srstd[p];
    in[p].x = (v.x - mean) * rstd * w4.x + b4.x;
    in[p].y = (v.y - mean) * rstd * w4.y + b4.y;
    in[p].z = (v.z - mean) * rstd * w4.z + b4.z;
    in[p].w = (v.w - mean) * rstd * w4.w + b4.w;
  }
  float ai = a9[iblk + 1];
  #pragma unroll
  for (int q = 0; q < 12; ++q) {
    float4 o = make_float4(scb[q], scb[q], scb[q], scb[q]);
    #pragma unroll
    for (int p = 0; p < 12; ++p) {
      float c = scw[q * 12 + p];
      o.x += c * in[p].x; o.y += c * in[p].y;
      o.z += c * in[p].z; o.w += c * in[p].w;
    }
    size_t off = base + q * strideP;
    float4* ap = (float4*)(acc + off);
    float4 av = *ap;
    float n0 = av.x + ai * o.x, n1 = av.y + ai * o.y;
    float n2 = av.z + ai * o.z, n3 = av.w + ai * o.w;
    if (!last) {
      *(float4*)(v2 + off) = o;
      *ap = make_float4(n0, n1, n2, n3);
    } else {
      float e0 = __shfl_xor(n0, 1, 64);
      float e1 = __shfl_xor(n1, 1, 64);
      float e2 = __shfl_xor(n2, 1, 64);
      float e3 = __shfl_xor(n3, 1, 64);
      float a8[8];
      if (c4 == 0) {
        a8[0] = n0; a8[1] = n1; a8[2] = n2; a8[3] = n3;
        a8[4] = e0; a8[5] = e1; a8[6] = e2; a8[7] = e3;
      } else {
        a8[0] = e0; a8[1] = e1; a8[2] = e2; a8[3] = e3;
        a8[4] = n0; a8[5] = n1; a8[6] = n2; a8[7] = n3;
      }
      if (c4 == 0) {
        float oo = sob2[0];
        #pragma unroll
        for (int j = 0; j < 8; ++j) {
          float s = sob1[j];
          #pragma unroll
          for (int k = 0; k < 8; ++k) s += a8[k] * sow1[k * 8 + j];
          oo += fmaxf(s, 0.f) * sow2[j];
        }
        out[((size_t)b * Pv + q) * Nv + n] = oo;
      }
    }
  }
}

extern "C" void kernel_launch(void* const* d_in, const int* in_sizes, int n_in,
                              void* d_out, int out_size, void* d_ws, size_t ws_size,
                              hipStream_t stream) {
  const float* x      = (const float*)d_in[0];
  const float* cond   = (const float*)d_in[1];
  const float* pos    = (const float*)d_in[2];
  const int*   timei  = (const int*)  d_in[3];
  const int*   eidx   = (const int*)  d_in[4];
  const float* te_w1  = (const float*)d_in[5];
  const float* te_b1  = (const float*)d_in[6];
  const float* te_w2  = (const float*)d_in[7];
  const float* te_b2  = (const float*)d_in[8];
  const float* in_w1  = (const float*)d_in[9];
  const float* in_b1  = (const float*)d_in[10];
  const float* in_w2  = (const float*)d_in[11];
  const float* in_b2  = (const float*)d_in[12];
  const float* pos_w1 = (const float*)d_in[13];
  const float* pos_b1 = (const float*)d_in[14];
  const float* pos_w2 = (const float*)d_in[15];
  const float* pos_b2 = (const float*)d_in[16];
  const float* attn   = (const float*)d_in[17];
  const float* bt_w1  = (const float*)d_in[18];
  const float* bt_b1  = (const float*)d_in[19];
  const float* bt_w2  = (const float*)d_in[20];
  const float* bt_b2  = (const float*)d_in[21];
  const float* bc_w1  = (const float*)d_in[22];
  const float* bc_b1  = (const float*)d_in[23];
  const float* bc_w2  = (const float*)d_in[24];
  const float* bc_b2  = (const float*)d_in[25];
  const float* gn_w   = (const float*)d_in[26];
  const float* gn_b   = (const float*)d_in[27];
  const float* tn_w   = (const float*)d_in[28];
  const float* tn_b   = (const float*)d_in[29];
  const float* cv_w   = (const float*)d_in[30];
  const float* cv_b   = (const float*)d_in[31];
  const float* out_w1 = (const float*)d_in[32];
  const float* out_b1 = (const float*)d_in[33];
  const float* out_w2 = (const float*)d_in[34];
  const float* out_b2 = (const float*)d_in[35];
  float* out = (float*)d_out;

  const size_t HSZ = (size_t)Bv * Pv * Nv * Hv;  // 3,840,000
  float* ws    = (float*)d_ws;
  float* X     = ws;                 // v2 buffer
  float* Y     = X + HSZ;            // vt (= gnw ⊙ v1) buffer
  float* acc   = Y + HSZ;
  float* posp  = acc + HSZ;          // Nv*Hv
  float* deg   = posp + Nv * Hv;     // Nv
  float* dinv  = deg + Nv;           // Nv
  float* epack = dinv + Nv;          // 2*Ev floats
  float* t_all = epack + 2 * Ev;     // NBv*Bv*Hv = 512
  float* a9    = t_all + NBv * Bv * Hv;  // 16
  float* stats = a9 + 16;            // NBv*2*NIMG*2 = 3072
  float* Gw    = stats + NBv * 2 * NIMG * 2;  // NBv*Nv*Hv = 320000
  float* Gb    = Gw + NBv * Nv * Hv;          // 320000
  int* row_ptr = (int*)(Gb + NBv * Nv * Hv);  // Nv+8
  int* cursor  = row_ptr + Nv + 8;   // Nv+8

  k_setup<<<1, 512, 0, stream>>>(timei, attn, te_w1, te_b1, te_w2, te_b2,
                                 bt_w1, bt_b1, bt_w2, bt_b2, t_all, a9);
  k_posp_zero<<<(Nv + 255) / 256, 256, 0, stream>>>(
      pos, pos_w1, pos_b1, pos_w2, pos_b2, posp, deg, cursor, stats);
  k_deg<<<(Ev + 255) / 256, 256, 0, stream>>>(eidx, deg);
  k_scan<<<1, 1024, 0, stream>>>(deg, dinv, row_ptr);
  k_csr<<<(Ev + 255) / 256, 256, 0, stream>>>(eidx, dinv, row_ptr, cursor, (float2*)epack);
  k_gwb<<<(NBv * Nv + 255) / 256, 256, 0, stream>>>(
      row_ptr, (const float2*)epack, gn_w, gn_b, Gw, Gb);

  for (int i = 0; i < NBv; ++i) {
    float* st1 = stats + (size_t)(i * 2 + 0) * NIMG * 2;
    float* st2 = stats + (size_t)(i * 2 + 1) * NIMG * 2;
    if (i == 0) {
      k_stage1_init<<<NIMG * BLKS_PER_IMG, 256, 0, stream>>>(
          x, posp, in_w1, in_b1, in_w2, in_b2,
          cond, bc_w1, bc_b1, bc_w2, bc_b2,
          gn_w, a9, acc, Y, st1);
    } else {
      k_stage1<<<8 * 12 * CHUNKS1, 256, 0, stream>>>(
          X, cond,
          bc_w1 + i * 64, bc_b1 + i * 8, bc_w2 + i * 64, bc_b2 + i * 8,
          gn_w + (size_t)i * Nv * Hv,
          Y, st1);
    }
    k_stage2<<<8 * 6 * BLKS_PER_IMG, 256, 0, stream>>>(
        Y, X, row_ptr, (const float2*)epack,
        Gw + (size_t)i * Nv * Hv, Gb + (size_t)i * Nv * Hv,
        st1, st2, t_all + i * Bv * Hv);
    k_stage3<<<8 * 40, 256, 0, stream>>>(
        X, acc, st2,
        tn_w + (size_t)i * Nv * Hv, tn_b + (size_t)i * Nv * Hv,
        cv_w + i * 144, cv_b + i * 12, a9, i,
        out_w1, out_b1, out_w2, out_b2, out);
  }
}

// Round 19
// 544.845 us; speedup vs baseline: 2.0125x; 1.0165x over previous
//
#include <hip/hip_runtime.h>
#include <math.h>

#define Bv 8
#define Pv 12
#define Nv 5000
#define Hv 8
#define Ev 50000
#define NBv 8
#define TD1v 64
#define NIMG (Bv * Pv)          // 96 images
#define BLKS_PER_IMG 20         // ceil(5000/256)
#define CHUNKS1 10              // stage1: 512-node chunks
#define ECAP 3072               // LDS edge-stage capacity (24 KB)
#define IPT2 2                  // images per thread in stage2
#define EU 8                    // stage2 edge unroll

typedef float f4v __attribute__((ext_vector_type(4)));

__device__ inline float4 nt_load4(const float* p) {
  f4v v = __builtin_nontemporal_load((const f4v*)p);
  return make_float4(v.x, v.y, v.z, v.w);
}
__device__ inline void nt_store4(float* p, float a, float b, float c, float d) {
  f4v v = {a, b, c, d};
  __builtin_nontemporal_store(v, (f4v*)p);
}

// correctly-rounded f32 of 10^(d/4), d=0..15 (matches numpy float32 powf)
__device__ __constant__ float POW10Q[16] = {
  1.0f, 1.7782794100389228f, 3.1622776601683795f, 5.623413251903491f,
  10.0f, 17.78279410038923f, 31.622776601683793f, 56.23413251903491f,
  100.0f, 177.82794100389228f, 316.22776601683796f, 562.341325190349f,
  1000.0f, 1778.2794100389228f, 3162.2776601683795f, 5623.413251903491f
};

// ---------------- setup (512 threads)
__global__ __launch_bounds__(512) void k_setup(
    const int* timei, const float* attn,
    const float* te_w1, const float* te_b1,
    const float* te_w2, const float* te_b2,
    const float* bt_w1, const float* bt_b1,
    const float* bt_w2, const float* bt_b2,
    float* t_all, float* a9) {
  __shared__ float te0[Bv][32];
  __shared__ float te1[Bv][64];
  __shared__ float te2[Bv][64];
  __shared__ float su[64][8];
  int t = threadIdx.x; // 512
  if (t < 256) {
    int b = t >> 5, k = t & 31;
    int d = k & 15;
    float e = (float)timei[b] * POW10Q[d];
    te0[b][k] = (k < 16) ? (float)sin((double)e) : (float)cos((double)e);
  }
  __syncthreads();
  {
    int b = t >> 6, j = t & 63;
    float s = te_b1[j];
    for (int k = 0; k < 32; ++k) s += te0[b][k] * te_w1[k * 64 + j];
    te1[b][j] = s / (1.0f + expf(-s));
  }
  __syncthreads();
  {
    int b = t >> 6, j = t & 63;
    float s = te_b2[j];
    for (int k = 0; k < 64; ++k) s += te1[b][k] * te_w2[k * 64 + j];
    te2[b][j] = s / (1.0f + expf(-s));
  }
  __syncthreads();
  {
    int ib = t >> 3, j = t & 7;
    int i = ib >> 3, b = ib & 7;
    float s = bt_b1[i * Hv + j];
    for (int k = 0; k < TD1v; ++k) s += te2[b][k] * bt_w1[(i * TD1v + k) * Hv + j];
    su[ib][j] = fmaxf(s, 0.0f);
  }
  __syncthreads();
  {
    int ib = t >> 3, ch = t & 7;
    int i = ib >> 3, b = ib & 7;
    float s = bt_b2[i * Hv + ch];
    #pragma unroll
    for (int j = 0; j < 8; ++j) s += su[ib][j] * bt_w2[(i * Hv + j) * Hv + ch];
    t_all[(i * Bv + b) * Hv + ch] = s;
  }
  if (t == 0) {
    float m = attn[0];
    for (int i = 1; i < 9; ++i) m = fmaxf(m, attn[i]);
    float s = 0.f, ex[9];
    for (int i = 0; i < 9; ++i) { ex[i] = expf(attn[i] - m); s += ex[i]; }
    for (int i = 0; i < 9; ++i) a9[i] = ex[i] / s;
  }
}

// ---------------- merged: posp projection + zero(deg/cursor/stats)
__global__ void k_posp_zero(const float* pos, const float* pw1, const float* pb1,
                            const float* pw2, const float* pb2, float* posp,
                            float* deg, int* cursor, float* stats) {
  int n = blockIdx.x * blockDim.x + threadIdx.x;
  if (n < Nv) { deg[n] = 0.f; cursor[n] = 0; }
  if (n < NBv * 2 * NIMG * 2) stats[n] = 0.f;
  if (n >= Nv) return;
  const float4* pr = (const float4*)(pos + (size_t)n * Hv);
  float4 r0 = pr[0], r1 = pr[1];
  float x[8] = {r0.x, r0.y, r0.z, r0.w, r1.x, r1.y, r1.z, r1.w};
  float u[8];
  #pragma unroll
  for (int j = 0; j < 8; ++j) {
    float s = pb1[j];
    #pragma unroll
    for (int k = 0; k < 8; ++k) s += x[k] * pw1[k * 8 + j];
    u[j] = fmaxf(s, 0.f);
  }
  float o[8];
  #pragma unroll
  for (int ch = 0; ch < 8; ++ch) {
    float s = pb2[ch];
    #pragma unroll
    for (int j = 0; j < 8; ++j) s += u[j] * pw2[j * 8 + ch];
    o[ch] = s;
  }
  float4* po = (float4*)(posp + (size_t)n * Hv);
  po[0] = make_float4(o[0], o[1], o[2], o[3]);
  po[1] = make_float4(o[4], o[5], o[6], o[7]);
}

__global__ void k_deg(const int* eidx, float* deg) {
  int e = blockIdx.x * blockDim.x + threadIdx.x;
  if (e < Ev) atomicAdd(&deg[eidx[Ev + e]], 1.0f);
}

// single-block: dinv + exclusive scan -> row_ptr[0..Nv] (wave shfl scan)
__global__ __launch_bounds__(1024) void k_scan(const float* deg, float* dinv,
                                               int* row_ptr) {
  __shared__ int wsum[16];
  __shared__ int base_s;
  int t = threadIdx.x;
  int lane = t & 63, wid = t >> 6;
  if (t == 0) { base_s = 0; row_ptr[0] = 0; }
  __syncthreads();
  for (int c = 0; c < 5; ++c) {
    int i = c * 1024 + t;
    float dv = (i < Nv) ? deg[i] : 0.f;
    if (i < Nv)
      dinv[i] = dv > 0.f ? (float)(1.0 / sqrt((double)dv)) : 0.f;
    int v = (int)(dv + 0.5f);
    int s = v;
    #pragma unroll
    for (int off = 1; off < 64; off <<= 1) {
      int up = __shfl_up(s, off, 64);
      if (lane >= off) s += up;
    }
    if (lane == 63) wsum[wid] = s;
    __syncthreads();
    if (wid == 0 && lane < 16) {
      int ws = wsum[lane];
      #pragma unroll
      for (int off = 1; off < 16; off <<= 1) {
        int up = __shfl_up(ws, off, 64);
        if (lane >= off) ws += up;
      }
      wsum[lane] = ws;
    }
    __syncthreads();
    int wbase = (wid > 0) ? wsum[wid - 1] : 0;
    int incl = base_s + wbase + s;
    if (i < Nv) row_ptr[i + 1] = incl;
    __syncthreads();
    if (t == 1023) base_s = incl;
    __syncthreads();
  }
}

// CSR fill: packed (src_bits, w) per edge
__global__ void k_csr(const int* eidx, const float* dinv, const int* row_ptr,
                      int* cursor, float2* epack) {
  int e = blockIdx.x * blockDim.x + threadIdx.x;
  if (e >= Ev) return;
  int s = eidx[e], d = eidx[Ev + e];
  int slot = atomicAdd(&cursor[d], 1);
  int pos = row_ptr[d] + slot;
  epack[pos] = make_float2(__int_as_float(s), dinv[s] * dinv[d]);
}

// ---------------- per block-iter: Gw[i][n]=Σ w_e gnw_i[src], Gb likewise (4-edge unroll)
__global__ __launch_bounds__(256) void k_gwb(
    const int* __restrict__ row_ptr, const float2* __restrict__ epack,
    const float* __restrict__ gn_w, const float* __restrict__ gn_b,
    float* __restrict__ Gw, float* __restrict__ Gb) {
  int id = blockIdx.x * 256 + threadIdx.x;
  if (id >= NBv * Nv) return;
  int i = id / Nv, n = id % Nv;
  const float* gw = gn_w + (size_t)i * Nv * Hv;
  const float* gb = gn_b + (size_t)i * Nv * Hv;
  float aw[8] = {0,0,0,0,0,0,0,0}, ab[8] = {0,0,0,0,0,0,0,0};
  int e0 = row_ptr[n], e1 = row_ptr[n + 1];
  int e = e0;
  for (; e + 4 <= e1; e += 4) {
    float2 p0 = epack[e], p1 = epack[e+1], p2 = epack[e+2], p3 = epack[e+3];
    size_t s0 = (size_t)__float_as_int(p0.x) * Hv;
    size_t s1 = (size_t)__float_as_int(p1.x) * Hv;
    size_t s2 = (size_t)__float_as_int(p2.x) * Hv;
    size_t s3 = (size_t)__float_as_int(p3.x) * Hv;
    const float4* w0p = (const float4*)(gw + s0);
    const float4* w1p = (const float4*)(gw + s1);
    const float4* w2p = (const float4*)(gw + s2);
    const float4* w3p = (const float4*)(gw + s3);
    const float4* b0p = (const float4*)(gb + s0);
    const float4* b1p = (const float4*)(gb + s1);
    const float4* b2p = (const float4*)(gb + s2);
    const float4* b3p = (const float4*)(gb + s3);
    float4 wa0 = w0p[0], wb0 = w0p[1], wa1 = w1p[0], wb1 = w1p[1];
    float4 wa2 = w2p[0], wb2 = w2p[1], wa3 = w3p[0], wb3 = w3p[1];
    float4 ba0 = b0p[0], bb0 = b0p[1], ba1 = b1p[0], bb1 = b1p[1];
    float4 ba2 = b2p[0], bb2 = b2p[1], ba3 = b3p[0], bb3 = b3p[1];
    aw[0] += p0.y*wa0.x + p1.y*wa1.x + p2.y*wa2.x + p3.y*wa3.x;
    aw[1] += p0.y*wa0.y + p1.y*wa1.y + p2.y*wa2.y + p3.y*wa3.y;
    aw[2] += p0.y*wa0.z + p1.y*wa1.z + p2.y*wa2.z + p3.y*wa3.z;
    aw[3] += p0.y*wa0.w + p1.y*wa1.w + p2.y*wa2.w + p3.y*wa3.w;
    aw[4] += p0.y*wb0.x + p1.y*wb1.x + p2.y*wb2.x + p3.y*wb3.x;
    aw[5] += p0.y*wb0.y + p1.y*wb1.y + p2.y*wb2.y + p3.y*wb3.y;
    aw[6] += p0.y*wb0.z + p1.y*wb1.z + p2.y*wb2.z + p3.y*wb3.z;
    aw[7] += p0.y*wb0.w + p1.y*wb1.w + p2.y*wb2.w + p3.y*wb3.w;
    ab[0] += p0.y*ba0.x + p1.y*ba1.x + p2.y*ba2.x + p3.y*ba3.x;
    ab[1] += p0.y*ba0.y + p1.y*ba1.y + p2.y*ba2.y + p3.y*ba3.y;
    ab[2] += p0.y*ba0.z + p1.y*ba1.z + p2.y*ba2.z + p3.y*ba3.z;
    ab[3] += p0.y*ba0.w + p1.y*ba1.w + p2.y*ba2.w + p3.y*ba3.w;
    ab[4] += p0.y*bb0.x + p1.y*bb1.x + p2.y*bb2.x + p3.y*bb3.x;
    ab[5] += p0.y*bb0.y + p1.y*bb1.y + p2.y*bb2.y + p3.y*bb3.y;
    ab[6] += p0.y*bb0.z + p1.y*bb1.z + p2.y*bb2.z + p3.y*bb3.z;
    ab[7] += p0.y*bb0.w + p1.y*bb1.w + p2.y*bb2.w + p3.y*bb3.w;
  }
  for (; e < e1; ++e) {
    float2 ep = epack[e];
    int s = __float_as_int(ep.x);
    float w = ep.y;
    const float4* wr = (const float4*)(gw + (size_t)s * Hv);
    const float4* br = (const float4*)(gb + (size_t)s * Hv);
    float4 w0 = wr[0], w1 = wr[1], b0 = br[0], b1 = br[1];
    aw[0] += w * w0.x; aw[1] += w * w0.y; aw[2] += w * w0.z; aw[3] += w * w0.w;
    aw[4] += w * w1.x; aw[5] += w * w1.y; aw[6] += w * w1.z; aw[7] += w * w1.w;
    ab[0] += w * b0.x; ab[1] += w * b0.y; ab[2] += w * b0.z; ab[3] += w * b0.w;
    ab[4] += w * b1.x; ab[5] += w * b1.y; ab[6] += w * b1.z; ab[7] += w * b1.w;
  }
  float4* wo = (float4*)(Gw + (size_t)id * Hv);
  wo[0] = make_float4(aw[0], aw[1], aw[2], aw[3]);
  wo[1] = make_float4(aw[4], aw[5], aw[6], aw[7]);
  float4* bo = (float4*)(Gb + (size_t)id * Hv);
  bo[0] = make_float4(ab[0], ab[1], ab[2], ab[3]);
  bo[1] = make_float4(ab[4], ab[5], ab[6], ab[7]);
}

// block-level reduce of (s1,s2) over 256 threads, then one atomicAdd pair.
__device__ inline void partial_to_stats(float s1, float s2, float* stats_g) {
  #pragma unroll
  for (int off = 32; off > 0; off >>= 1) {
    s1 += __shfl_down(s1, off, 64);
    s2 += __shfl_down(s2, off, 64);
  }
  __shared__ float r1[4], r2[4];
  int wid = threadIdx.x >> 6, lane = threadIdx.x & 63;
  if (lane == 0) { r1[wid] = s1; r2[wid] = s2; }
  __syncthreads();
  if (threadIdx.x == 0) {
    float a = r1[0] + r1[1] + r1[2] + r1[3];
    float b = r2[0] + r2[1] + r2[2] + r2[3];
    atomicAdd(&stats_g[0], a);
    atomicAdd(&stats_g[1], b);
  }
  __syncthreads();
}

// ---------------- stage 1 (i>=1): 2 nodes/thread; h read from hbuf, vt written in-place
// grid: 8 (xcd=b) * 12 (img) * 10 (512-node chunk) = 960 blocks
__global__ __launch_bounds__(256) void k_stage1(
    float* __restrict__ hv_buf, const float* __restrict__ cond,
    const float* w1, const float* b1, const float* w2, const float* b2,
    const float* __restrict__ gnw,
    float* stats1) {
  __shared__ float lw1[64], lw2[64], lb1[8], lb2[8];
  int t = threadIdx.x;
  if (t < 64) lw1[t] = w1[t];
  else if (t < 128) lw2[t - 64] = w2[t - 64];
  else if (t < 136) lb1[t - 128] = b1[t - 128];
  else if (t < 144) lb2[t - 136] = b2[t - 136];
  __syncthreads();
  int xcd = blockIdx.x & 7;
  int local = blockIdx.x >> 3;
  int g = xcd * 12 + local / CHUNKS1;
  int chunk = local % CHUNKS1;
  int n0 = chunk * 512 + t;
  float s1 = 0.f, s2 = 0.f;
  #pragma unroll
  for (int r = 0; r < 2; ++r) {
    int n = n0 + r * 256;
    if (n < Nv) {
      size_t row = ((size_t)g * Nv + n) * Hv;
      float4 c0 = nt_load4(cond + row);
      float4 c1 = nt_load4(cond + row + 4);
      float xc[8] = {c0.x, c0.y, c0.z, c0.w, c1.x, c1.y, c1.z, c1.w};
      float u[8];
      #pragma unroll
      for (int j = 0; j < 8; ++j) {
        float s = lb1[j];
        #pragma unroll
        for (int k = 0; k < 8; ++k) s += xc[k] * lw1[k * 8 + j];
        u[j] = fmaxf(s, 0.f);
      }
      const float4* hr = (const float4*)(hv_buf + row);
      float4 h0 = hr[0], h1 = hr[1];
      float hv[8] = {h0.x, h0.y, h0.z, h0.w, h1.x, h1.y, h1.z, h1.w};
      const float4* gr = (const float4*)(gnw + (size_t)n * Hv);
      float4 g0 = gr[0], g1 = gr[1];
      float gv[8] = {g0.x, g0.y, g0.z, g0.w, g1.x, g1.y, g1.z, g1.w};
      float o[8];
      #pragma unroll
      for (int ch = 0; ch < 8; ++ch) {
        float s = lb2[ch];
        #pragma unroll
        for (int j = 0; j < 8; ++j) s += u[j] * lw2[j * 8 + ch];
        float val = s + hv[ch];
        s1 += val; s2 += val * val;
        o[ch] = val * gv[ch];
      }
      float4* vo = (float4*)(hv_buf + row);   // vt overwrites h in-place (per-thread RAW safe)
      vo[0] = make_float4(o[0], o[1], o[2], o[3]);
      vo[1] = make_float4(o[4], o[5], o[6], o[7]);
    }
  }
  partial_to_stats(s1, s2, stats1 + (size_t)g * 2);
}

// ---------------- fused k_init + stage1 for i=0 (writes vt into hv_buf)
__global__ __launch_bounds__(256) void k_stage1_init(
    const float* __restrict__ x, const float* __restrict__ posp,
    const float* iw1, const float* ib1, const float* iw2, const float* ib2,
    const float* __restrict__ cond,
    const float* w1, const float* b1, const float* w2, const float* b2,
    const float* __restrict__ gnw, const float* __restrict__ a9,
    float* __restrict__ acc,
    float* __restrict__ vt, float* stats1) {
  __shared__ float lw1[64], lw2[64], lb1[8], lb2[8];
  __shared__ float li1[8], li2[64], lib1[8], lib2[8];
  int t = threadIdx.x;
  if (t < 64) lw1[t] = w1[t];
  else if (t < 128) lw2[t - 64] = w2[t - 64];
  else if (t < 136) lb1[t - 128] = b1[t - 128];
  else if (t < 144) lb2[t - 136] = b2[t - 136];
  else if (t < 152) li1[t - 144] = iw1[t - 144];
  else if (t < 216) li2[t - 152] = iw2[t - 152];
  else if (t < 224) lib1[t - 216] = ib1[t - 216];
  else if (t < 232) lib2[t - 224] = ib2[t - 224];
  __syncthreads();
  int xcd = blockIdx.x & 7;
  int local = blockIdx.x >> 3;
  int g = xcd * 12 + local / BLKS_PER_IMG;
  int chunk = local % BLKS_PER_IMG;
  int n = chunk * 256 + t;
  float s1 = 0.f, s2 = 0.f;
  if (n < Nv) {
    size_t row = ((size_t)g * Nv + n) * Hv;
    float xv = __builtin_nontemporal_load(x + (size_t)g * Nv + n);
    float ui[8];
    #pragma unroll
    for (int j = 0; j < 8; ++j) ui[j] = fmaxf(xv * li1[j] + lib1[j], 0.f);
    const float4* pp = (const float4*)(posp + (size_t)n * Hv);
    float4 p0 = pp[0], p1 = pp[1];
    float pv[8] = {p0.x, p0.y, p0.z, p0.w, p1.x, p1.y, p1.z, p1.w};
    float hv[8];
    #pragma unroll
    for (int ch = 0; ch < 8; ++ch) {
      float s = lib2[ch];
      #pragma unroll
      for (int j = 0; j < 8; ++j) s += ui[j] * li2[j * 8 + ch];
      hv[ch] = s + pv[ch];
    }
    float a0 = a9[0];
    float4* ar = (float4*)(acc + row);
    ar[0] = make_float4(a0 * hv[0], a0 * hv[1], a0 * hv[2], a0 * hv[3]);
    ar[1] = make_float4(a0 * hv[4], a0 * hv[5], a0 * hv[6], a0 * hv[7]);
    float4 c0 = nt_load4(cond + row);
    float4 c1 = nt_load4(cond + row + 4);
    float xc[8] = {c0.x, c0.y, c0.z, c0.w, c1.x, c1.y, c1.z, c1.w};
    float u[8];
    #pragma unroll
    for (int j = 0; j < 8; ++j) {
      float s = lb1[j];
      #pragma unroll
      for (int k = 0; k < 8; ++k) s += xc[k] * lw1[k * 8 + j];
      u[j] = fmaxf(s, 0.f);
    }
    const float4* gr = (const float4*)(gnw + (size_t)n * Hv);
    float4 g0 = gr[0], g1 = gr[1];
    float gv[8] = {g0.x, g0.y, g0.z, g0.w, g1.x, g1.y, g1.z, g1.w};
    float o[8];
    #pragma unroll
    for (int ch = 0; ch < 8; ++ch) {
      float s = lb2[ch];
      #pragma unroll
      for (int j = 0; j < 8; ++j) s += u[j] * lw2[j * 8 + ch];
      float val = s + hv[ch];
      s1 += val; s2 += val * val;
      o[ch] = val * gv[ch];
    }
    float4* vo = (float4*)(vt + row);
    vo[0] = make_float4(o[0], o[1], o[2], o[3]);
    vo[1] = make_float4(o[4], o[5], o[6], o[7]);
  }
  partial_to_stats(s1, s2, stats1 + (size_t)g * 2);
}

// ---------------- stage 2: IPT2 images/thread, EU-edge unroll (16 gathers in flight)
__global__ __launch_bounds__(256) void k_stage2(
    const float* __restrict__ vt, float* __restrict__ v2,
    const int* __restrict__ row_ptr, const float2* __restrict__ epack,
    const float* __restrict__ Gw, const float* __restrict__ Gb,
    const float* __restrict__ stats1, float* stats2,
    const float* __restrict__ tvec) {
  __shared__ float2 se[ECAP];
  int t = threadIdx.x;
  int b = blockIdx.x & 7;
  int local = blockIdx.x >> 3;
  int pair = local % 6;
  int chunk = local / 6;
  int g0 = b * Pv + pair * IPT2;
  int nb0 = chunk * 256;
  int nb1 = nb0 + 256; if (nb1 > Nv) nb1 = Nv;
  int eb0 = row_ptr[nb0];
  int eb1 = row_ptr[nb1];
  int cnt = eb1 - eb0;
  const float2* eps;
  int ebase;
  if (cnt <= ECAP) {
    for (int k = t; k < cnt; k += 256) se[k] = epack[eb0 + k];
    eps = se; ebase = eb0;
  } else {
    eps = epack; ebase = 0;
  }
  __syncthreads();
  float mean[IPT2], rstd[IPT2], mrs[IPT2];
  #pragma unroll
  for (int j = 0; j < IPT2; ++j) {
    float m  = stats1[(g0 + j) * 2]     * (1.f / 40000.f);
    float m2 = stats1[(g0 + j) * 2 + 1] * (1.f / 40000.f);
    float var = m2 - m * m;
    mean[j] = m;
    rstd[j] = (float)(1.0 / sqrt((double)var + 1e-5));
    mrs[j]  = m * rstd[j];
  }
  int n = nb0 + t;
  float s1a[IPT2], s2a[IPT2];
  #pragma unroll
  for (int j = 0; j < IPT2; ++j) { s1a[j] = 0.f; s2a[j] = 0.f; }
  if (n < Nv) {
    const float* vt0 = vt + (size_t)(g0 + 0) * Nv * Hv;
    const float* vt1 = vt + (size_t)(g0 + 1) * Nv * Hv;
    float a[IPT2][8];
    #pragma unroll
    for (int j = 0; j < IPT2; ++j)
      #pragma unroll
      for (int ch = 0; ch < 8; ++ch) a[j][ch] = 0.f;
    int e0 = row_ptr[n] - ebase, e1 = row_ptr[n + 1] - ebase;
    int e = e0;
    for (; e + EU <= e1; e += EU) {
      float2 pp[EU];
      float4 A0[EU], B0[EU], A1[EU], B1[EU];
      #pragma unroll
      for (int k = 0; k < EU; ++k) pp[k] = eps[e + k];
      #pragma unroll
      for (int k = 0; k < EU; ++k) {
        size_t so = (size_t)__float_as_int(pp[k].x) * Hv;
        const float4* r0 = (const float4*)(vt0 + so);
        const float4* r1 = (const float4*)(vt1 + so);
        A0[k] = r0[0]; B0[k] = r0[1];
        A1[k] = r1[0]; B1[k] = r1[1];
      }
      #pragma unroll
      for (int k = 0; k < EU; ++k) {
        float w = pp[k].y;
        a[0][0] += w * A0[k].x; a[0][1] += w * A0[k].y;
        a[0][2] += w * A0[k].z; a[0][3] += w * A0[k].w;
        a[0][4] += w * B0[k].x; a[0][5] += w * B0[k].y;
        a[0][6] += w * B0[k].z; a[0][7] += w * B0[k].w;
        a[1][0] += w * A1[k].x; a[1][1] += w * A1[k].y;
        a[1][2] += w * A1[k].z; a[1][3] += w * A1[k].w;
        a[1][4] += w * B1[k].x; a[1][5] += w * B1[k].y;
        a[1][6] += w * B1[k].z; a[1][7] += w * B1[k].w;
      }
    }
    for (; e < e1; ++e) {
      float2 ep = eps[e];
      float w = ep.y;
      size_t so = (size_t)__float_as_int(ep.x) * Hv;
      const float4* r0 = (const float4*)(vt0 + so);
      const float4* r1 = (const float4*)(vt1 + so);
      float4 xa = r0[0], xb = r0[1];
      float4 ya = r1[0], yb = r1[1];
      a[0][0] += w*xa.x; a[0][1] += w*xa.y; a[0][2] += w*xa.z; a[0][3] += w*xa.w;
      a[0][4] += w*xb.x; a[0][5] += w*xb.y; a[0][6] += w*xb.z; a[0][7] += w*xb.w;
      a[1][0] += w*ya.x; a[1][1] += w*ya.y; a[1][2] += w*ya.z; a[1][3] += w*ya.w;
      a[1][4] += w*yb.x; a[1][5] += w*yb.y; a[1][6] += w*yb.z; a[1][7] += w*yb.w;
    }
    size_t noff = (size_t)n * Hv;
    const float4* wr = (const float4*)(Gw + noff);
    const float4* br = (const float4*)(Gb + noff);
    float4 w0 = wr[0], w1 = wr[1], b0 = br[0], b1 = br[1];
    float gw8[8] = {w0.x, w0.y, w0.z, w0.w, w1.x, w1.y, w1.z, w1.w};
    float gb8[8] = {b0.x, b0.y, b0.z, b0.w, b1.x, b1.y, b1.z, b1.w};
    float tl[8];
    {
      const float4* tr = (const float4*)(tvec + b * Hv);
      float4 t0 = tr[0], t1 = tr[1];
      tl[0] = t0.x; tl[1] = t0.y; tl[2] = t0.z; tl[3] = t0.w;
      tl[4] = t1.x; tl[5] = t1.y; tl[6] = t1.z; tl[7] = t1.w;
    }
    #pragma unroll
    for (int j = 0; j < IPT2; ++j) {
      float o[8];
      #pragma unroll
      for (int ch = 0; ch < 8; ++ch) {
        float val = rstd[j] * a[j][ch] - mrs[j] * gw8[ch] + gb8[ch] + tl[ch];
        o[ch] = val;
        s1a[j] += val; s2a[j] += val * val;
      }
      float* vo = v2 + (size_t)(g0 + j) * Nv * Hv + noff;
      nt_store4(vo,     o[0], o[1], o[2], o[3]);
      nt_store4(vo + 4, o[4], o[5], o[6], o[7]);
    }
  }
  #pragma unroll
  for (int j = 0; j < IPT2; ++j)
    partial_to_stats(s1a[j], s2a[j], stats2 + (size_t)(g0 + j) * 2);
}

// ---------------- stage 3: LN(v2) + conv (6 q per block) + skip acc; conv-out -> hout.
// grid: 8 (b) * 40 (chunk) * 2 (q-half) = 640 blocks; last iter fuses out proj
__global__ __launch_bounds__(256) void k_stage3(
    const float* __restrict__ v2, float* __restrict__ hout,
    float* __restrict__ acc,
    const float* __restrict__ stats2,
    const float* __restrict__ tnw, const float* __restrict__ tnb,
    const float* __restrict__ cw, const float* __restrict__ cb,
    const float* __restrict__ a9, int iblk,
    const float* __restrict__ ow1, const float* __restrict__ ob1,
    const float* __restrict__ ow2, const float* __restrict__ ob2,
    float* __restrict__ out) {
  __shared__ float scw[144], scb[12], smean[12], srstd[12];
  __shared__ float sow1[64], sob1[8], sow2[8], sob2[1];
  int t = threadIdx.x;
  int b = blockIdx.x & 7;
  int local = blockIdx.x >> 3;
  int qh = local & 1;
  int chunk = local >> 1;
  bool last = (iblk == NBv - 1);
  if (t < 144) scw[t] = cw[t];
  else if (t < 156) scb[t - 144] = cb[t - 144];
  else if (t < 168) {
    int p = t - 156;
    int g = b * Pv + p;
    float mean = stats2[g * 2]     * (1.f / 40000.f);
    float m2   = stats2[g * 2 + 1] * (1.f / 40000.f);
    float var  = m2 - mean * mean;
    smean[p] = mean;
    srstd[p] = (float)(1.0 / sqrt((double)var + 1e-5));
  } else if (last) {
    if (t < 232) sow1[t - 168] = ow1[t - 168];
    else if (t < 240) sob1[t - 232] = ob1[t - 232];
    else if (t < 248) sow2[t - 240] = ow2[t - 240];
    else if (t == 248) sob2[0] = ob2[0];
  }
  __syncthreads();
  int idx = chunk * 256 + t;
  if (idx >= Nv * 2) return;
  int n = idx >> 1, c4 = idx & 1;
  size_t noff = (size_t)n * Hv + c4 * 4;
  const float4 w4 = nt_load4(tnw + noff);
  const float4 b4 = nt_load4(tnb + noff);
  size_t strideP = (size_t)Nv * Hv;
  size_t base = (size_t)b * Pv * strideP + noff;
  float4 in[12];
  #pragma unroll
  for (int p = 0; p < 12; ++p) {
    float4 v = nt_load4(v2 + base + p * strideP);
    float mean = smean[p], rstd = srstd[p];
    in[p].x = (v.x - mean) * rstd * w4.x + b4.x;
    in[p].y = (v.y - mean) * rstd * w4.y + b4.y;
    in[p].z = (v.z - mean) * rstd * w4.z + b4.z;
    in[p].w = (v.w - mean) * rstd * w4.w + b4.w;
  }
  float ai = a9[iblk + 1];
  int q0 = qh * 6;
  #pragma unroll
  for (int qi = 0; qi < 6; ++qi) {
    int q = q0 + qi;
    float4 o = make_float4(scb[q], scb[q], scb[q], scb[q]);
    #pragma unroll
    for (int p = 0; p < 12; ++p) {
      float c = scw[q * 12 + p];
      o.x += c * in[p].x; o.y += c * in[p].y;
      o.z += c * in[p].z; o.w += c * in[p].w;
    }
    size_t off = base + q * strideP;
    float4* ap = (float4*)(acc + off);
    float4 av = *ap;
    float n0 = av.x + ai * o.x, n1 = av.y + ai * o.y;
    float n2 = av.z + ai * o.z, n3 = av.w + ai * o.w;
    if (!last) {
      *(float4*)(hout + off) = o;     // h for next stage1 (Y buffer; vt dead)
      *ap = make_float4(n0, n1, n2, n3);
    } else {
      float e0 = __shfl_xor(n0, 1, 64);
      float e1 = __shfl_xor(n1, 1, 64);
      float e2 = __shfl_xor(n2, 1, 64);
      float e3 = __shfl_xor(n3, 1, 64);
      float a8[8];
      if (c4 == 0) {
        a8[0] = n0; a8[1] = n1; a8[2] = n2; a8[3] = n3;
        a8[4] = e0; a8[5] = e1; a8[6] = e2; a8[7] = e3;
      } else {
        a8[0] = e0; a8[1] = e1; a8[2] = e2; a8[3] = e3;
        a8[4] = n0; a8[5] = n1; a8[6] = n2; a8[7] = n3;
      }
      if (c4 == 0) {
        float oo = sob2[0];
        #pragma unroll
        for (int j = 0; j < 8; ++j) {
          float s = sob1[j];
          #pragma unroll
          for (int k = 0; k < 8; ++k) s += a8[k] * sow1[k * 8 + j];
          oo += fmaxf(s, 0.f) * sow2[j];
        }
        out[((size_t)b * Pv + q) * Nv + n] = oo;
      }
    }
  }
}

extern "C" void kernel_launch(void* const* d_in, const int* in_sizes, int n_in,
                              void* d_out, int out_size, void* d_ws, size_t ws_size,
                              hipStream_t stream) {
  const float* x      = (const float*)d_in[0];
  const float* cond   = (const float*)d_in[1];
  const float* pos    = (const float*)d_in[2];
  const int*   timei  = (const int*)  d_in[3];
  const int*   eidx   = (const int*)  d_in[4];
  const float* te_w1  = (const float*)d_in[5];
  const float* te_b1  = (const float*)d_in[6];
  const float* te_w2  = (const float*)d_in[7];
  const float* te_b2  = (const float*)d_in[8];
  const float* in_w1  = (const float*)d_in[9];
  const float* in_b1  = (const float*)d_in[10];
  const float* in_w2  = (const float*)d_in[11];
  const float* in_b2  = (const float*)d_in[12];
  const float* pos_w1 = (const float*)d_in[13];
  const float* pos_b1 = (const float*)d_in[14];
  const float* pos_w2 = (const float*)d_in[15];
  const float* pos_b2 = (const float*)d_in[16];
  const float* attn   = (const float*)d_in[17];
  const float* bt_w1  = (const float*)d_in[18];
  const float* bt_b1  = (const float*)d_in[19];
  const float* bt_w2  = (const float*)d_in[20];
  const float* bt_b2  = (const float*)d_in[21];
  const float* bc_w1  = (const float*)d_in[22];
  const float* bc_b1  = (const float*)d_in[23];
  const float* bc_w2  = (const float*)d_in[24];
  const float* bc_b2  = (const float*)d_in[25];
  const float* gn_w   = (const float*)d_in[26];
  const float* gn_b   = (const float*)d_in[27];
  const float* tn_w   = (const float*)d_in[28];
  const float* tn_b   = (const float*)d_in[29];
  const float* cv_w   = (const float*)d_in[30];
  const float* cv_b   = (const float*)d_in[31];
  const float* out_w1 = (const float*)d_in[32];
  const float* out_b1 = (const float*)d_in[33];
  const float* out_w2 = (const float*)d_in[34];
  const float* out_b2 = (const float*)d_in[35];
  float* out = (float*)d_out;

  const size_t HSZ = (size_t)Bv * Pv * Nv * Hv;  // 3,840,000
  float* ws    = (float*)d_ws;
  float* X     = ws;                 // v2 buffer
  float* Y     = X + HSZ;            // h / vt buffer (stage1 swaps in-place)
  float* acc   = Y + HSZ;
  float* posp  = acc + HSZ;          // Nv*Hv
  float* deg   = posp + Nv * Hv;     // Nv
  float* dinv  = deg + Nv;           // Nv
  float* epack = dinv + Nv;          // 2*Ev floats
  float* t_all = epack + 2 * Ev;     // NBv*Bv*Hv = 512
  float* a9    = t_all + NBv * Bv * Hv;  // 16
  float* stats = a9 + 16;            // NBv*2*NIMG*2 = 3072
  float* Gw    = stats + NBv * 2 * NIMG * 2;  // NBv*Nv*Hv = 320000
  float* Gb    = Gw + NBv * Nv * Hv;          // 320000
  int* row_ptr = (int*)(Gb + NBv * Nv * Hv);  // Nv+8
  int* cursor  = row_ptr + Nv + 8;   // Nv+8

  k_setup<<<1, 512, 0, stream>>>(timei, attn, te_w1, te_b1, te_w2, te_b2,
                                 bt_w1, bt_b1, bt_w2, bt_b2, t_all, a9);
  k_posp_zero<<<(Nv + 255) / 256, 256, 0, stream>>>(
      pos, pos_w1, pos_b1, pos_w2, pos_b2, posp, deg, cursor, stats);
  k_deg<<<(Ev + 255) / 256, 256, 0, stream>>>(eidx, deg);
  k_scan<<<1, 1024, 0, stream>>>(deg, dinv, row_ptr);
  k_csr<<<(Ev + 255) / 256, 256, 0, stream>>>(eidx, dinv, row_ptr, cursor, (float2*)epack);
  k_gwb<<<(NBv * Nv + 255) / 256, 256, 0, stream>>>(
      row_ptr, (const float2*)epack, gn_w, gn_b, Gw, Gb);

  for (int i = 0; i < NBv; ++i) {
    float* st1 = stats + (size_t)(i * 2 + 0) * NIMG * 2;
    float* st2 = stats + (size_t)(i * 2 + 1) * NIMG * 2;
    if (i == 0) {
      k_stage1_init<<<NIMG * BLKS_PER_IMG, 256, 0, stream>>>(
          x, posp, in_w1, in_b1, in_w2, in_b2,
          cond, bc_w1, bc_b1, bc_w2, bc_b2,
          gn_w, a9, acc, Y, st1);
    } else {
      k_stage1<<<8 * 12 * CHUNKS1, 256, 0, stream>>>(
          Y, cond,
          bc_w1 + i * 64, bc_b1 + i * 8, bc_w2 + i * 64, bc_b2 + i * 8,
          gn_w + (size_t)i * Nv * Hv,
          st1);
    }
    k_stage2<<<8 * 6 * BLKS_PER_IMG, 256, 0, stream>>>(
        Y, X, row_ptr, (const float2*)epack,
        Gw + (size_t)i * Nv * Hv, Gb + (size_t)i * Nv * Hv,
        st1, st2, t_all + i * Bv * Hv);
    k_stage3<<<8 * 40 * 2, 256, 0, stream>>>(
        X, Y, acc, st2,
        tn_w + (size_t)i * Nv * Hv, tn_b + (size_t)i * Nv * Hv,
        cv_w + i * 144, cv_b + i * 12, a9, i,
        out_w1, out_b1, out_w2, out_b2, out);
  }
}